// Round 2
// baseline (2004.540 us; speedup 1.0000x reference)
//
#include <hip/hip_runtime.h>
#include <math.h>

#define NB 16
#define NN 2048
#define ND 256
#define BNtot (NB*NN)
#define HH 33554432u   // 2^25 = half of 16*2048*2048 (threefry counter split)

// ---------------- threefry2x32, bit-exact vs jax.random.key(42) ----------------
// Single-output version (fallback path)
__device__ __forceinline__ float gumbelv(unsigned b, unsigned n, unsigned m){
  unsigned f = (b<<22) | (n<<11) | m;
  unsigned x0 = (b < 8u) ? f : (f - HH);
  unsigned x1 = x0 + HH;
  const unsigned ks0=0u, ks1=42u, ks2=0u^42u^0x1BD11BDAu;
  unsigned v0 = x0 + ks0;
  unsigned v1 = x1 + ks1;
#define TFR(r) { v0 += v1; v1 = (v1<<(r))|(v1>>(32-(r))); v1 ^= v0; }
  TFR(13) TFR(15) TFR(26) TFR(6)
  v0 += ks1; v1 += ks2 + 1u;
  TFR(17) TFR(29) TFR(16) TFR(24)
  v0 += ks2; v1 += ks0 + 2u;
  TFR(13) TFR(15) TFR(26) TFR(6)
  v0 += ks0; v1 += ks1 + 3u;
  TFR(17) TFR(29) TFR(16) TFR(24)
  v0 += ks1; v1 += ks2 + 4u;
  TFR(13) TFR(15) TFR(26) TFR(6)
  v0 += ks2; v1 += ks0 + 5u;
#undef TFR
  unsigned bits = (b < 8u) ? v0 : v1;
  float fl = __uint_as_float((bits>>9) | 0x3F800000u) - 1.0f;
  float u = fmaxf(1e-10f, fl + 1e-10f);
  return -logf(-logf(u));
}

// Paired version: one threefry eval serves batches bl and bl+8 (counter pair f, f+2^25)
__device__ __forceinline__ float2 gumbel2(unsigned bl, unsigned n, unsigned m){
  unsigned x0 = (bl<<22) | (n<<11) | m;
  unsigned x1 = x0 + HH;
  const unsigned ks0=0u, ks1=42u, ks2=0u^42u^0x1BD11BDAu;
  unsigned v0 = x0 + ks0;
  unsigned v1 = x1 + ks1;
#define TFR(r) { v0 += v1; v1 = (v1<<(r))|(v1>>(32-(r))); v1 ^= v0; }
  TFR(13) TFR(15) TFR(26) TFR(6)
  v0 += ks1; v1 += ks2 + 1u;
  TFR(17) TFR(29) TFR(16) TFR(24)
  v0 += ks2; v1 += ks0 + 2u;
  TFR(13) TFR(15) TFR(26) TFR(6)
  v0 += ks0; v1 += ks1 + 3u;
  TFR(17) TFR(29) TFR(16) TFR(24)
  v0 += ks1; v1 += ks2 + 4u;
  TFR(13) TFR(15) TFR(26) TFR(6)
  v0 += ks2; v1 += ks0 + 5u;
#undef TFR
  float f0 = __uint_as_float((v0>>9) | 0x3F800000u) - 1.0f;
  float f1 = __uint_as_float((v1>>9) | 0x3F800000u) - 1.0f;
  float u0 = fmaxf(1e-10f, f0 + 1e-10f);
  float u1 = fmaxf(1e-10f, f1 + 1e-10f);
  return make_float2(-logf(-logf(u0)), -logf(-logf(u1)));
}

// ---------------- row norms ----------------
__global__ void knorms(const float* __restrict__ LLF, const float* __restrict__ HLF,
                       float* __restrict__ nl, float* __restrict__ nh){
  int row = blockIdx.x;
  int wave = threadIdx.x >> 6;
  int lane = threadIdx.x & 63;
  const float* src = wave ? HLF : LLF;
  float4 v = ((const float4*)(src + (size_t)row*ND))[lane];
  float s = v.x*v.x + v.y*v.y + v.z*v.z + v.w*v.w;
  for (int o=32;o;o>>=1) s += __shfl_down(s,o);
  if (lane==0) (wave? nh: nl)[row] = sqrtf(s);
}

// ---------------- fast path: 128x128 SGEMM, 8x8/thread, k-major LDS ----------------
__launch_bounds__(256)
__global__ void kgemm(const float* __restrict__ LLF, const float* __restrict__ HLF,
                      const float* __restrict__ nl, const float* __restrict__ nh,
                      float* __restrict__ sim){
  __shared__ float As[16][132];   // [k][n], pad 132: staging writes 2-way max, frag reads b128
  __shared__ float Bs[16][132];   // [k][m]
  const int b  = blockIdx.z;
  const int n0 = blockIdx.y << 7;
  const int m0 = blockIdx.x << 7;
  const float* Ab = LLF + (size_t)b*NN*ND;
  const float* Bb = HLF + (size_t)b*NN*ND;
  const int tid = threadIdx.x;
  const int tx = tid & 15, ty = tid >> 4;
  const int lr = tid >> 2;          // staging row 0..63 (+64)
  const int lc = (tid & 3) << 2;    // staging k-col 0,4,8,12
  float acc[8][8];
  #pragma unroll
  for (int i=0;i<8;i++)
    #pragma unroll
    for (int j=0;j<8;j++) acc[i][j] = 0.0f;

  for (int kc=0; kc<ND; kc+=16){
    __syncthreads();
    #pragma unroll
    for (int s=0;s<2;s++){
      int row = lr + (s<<6);
      float4 va = *(const float4*)(Ab + (size_t)(n0+row)*ND + kc + lc);
      As[lc+0][row]=va.x; As[lc+1][row]=va.y; As[lc+2][row]=va.z; As[lc+3][row]=va.w;
      float4 vb = *(const float4*)(Bb + (size_t)(m0+row)*ND + kc + lc);
      Bs[lc+0][row]=vb.x; Bs[lc+1][row]=vb.y; Bs[lc+2][row]=vb.z; Bs[lc+3][row]=vb.w;
    }
    __syncthreads();
    #pragma unroll
    for (int k=0;k<16;k++){
      float a[8], bb[8];
      *(float4*)&a[0]  = *(const float4*)&As[k][ty*8];
      *(float4*)&a[4]  = *(const float4*)&As[k][ty*8+4];
      *(float4*)&bb[0] = *(const float4*)&Bs[k][tx*8];
      *(float4*)&bb[4] = *(const float4*)&Bs[k][tx*8+4];
      #pragma unroll
      for (int i=0;i<8;i++)
        #pragma unroll
        for (int j=0;j<8;j++) acc[i][j] += a[i]*bb[j];
    }
  }
  float nlv[8], nhv[8];
  #pragma unroll
  for (int i=0;i<8;i++) nlv[i] = nl[b*NN + n0 + ty*8 + i];
  #pragma unroll
  for (int j=0;j<8;j++) nhv[j] = nh[b*NN + m0 + tx*8 + j];
  #pragma unroll
  for (int i=0;i<8;i++){
    float r[8];
    #pragma unroll
    for (int j=0;j<8;j++) r[j] = (acc[i][j] / fmaxf(nlv[i]*nhv[j], 1e-8f)) * 0.0625f;
    float* dst = sim + ((size_t)(b*NN + n0 + ty*8 + i))*NN + m0 + tx*8;
    *(float4*)dst     = make_float4(r[0],r[1],r[2],r[3]);
    *(float4*)(dst+4) = make_float4(r[4],r[5],r[6],r[7]);
  }
}

// ---------------- fast path: column softmax partial sums ----------------
// |sim| <= 1/16 (cosine/16), so a fixed shift 0.0625 replaces the online max:
// softmax is shift-invariant, exp(sim-0.0625) in [0.88,1] — no overflow possible.
__global__ void kstats2(const float* __restrict__ sim, float* __restrict__ partS){
  int b  = blockIdx.z;                       // 16
  int np = blockIdx.y;                       // 8 n-parts of 256
  int m  = (blockIdx.x<<8) + threadIdx.x;    // 8 m-chunks of 256
  const float* p = sim + ((size_t)b*NN + (np<<8))*NN + m;
  float s = 0.0f;
  #pragma unroll 8
  for (int k=0;k<256;k++) s += expf(p[(size_t)k*NN] - 0.0625f);
  partS[((b<<3)+np)*NN + m] = s;
}

__global__ void kcomb(const float* __restrict__ partS, float* __restrict__ iS){
  int g = blockIdx.x*256 + threadIdx.x;      // b*NN+m
  int b = g >> 11, m = g & 2047;
  float s = 0.0f;
  #pragma unroll
  for (int p=0;p<8;p++) s += partS[((b<<3)+p)*NN + m];
  iS[g] = 1.0f/s;
}

// ---------------- fast path: argmax_n(probs + gumbel), batch-paired ----------------
__global__ void kargmax2(const float* __restrict__ sim, const float* __restrict__ iS,
                         float* __restrict__ partV, int* __restrict__ partI){
  int bl = blockIdx.z;                       // 8 batch pairs (bl, bl+8)
  int np = blockIdx.y;                       // 8 n-parts
  int m  = (blockIdx.x<<8) + threadIdx.x;    // 8 m-chunks
  int bh = bl + 8;
  const float* p0 = sim + ((size_t)bl*NN + (np<<8))*NN + m;
  const float* p1 = sim + ((size_t)bh*NN + (np<<8))*NN + m;
  float is0 = iS[bl*NN+m], is1 = iS[bh*NN+m];
  float v0b = -INFINITY, v1b = -INFINITY;
  int   i0b = 0,         i1b = 0;
  int nbase = np << 8;
  #pragma unroll 2
  for (int k=0;k<256;k++){
    int n = nbase + k;
    float2 g = gumbel2((unsigned)bl, (unsigned)n, (unsigned)m);
    float q0 = expf(p0[(size_t)k*NN] - 0.0625f)*is0 + g.x;
    float q1 = expf(p1[(size_t)k*NN] - 0.0625f)*is1 + g.y;
    if (q0 > v0b){ v0b = q0; i0b = n; }      // strict > + ascending n = first max
    if (q1 > v1b){ v1b = q1; i1b = n; }
  }
  partV[((bl<<3)+np)*NN+m] = v0b; partI[((bl<<3)+np)*NN+m] = i0b;
  partV[((bh<<3)+np)*NN+m] = v1b; partI[((bh<<3)+np)*NN+m] = i1b;
}

__global__ void kargcomb(const float* __restrict__ partV, const int* __restrict__ partI,
                         int* __restrict__ idx){
  int g = blockIdx.x*256 + threadIdx.x;
  int b = g >> 11, m = g & 2047;
  float bv = -INFINITY; int bi = 0;
  #pragma unroll
  for (int p=0;p<8;p++){                     // ascending p = ascending n, strict >
    float v = partV[((b<<3)+p)*NN+m];
    if (v > bv){ bv = v; bi = partI[((b<<3)+p)*NN+m]; }
  }
  idx[g] = bi;
}

// ---------------- fallback path (round-1 kernels, used if ws too small) ----------------
__launch_bounds__(256)
__global__ void kstats(const float* __restrict__ A, const float* __restrict__ Bm,
                       const float* __restrict__ nl, const float* __restrict__ nh,
                       float* __restrict__ Mout, float* __restrict__ Sinv){
  __shared__ float As[64][33];
  __shared__ float Bs[64][33];
  __shared__ float Cs[64][65];
  const int b  = blockIdx.x >> 5;
  const int m0 = (blockIdx.x & 31) << 6;
  const float* Ab = A  + (size_t)b*NN*ND;
  const float* Bb = Bm + (size_t)b*NN*ND;
  const int tid = threadIdx.x;
  const int tx = tid & 15, ty = tid >> 4;
  float nhv[4];
  #pragma unroll
  for (int j=0;j<4;j++) nhv[j] = nh[b*NN + m0 + tx*4 + j];
  float Mr = -INFINITY, Sr = 0.0f;
  for (int nt=0; nt<NN; nt+=64){
    float acc[4][4] = {{0.f,0.f,0.f,0.f},{0.f,0.f,0.f,0.f},{0.f,0.f,0.f,0.f},{0.f,0.f,0.f,0.f}};
    for (int kc=0; kc<ND; kc+=32){
      __syncthreads();
      #pragma unroll
      for (int s=0;s<2;s++){
        int f = tid + (s<<8);
        int r = f >> 3;
        int c = (f & 7) << 2;
        float4 va = *(const float4*)(Ab + (size_t)(nt+r)*ND + kc + c);
        As[r][c]=va.x; As[r][c+1]=va.y; As[r][c+2]=va.z; As[r][c+3]=va.w;
        float4 vb = *(const float4*)(Bb + (size_t)(m0+r)*ND + kc + c);
        Bs[r][c]=vb.x; Bs[r][c+1]=vb.y; Bs[r][c+2]=vb.z; Bs[r][c+3]=vb.w;
      }
      __syncthreads();
      #pragma unroll 4
      for (int k=0;k<32;k++){
        float a0=As[ty*4+0][k], a1=As[ty*4+1][k], a2=As[ty*4+2][k], a3=As[ty*4+3][k];
        float b0=Bs[tx*4+0][k], b1=Bs[tx*4+1][k], b2=Bs[tx*4+2][k], b3=Bs[tx*4+3][k];
        acc[0][0]+=a0*b0; acc[0][1]+=a0*b1; acc[0][2]+=a0*b2; acc[0][3]+=a0*b3;
        acc[1][0]+=a1*b0; acc[1][1]+=a1*b1; acc[1][2]+=a1*b2; acc[1][3]+=a1*b3;
        acc[2][0]+=a2*b0; acc[2][1]+=a2*b1; acc[2][2]+=a2*b2; acc[2][3]+=a2*b3;
        acc[3][0]+=a3*b0; acc[3][1]+=a3*b1; acc[3][2]+=a3*b2; acc[3][3]+=a3*b3;
      }
    }
    float nlv[4];
    #pragma unroll
    for (int i=0;i<4;i++) nlv[i] = nl[b*NN + nt + ty*4 + i];
    __syncthreads();
    #pragma unroll
    for (int i=0;i<4;i++)
      #pragma unroll
      for (int j=0;j<4;j++){
        float denom = fmaxf(nlv[i]*nhv[j], 1e-8f);
        Cs[ty*4+i][tx*4+j] = (acc[i][j]/denom)*0.0625f;
      }
    __syncthreads();
    if (tid < 64){
      float tmax = -INFINITY;
      #pragma unroll 8
      for (int r=0;r<64;r++) tmax = fmaxf(tmax, Cs[r][tid]);
      float newM = fmaxf(Mr, tmax);
      float s = 0.0f;
      #pragma unroll 4
      for (int r=0;r<64;r++) s += expf(Cs[r][tid]-newM);
      Sr = Sr*expf(Mr-newM) + s;
      Mr = newM;
    }
  }
  if (tid < 64){
    Mout[b*NN+m0+tid] = Mr;
    Sinv[b*NN+m0+tid] = 1.0f/Sr;
  }
}

__launch_bounds__(256)
__global__ void kargmax(const float* __restrict__ A, const float* __restrict__ Bm,
                        const float* __restrict__ nl, const float* __restrict__ nh,
                        const float* __restrict__ Mv, const float* __restrict__ Sv,
                        int* __restrict__ idxout){
  __shared__ float As[64][33];
  __shared__ float Bs[64][33];
  __shared__ float Vs[16][64];
  __shared__ int   Is[16][64];
  const int b  = blockIdx.x >> 5;
  const int m0 = (blockIdx.x & 31) << 6;
  const float* Ab = A  + (size_t)b*NN*ND;
  const float* Bb = Bm + (size_t)b*NN*ND;
  const int tid = threadIdx.x;
  const int tx = tid & 15, ty = tid >> 4;
  float nhv[4], Mj[4], iSj[4];
  #pragma unroll
  for (int j=0;j<4;j++){
    int m = m0 + tx*4 + j;
    nhv[j] = nh[b*NN + m];
    Mj[j]  = Mv[b*NN + m];
    iSj[j] = Sv[b*NN + m];
  }
  float bestV = -INFINITY; int bestN = 0;
  for (int nt=0; nt<NN; nt+=64){
    float acc[4][4] = {{0.f,0.f,0.f,0.f},{0.f,0.f,0.f,0.f},{0.f,0.f,0.f,0.f},{0.f,0.f,0.f,0.f}};
    for (int kc=0; kc<ND; kc+=32){
      __syncthreads();
      #pragma unroll
      for (int s=0;s<2;s++){
        int f = tid + (s<<8);
        int r = f >> 3;
        int c = (f & 7) << 2;
        float4 va = *(const float4*)(Ab + (size_t)(nt+r)*ND + kc + c);
        As[r][c]=va.x; As[r][c+1]=va.y; As[r][c+2]=va.z; As[r][c+3]=va.w;
        float4 vb = *(const float4*)(Bb + (size_t)(m0+r)*ND + kc + c);
        Bs[r][c]=vb.x; Bs[r][c+1]=vb.y; Bs[r][c+2]=vb.z; Bs[r][c+3]=vb.w;
      }
      __syncthreads();
      #pragma unroll 4
      for (int k=0;k<32;k++){
        float a0=As[ty*4+0][k], a1=As[ty*4+1][k], a2=As[ty*4+2][k], a3=As[ty*4+3][k];
        float b0=Bs[tx*4+0][k], b1=Bs[tx*4+1][k], b2=Bs[tx*4+2][k], b3=Bs[tx*4+3][k];
        acc[0][0]+=a0*b0; acc[0][1]+=a0*b1; acc[0][2]+=a0*b2; acc[0][3]+=a0*b3;
        acc[1][0]+=a1*b0; acc[1][1]+=a1*b1; acc[1][2]+=a1*b2; acc[1][3]+=a1*b3;
        acc[2][0]+=a2*b0; acc[2][1]+=a2*b1; acc[2][2]+=a2*b2; acc[2][3]+=a2*b3;
        acc[3][0]+=a3*b0; acc[3][1]+=a3*b1; acc[3][2]+=a3*b2; acc[3][3]+=a3*b3;
      }
    }
    float nlv[4];
    #pragma unroll
    for (int i=0;i<4;i++) nlv[i] = nl[b*NN + nt + ty*4 + i];
    float lv[4]; int li[4];
    #pragma unroll
    for (int j=0;j<4;j++){ lv[j] = -INFINITY; li[j] = 0; }
    #pragma unroll
    for (int i=0;i<4;i++){
      int n = nt + ty*4 + i;
      #pragma unroll
      for (int j=0;j<4;j++){
        float denom = fmaxf(nlv[i]*nhv[j], 1e-8f);
        float sim = (acc[i][j]/denom)*0.0625f;
        float p = expf(sim - Mj[j]) * iSj[j];
        float v = p + gumbelv((unsigned)b, (unsigned)n, (unsigned)(m0 + tx*4 + j));
        if (v > lv[j]) { lv[j] = v; li[j] = n; }
      }
    }
    __syncthreads();
    #pragma unroll
    for (int j=0;j<4;j++){ Vs[ty][tx*4+j]=lv[j]; Is[ty][tx*4+j]=li[j]; }
    __syncthreads();
    if (tid < 64){
      #pragma unroll 4
      for (int t=0;t<16;t++){
        float v = Vs[t][tid];
        if (v > bestV){ bestV = v; bestN = Is[t][tid]; }
      }
    }
  }
  if (tid < 64) idxout[b*NN + m0 + tid] = bestN;
}

// ---------------- shared tail kernels ----------------
__global__ void ksort(const int* __restrict__ idx, int* __restrict__ cntg,
                      int* __restrict__ offg, int* __restrict__ sl){
  __shared__ int c[NN];
  __shared__ int part[256];
  int b = blockIdx.x, tid = threadIdx.x;
  for (int v=tid; v<NN; v+=256) c[v]=0;
  __syncthreads();
  for (int j=tid; j<NN; j+=256) atomicAdd(&c[idx[b*NN+j]], 1);
  __syncthreads();
  int base = tid*8, s=0, lc[8];
  #pragma unroll
  for (int k=0;k<8;k++){ lc[k]=c[base+k]; s+=lc[k]; }
  part[tid]=s; __syncthreads();
  for (int o=1;o<256;o<<=1){
    int v = (tid>=o)? part[tid-o] : 0;
    __syncthreads();
    part[tid]+=v;
    __syncthreads();
  }
  int run = part[tid]-s;
  #pragma unroll
  for (int k=0;k<8;k++){
    int v = base+k;
    cntg[b*NN+v]=lc[k];
    offg[b*NN+v]=run;
    for (int j=0;j<lc[k];j++) sl[b*NN+run+j]=v;
    run += lc[k];
  }
}

__global__ void kw(const float* __restrict__ LLF, const float* __restrict__ HLF,
                   const float* __restrict__ nl, const float* __restrict__ nh,
                   const int* __restrict__ sl, float* __restrict__ w){
  int g = blockIdx.x*4 + (threadIdx.x>>6);
  int lane = threadIdx.x & 63;
  int b = g >> 11;
  int s = sl[g];
  float4 a = ((const float4*)(HLF + ((size_t)b*NN + s)*ND))[lane];
  float4 l = ((const float4*)(LLF + (size_t)g*ND))[lane];
  float d = a.x*l.x + a.y*l.y + a.z*l.z + a.w*l.w;
  for (int o=32;o;o>>=1) d += __shfl_down(d,o);
  if (lane==0){
    float denom = fmaxf(nh[b*NN+s]*nl[g], 1e-8f);
    w[g] = d/denom;
  }
}

__global__ void knoise(const float* __restrict__ w, float* __restrict__ nz){
  int b = blockIdx.x, tid = threadIdx.x;
  __shared__ float sred[4];
  float x[8]; float mx = -INFINITY;
  #pragma unroll
  for (int k=0;k<8;k++){ x[k] = w[b*NN + tid*8 + k] / 0.1f; mx = fmaxf(mx, x[k]); }
  for (int o=32;o;o>>=1) mx = fmaxf(mx, __shfl_down(mx,o));
  mx = __shfl(mx, 0);
  if ((tid&63)==0) sred[tid>>6] = mx;
  __syncthreads();
  mx = fmaxf(fmaxf(sred[0],sred[1]), fmaxf(sred[2],sred[3]));
  __syncthreads();
  float e[8]; float s = 0.f;
  #pragma unroll
  for (int k=0;k<8;k++){ e[k] = expf(x[k]-mx); s += e[k]; }
  for (int o=32;o;o>>=1) s += __shfl_down(s,o);
  s = __shfl(s, 0);
  if ((tid&63)==0) sred[tid>>6] = s;
  __syncthreads();
  s = sred[0]+sred[1]+sred[2]+sred[3];
  #pragma unroll
  for (int k=0;k<8;k++) nz[b*NN + tid*8 + k] = e[k]/s;
}

__global__ void kfinal(const float* __restrict__ LLF, const float* __restrict__ HLF,
                       const int* __restrict__ cnt, const int* __restrict__ off,
                       const float* __restrict__ nz, float* __restrict__ out){
  int row = blockIdx.x;
  int lane = threadIdx.x;
  int b = row >> 11;
  float4 h = ((const float4*)(HLF + (size_t)row*ND))[lane];
  int c = cnt[row];
  if (c > 0){
    int i = off[row] + c - 1;
    float ns = nz[b*NN + i];
    float4 l = ((const float4*)(LLF + ((size_t)(b*NN + i))*ND))[lane];
    h.x += l.x*ns; h.y += l.y*ns; h.z += l.z*ns; h.w += l.w*ns;
  }
  ((float4*)(out + (size_t)row*ND))[lane] = h;
}

extern "C" void kernel_launch(void* const* d_in, const int* in_sizes, int n_in,
                              void* d_out, int out_size, void* d_ws, size_t ws_size,
                              hipStream_t stream){
  const float* LLF = (const float*)d_in[0];
  const float* HLF = (const float*)d_in[1];
  float* out = (float*)d_out;
  float* ws = (float*)d_ws;

  // fast-path workspace layout (floats)
  // [0..9*BNtot): nl, nh, iS, idx, cnt, off, sl, wv, nz (9 arrays)
  // then partS (8*BNtot/...): [16][8][2048] = 262144 floats
  // then partV 262144, partI 262144, then sim 16*2048*2048
  const size_t PART = (size_t)NB*8*NN;                 // 262144
  const size_t simOff = 9*(size_t)BNtot + 3*PART;
  const size_t needBytes = (simOff + (size_t)NB*NN*NN) * 4;

  float* nl  = ws;
  float* nh  = ws + 1*(size_t)BNtot;
  float* iS  = ws + 2*(size_t)BNtot;
  int*   idx = (int*)(ws + 3*(size_t)BNtot);
  int*   cnt = (int*)(ws + 4*(size_t)BNtot);
  int*   off = (int*)(ws + 5*(size_t)BNtot);
  int*   sl  = (int*)(ws + 6*(size_t)BNtot);
  float* wv  = ws + 7*(size_t)BNtot;
  float* nz  = ws + 8*(size_t)BNtot;

  hipLaunchKernelGGL(knorms, dim3(BNtot), dim3(128), 0, stream, LLF, HLF, nl, nh);

  if (ws_size >= needBytes){
    float* partS = ws + 9*(size_t)BNtot;
    float* partV = partS + PART;
    int*   partI = (int*)(partV + PART);
    float* sim   = ws + simOff;
    hipLaunchKernelGGL(kgemm,    dim3(16,16,16), dim3(256), 0, stream, LLF, HLF, nl, nh, sim);
    hipLaunchKernelGGL(kstats2,  dim3(8,8,16),   dim3(256), 0, stream, sim, partS);
    hipLaunchKernelGGL(kcomb,    dim3(BNtot/256),dim3(256), 0, stream, partS, iS);
    hipLaunchKernelGGL(kargmax2, dim3(8,8,8),    dim3(256), 0, stream, sim, iS, partV, partI);
    hipLaunchKernelGGL(kargcomb, dim3(BNtot/256),dim3(256), 0, stream, partV, partI, idx);
  } else {
    // fallback: recompute-GEMM path (round 1); borrow partS slot for Mv
    float* Mv = ws + 9*(size_t)BNtot;
    hipLaunchKernelGGL(kstats,  dim3(NB*32), dim3(256), 0, stream, LLF, HLF, nl, nh, Mv, iS);
    hipLaunchKernelGGL(kargmax, dim3(NB*32), dim3(256), 0, stream, LLF, HLF, nl, nh, Mv, iS, idx);
  }

  hipLaunchKernelGGL(ksort,  dim3(NB),      dim3(256), 0, stream, idx, cnt, off, sl);
  hipLaunchKernelGGL(kw,     dim3(BNtot/4), dim3(256), 0, stream, LLF, HLF, nl, nh, sl, wv);
  hipLaunchKernelGGL(knoise, dim3(NB),      dim3(256), 0, stream, wv, nz);
  hipLaunchKernelGGL(kfinal, dim3(BNtot),   dim3(64),  0, stream, LLF, HLF, cnt, off, nz, out);
}

// Round 3
// 734.302 us; speedup vs baseline: 2.7299x; 2.7299x over previous
//
#include <hip/hip_runtime.h>
#include <math.h>

#define NB 16
#define NN 2048
#define ND 256
#define BNtot (NB*NN)
#define HH 33554432u   // 2^25 = half of 16*2048*2048 (threefry counter split)

// ---------------- threefry2x32, bit-exact vs jax.random.key(42) ----------------
__device__ __forceinline__ float gumbelv(unsigned b, unsigned n, unsigned m){
  unsigned f = (b<<22) | (n<<11) | m;
  unsigned x0 = (b < 8u) ? f : (f - HH);
  unsigned x1 = x0 + HH;
  const unsigned ks0=0u, ks1=42u, ks2=0u^42u^0x1BD11BDAu;
  unsigned v0 = x0 + ks0;
  unsigned v1 = x1 + ks1;
#define TFR(r) { v0 += v1; v1 = (v1<<(r))|(v1>>(32-(r))); v1 ^= v0; }
  TFR(13) TFR(15) TFR(26) TFR(6)
  v0 += ks1; v1 += ks2 + 1u;
  TFR(17) TFR(29) TFR(16) TFR(24)
  v0 += ks2; v1 += ks0 + 2u;
  TFR(13) TFR(15) TFR(26) TFR(6)
  v0 += ks0; v1 += ks1 + 3u;
  TFR(17) TFR(29) TFR(16) TFR(24)
  v0 += ks1; v1 += ks2 + 4u;
  TFR(13) TFR(15) TFR(26) TFR(6)
  v0 += ks2; v1 += ks0 + 5u;
#undef TFR
  unsigned bits = (b < 8u) ? v0 : v1;
  float fl = __uint_as_float((bits>>9) | 0x3F800000u) - 1.0f;
  float u = fmaxf(1e-10f, fl + 1e-10f);
  return -logf(-logf(u));
}

// Paired: one threefry eval serves batches bl and bl+8 (counter pair f, f+2^25)
__device__ __forceinline__ float2 gumbel2(unsigned bl, unsigned n, unsigned m){
  unsigned x0 = (bl<<22) | (n<<11) | m;
  unsigned x1 = x0 + HH;
  const unsigned ks0=0u, ks1=42u, ks2=0u^42u^0x1BD11BDAu;
  unsigned v0 = x0 + ks0;
  unsigned v1 = x1 + ks1;
#define TFR(r) { v0 += v1; v1 = (v1<<(r))|(v1>>(32-(r))); v1 ^= v0; }
  TFR(13) TFR(15) TFR(26) TFR(6)
  v0 += ks1; v1 += ks2 + 1u;
  TFR(17) TFR(29) TFR(16) TFR(24)
  v0 += ks2; v1 += ks0 + 2u;
  TFR(13) TFR(15) TFR(26) TFR(6)
  v0 += ks0; v1 += ks1 + 3u;
  TFR(17) TFR(29) TFR(16) TFR(24)
  v0 += ks1; v1 += ks2 + 4u;
  TFR(13) TFR(15) TFR(26) TFR(6)
  v0 += ks2; v1 += ks0 + 5u;
#undef TFR
  float f0 = __uint_as_float((v0>>9) | 0x3F800000u) - 1.0f;
  float f1 = __uint_as_float((v1>>9) | 0x3F800000u) - 1.0f;
  float u0 = fmaxf(1e-10f, f0 + 1e-10f);
  float u1 = fmaxf(1e-10f, f1 + 1e-10f);
  return make_float2(-logf(-logf(u0)), -logf(-logf(u1)));
}

// ---------------- row norms ----------------
__global__ void knorms(const float* __restrict__ LLF, const float* __restrict__ HLF,
                       float* __restrict__ nl, float* __restrict__ nh){
  int row = blockIdx.x;
  int wave = threadIdx.x >> 6;
  int lane = threadIdx.x & 63;
  const float* src = wave ? HLF : LLF;
  float4 v = ((const float4*)(src + (size_t)row*ND))[lane];
  float s = v.x*v.x + v.y*v.y + v.z*v.z + v.w*v.w;
  for (int o=32;o;o>>=1) s += __shfl_down(s,o);
  if (lane==0) (wave? nh: nl)[row] = sqrtf(s);
}

// ---------------- fused 128x128 SGEMM + column-sum-of-exp epilogue ----------------
// |sim| <= 1/16 so exp(sim - 1/16) in [0.8825, 1]: fixed-shift softmax, no column max.
__launch_bounds__(256)
__global__ void kgemm(const float* __restrict__ LLF, const float* __restrict__ HLF,
                      const float* __restrict__ nl, const float* __restrict__ nh,
                      float* __restrict__ partS){
  __shared__ float As[16][132];   // [k][n]
  __shared__ float Bs[16][132];   // [k][m]
  const int b  = blockIdx.z;
  const int n0 = blockIdx.y << 7;
  const int m0 = blockIdx.x << 7;
  const float* Ab = LLF + (size_t)b*NN*ND;
  const float* Bb = HLF + (size_t)b*NN*ND;
  const int tid = threadIdx.x;
  const int tx = tid & 15, ty = tid >> 4;
  const int lr = tid >> 2;          // staging row 0..63 (+64)
  const int lc = (tid & 3) << 2;    // staging k-col 0,4,8,12
  float acc[8][8];
  #pragma unroll
  for (int i=0;i<8;i++)
    #pragma unroll
    for (int j=0;j<8;j++) acc[i][j] = 0.0f;

  for (int kc=0; kc<ND; kc+=16){
    __syncthreads();
    #pragma unroll
    for (int s=0;s<2;s++){
      int row = lr + (s<<6);
      float4 va = *(const float4*)(Ab + (size_t)(n0+row)*ND + kc + lc);
      As[lc+0][row]=va.x; As[lc+1][row]=va.y; As[lc+2][row]=va.z; As[lc+3][row]=va.w;
      float4 vb = *(const float4*)(Bb + (size_t)(m0+row)*ND + kc + lc);
      Bs[lc+0][row]=vb.x; Bs[lc+1][row]=vb.y; Bs[lc+2][row]=vb.z; Bs[lc+3][row]=vb.w;
    }
    __syncthreads();
    #pragma unroll
    for (int k=0;k<16;k++){
      float a[8], bb[8];
      *(float4*)&a[0]  = *(const float4*)&As[k][ty*8];
      *(float4*)&a[4]  = *(const float4*)&As[k][ty*8+4];
      *(float4*)&bb[0] = *(const float4*)&Bs[k][tx*8];
      *(float4*)&bb[4] = *(const float4*)&Bs[k][tx*8+4];
      #pragma unroll
      for (int i=0;i<8;i++)
        #pragma unroll
        for (int j=0;j<8;j++) acc[i][j] += a[i]*bb[j];
    }
  }
  float nlv[8], nhv[8];
  #pragma unroll
  for (int i=0;i<8;i++) nlv[i] = nl[b*NN + n0 + ty*8 + i];
  #pragma unroll
  for (int j=0;j<8;j++) nhv[j] = nh[b*NN + m0 + tx*8 + j];
  float colsum[8];
  #pragma unroll
  for (int j=0;j<8;j++) colsum[j] = 0.0f;
  #pragma unroll
  for (int i=0;i<8;i++)
    #pragma unroll
    for (int j=0;j<8;j++){
      float sim = (acc[i][j] / fmaxf(nlv[i]*nhv[j], 1e-8f)) * 0.0625f;
      colsum[j] += expf(sim - 0.0625f);
    }
  __syncthreads();                 // done reading As/Bs; reuse As for reduction
  #pragma unroll
  for (int j=0;j<8;j++) As[ty][tx*8+j] = colsum[j];
  __syncthreads();
  if (tid < 128){
    float s = 0.0f;
    #pragma unroll
    for (int r=0;r<16;r++) s += As[r][tid];
    partS[(size_t)blockIdx.y*BNtot + b*NN + m0 + tid] = s;
  }
}

__global__ void kScomb(const float* __restrict__ partS, float* __restrict__ iS){
  int g = blockIdx.x*256 + threadIdx.x;      // b*NN+m
  float s = 0.0f;
  #pragma unroll
  for (int nt=0; nt<16; nt++) s += partS[(size_t)nt*BNtot + g];
  iS[g] = 1.0f/s;
}

// ---------------- gumbel scan: windowed top-4 per (n-chunk, column) ----------------
// Winner needs g >= gmax - 0.1175/S >= gmax - 6.6e-5 (S >= 2048*e^-0.125, data-independent).
#define INS4(v0,v1,v2,v3,i0,i1,i2,i3,gv,nn) \
  if (gv > v3){ \
    if (gv > v1){ \
      v3=v2; i3=i2; v2=v1; i2=i1; \
      if (gv > v0){ v1=v0; i1=i0; v0=gv; i0=nn; } else { v1=gv; i1=nn; } \
    } else { \
      if (gv > v2){ v3=v2; i3=i2; v2=gv; i2=nn; } else { v3=gv; i3=nn; } \
    } \
  }

__global__ void kgumbel(float* __restrict__ pcv, int* __restrict__ pci){
  int t  = blockIdx.x*256 + threadIdx.x;     // 131072 threads
  int m  = t & 2047;
  int bl = (t >> 11) & 7;
  int nq = t >> 14;                          // 0..7, n-chunk of 256
  float a0=-INFINITY,a1=-INFINITY,a2=-INFINITY,a3=-INFINITY;
  float b0=-INFINITY,b1=-INFINITY,b2=-INFINITY,b3=-INFINITY;
  int   ai0=0,ai1=0,ai2=0,ai3=0, bi0=0,bi1=0,bi2=0,bi3=0;
  int nbase = nq << 8;
  for (int k=0;k<256;k++){
    int n = nbase + k;
    float2 g = gumbel2((unsigned)bl, (unsigned)n, (unsigned)m);
    INS4(a0,a1,a2,a3,ai0,ai1,ai2,ai3,g.x,n)
    INS4(b0,b1,b2,b3,bi0,bi1,bi2,bi3,g.y,n)
  }
  int baseA = (((nq*NB + bl  )*NN + m) << 2);
  int baseB = (((nq*NB + bl+8)*NN + m) << 2);
  pcv[baseA+0]=a0; pcv[baseA+1]=a1; pcv[baseA+2]=a2; pcv[baseA+3]=a3;
  pci[baseA+0]=ai0; pci[baseA+1]=ai1; pci[baseA+2]=ai2; pci[baseA+3]=ai3;
  pcv[baseB+0]=b0; pcv[baseB+1]=b1; pcv[baseB+2]=b2; pcv[baseB+3]=b3;
  pci[baseB+0]=bi0; pci[baseB+1]=bi1; pci[baseB+2]=bi2; pci[baseB+3]=bi3;
}

// ---------------- resolve: exact argmax among windowed candidates ----------------
__launch_bounds__(256)
__global__ void kresolve(const float* __restrict__ LLF, const float* __restrict__ HLF,
                         const float* __restrict__ nl, const float* __restrict__ nh,
                         const float* __restrict__ iS,
                         const float* __restrict__ pcv, const int* __restrict__ pci,
                         int* __restrict__ idx){
  int w    = threadIdx.x >> 6;               // wave within block
  int lane = threadIdx.x & 63;
  int g = blockIdx.x*4 + w;                  // b*NN+m
  int b = g >> 11, m = g & 2047;
  float pv = -INFINITY; int pn = 0;
  if (lane < 32){                            // nq = lane>>2, rank j = lane&3
    int base = ((((lane>>2)*NB + b)*NN + m) << 2) + (lane & 3);
    pv = pcv[base]; pn = pci[base];
  }
  float gmax = pv;
  for (int o=32;o;o>>=1) gmax = fmaxf(gmax, __shfl_down(gmax,o));
  gmax = __shfl(gmax, 0);
  unsigned long long mask = __ballot(pv >= gmax - 8e-5f);
  mask &= 0xFFFFFFFFull;
  float invS = iS[g];
  float bestQ = -INFINITY; int bestN = 1<<30;
  while (mask){
    int src = __builtin_ctzll(mask); mask &= mask-1;
    int   n  = __shfl(pn, src);
    float gv = __shfl(pv, src);
    float4 a = ((const float4*)(LLF + ((size_t)b*NN + n)*ND))[lane];
    float4 h = ((const float4*)(HLF + ((size_t)b*NN + m)*ND))[lane];
    float d = a.x*h.x + a.y*h.y + a.z*h.z + a.w*h.w;
    for (int o=32;o;o>>=1) d += __shfl_down(d,o);
    d = __shfl(d, 0);
    float sim = (d / fmaxf(nl[b*NN+n]*nh[g], 1e-8f)) * 0.0625f;
    float q = expf(sim - 0.0625f)*invS + gv;
    if (q > bestQ || (q == bestQ && n < bestN)){ bestQ = q; bestN = n; }
  }
  if (lane==0) idx[g] = bestN;
}

// ---------------- fallback path (round-1 kernels, used only if ws too small) ----------------
__launch_bounds__(256)
__global__ void kstats(const float* __restrict__ A, const float* __restrict__ Bm,
                       const float* __restrict__ nl, const float* __restrict__ nh,
                       float* __restrict__ Mout, float* __restrict__ Sinv){
  __shared__ float As[64][33];
  __shared__ float Bs[64][33];
  __shared__ float Cs[64][65];
  const int b  = blockIdx.x >> 5;
  const int m0 = (blockIdx.x & 31) << 6;
  const float* Ab = A  + (size_t)b*NN*ND;
  const float* Bb = Bm + (size_t)b*NN*ND;
  const int tid = threadIdx.x;
  const int tx = tid & 15, ty = tid >> 4;
  float nhv[4];
  #pragma unroll
  for (int j=0;j<4;j++) nhv[j] = nh[b*NN + m0 + tx*4 + j];
  float Mr = -INFINITY, Sr = 0.0f;
  for (int nt=0; nt<NN; nt+=64){
    float acc[4][4] = {{0.f,0.f,0.f,0.f},{0.f,0.f,0.f,0.f},{0.f,0.f,0.f,0.f},{0.f,0.f,0.f,0.f}};
    for (int kc=0; kc<ND; kc+=32){
      __syncthreads();
      #pragma unroll
      for (int s=0;s<2;s++){
        int f = tid + (s<<8);
        int r = f >> 3;
        int c = (f & 7) << 2;
        float4 va = *(const float4*)(Ab + (size_t)(nt+r)*ND + kc + c);
        As[r][c]=va.x; As[r][c+1]=va.y; As[r][c+2]=va.z; As[r][c+3]=va.w;
        float4 vb = *(const float4*)(Bb + (size_t)(m0+r)*ND + kc + c);
        Bs[r][c]=vb.x; Bs[r][c+1]=vb.y; Bs[r][c+2]=vb.z; Bs[r][c+3]=vb.w;
      }
      __syncthreads();
      #pragma unroll 4
      for (int k=0;k<32;k++){
        float a0=As[ty*4+0][k], a1=As[ty*4+1][k], a2=As[ty*4+2][k], a3=As[ty*4+3][k];
        float b0=Bs[tx*4+0][k], b1=Bs[tx*4+1][k], b2=Bs[tx*4+2][k], b3=Bs[tx*4+3][k];
        acc[0][0]+=a0*b0; acc[0][1]+=a0*b1; acc[0][2]+=a0*b2; acc[0][3]+=a0*b3;
        acc[1][0]+=a1*b0; acc[1][1]+=a1*b1; acc[1][2]+=a1*b2; acc[1][3]+=a1*b3;
        acc[2][0]+=a2*b0; acc[2][1]+=a2*b1; acc[2][2]+=a2*b2; acc[2][3]+=a2*b3;
        acc[3][0]+=a3*b0; acc[3][1]+=a3*b1; acc[3][2]+=a3*b2; acc[3][3]+=a3*b3;
      }
    }
    float nlv[4];
    #pragma unroll
    for (int i=0;i<4;i++) nlv[i] = nl[b*NN + nt + ty*4 + i];
    __syncthreads();
    #pragma unroll
    for (int i=0;i<4;i++)
      #pragma unroll
      for (int j=0;j<4;j++){
        float denom = fmaxf(nlv[i]*nhv[j], 1e-8f);
        Cs[ty*4+i][tx*4+j] = (acc[i][j]/denom)*0.0625f;
      }
    __syncthreads();
    if (tid < 64){
      float tmax = -INFINITY;
      #pragma unroll 8
      for (int r=0;r<64;r++) tmax = fmaxf(tmax, Cs[r][tid]);
      float newM = fmaxf(Mr, tmax);
      float s = 0.0f;
      #pragma unroll 4
      for (int r=0;r<64;r++) s += expf(Cs[r][tid]-newM);
      Sr = Sr*expf(Mr-newM) + s;
      Mr = newM;
    }
  }
  if (tid < 64){
    Mout[b*NN+m0+tid] = Mr;
    Sinv[b*NN+m0+tid] = 1.0f/Sr;
  }
}

__launch_bounds__(256)
__global__ void kargmax(const float* __restrict__ A, const float* __restrict__ Bm,
                        const float* __restrict__ nl, const float* __restrict__ nh,
                        const float* __restrict__ Mv, const float* __restrict__ Sv,
                        int* __restrict__ idxout){
  __shared__ float As[64][33];
  __shared__ float Bs[64][33];
  __shared__ float Vs[16][64];
  __shared__ int   Is[16][64];
  const int b  = blockIdx.x >> 5;
  const int m0 = (blockIdx.x & 31) << 6;
  const float* Ab = A  + (size_t)b*NN*ND;
  const float* Bb = Bm + (size_t)b*NN*ND;
  const int tid = threadIdx.x;
  const int tx = tid & 15, ty = tid >> 4;
  float nhv[4], Mj[4], iSj[4];
  #pragma unroll
  for (int j=0;j<4;j++){
    int m = m0 + tx*4 + j;
    nhv[j] = nh[b*NN + m];
    Mj[j]  = Mv[b*NN + m];
    iSj[j] = Sv[b*NN + m];
  }
  float bestV = -INFINITY; int bestN = 0;
  for (int nt=0; nt<NN; nt+=64){
    float acc[4][4] = {{0.f,0.f,0.f,0.f},{0.f,0.f,0.f,0.f},{0.f,0.f,0.f,0.f},{0.f,0.f,0.f,0.f}};
    for (int kc=0; kc<ND; kc+=32){
      __syncthreads();
      #pragma unroll
      for (int s=0;s<2;s++){
        int f = tid + (s<<8);
        int r = f >> 3;
        int c = (f & 7) << 2;
        float4 va = *(const float4*)(Ab + (size_t)(nt+r)*ND + kc + c);
        As[r][c]=va.x; As[r][c+1]=va.y; As[r][c+2]=va.z; As[r][c+3]=va.w;
        float4 vb = *(const float4*)(Bb + (size_t)(m0+r)*ND + kc + c);
        Bs[r][c]=vb.x; Bs[r][c+1]=vb.y; Bs[r][c+2]=vb.z; Bs[r][c+3]=vb.w;
      }
      __syncthreads();
      #pragma unroll 4
      for (int k=0;k<32;k++){
        float a0=As[ty*4+0][k], a1=As[ty*4+1][k], a2=As[ty*4+2][k], a3=As[ty*4+3][k];
        float b0=Bs[tx*4+0][k], b1=Bs[tx*4+1][k], b2=Bs[tx*4+2][k], b3=Bs[tx*4+3][k];
        acc[0][0]+=a0*b0; acc[0][1]+=a0*b1; acc[0][2]+=a0*b2; acc[0][3]+=a0*b3;
        acc[1][0]+=a1*b0; acc[1][1]+=a1*b1; acc[1][2]+=a1*b2; acc[1][3]+=a1*b3;
        acc[2][0]+=a2*b0; acc[2][1]+=a2*b1; acc[2][2]+=a2*b2; acc[2][3]+=a2*b3;
        acc[3][0]+=a3*b0; acc[3][1]+=a3*b1; acc[3][2]+=a3*b2; acc[3][3]+=a3*b3;
      }
    }
    float nlv[4];
    #pragma unroll
    for (int i=0;i<4;i++) nlv[i] = nl[b*NN + nt + ty*4 + i];
    float lv[4]; int li[4];
    #pragma unroll
    for (int j=0;j<4;j++){ lv[j] = -INFINITY; li[j] = 0; }
    #pragma unroll
    for (int i=0;i<4;i++){
      int n = nt + ty*4 + i;
      #pragma unroll
      for (int j=0;j<4;j++){
        float denom = fmaxf(nlv[i]*nhv[j], 1e-8f);
        float sim = (acc[i][j]/denom)*0.0625f;
        float p = expf(sim - Mj[j]) * iSj[j];
        float v = p + gumbelv((unsigned)b, (unsigned)n, (unsigned)(m0 + tx*4 + j));
        if (v > lv[j]) { lv[j] = v; li[j] = n; }
      }
    }
    __syncthreads();
    #pragma unroll
    for (int j=0;j<4;j++){ Vs[ty][tx*4+j]=lv[j]; Is[ty][tx*4+j]=li[j]; }
    __syncthreads();
    if (tid < 64){
      #pragma unroll 4
      for (int t=0;t<16;t++){
        float v = Vs[t][tid];
        if (v > bestV){ bestV = v; bestN = Is[t][tid]; }
      }
    }
  }
  if (tid < 64) idxout[b*NN + m0 + tid] = bestN;
}

// ---------------- shared tail kernels ----------------
__global__ void ksort(const int* __restrict__ idx, int* __restrict__ cntg,
                      int* __restrict__ offg, int* __restrict__ sl){
  __shared__ int c[NN];
  __shared__ int part[256];
  int b = blockIdx.x, tid = threadIdx.x;
  for (int v=tid; v<NN; v+=256) c[v]=0;
  __syncthreads();
  for (int j=tid; j<NN; j+=256) atomicAdd(&c[idx[b*NN+j]], 1);
  __syncthreads();
  int base = tid*8, s=0, lc[8];
  #pragma unroll
  for (int k=0;k<8;k++){ lc[k]=c[base+k]; s+=lc[k]; }
  part[tid]=s; __syncthreads();
  for (int o=1;o<256;o<<=1){
    int v = (tid>=o)? part[tid-o] : 0;
    __syncthreads();
    part[tid]+=v;
    __syncthreads();
  }
  int run = part[tid]-s;
  #pragma unroll
  for (int k=0;k<8;k++){
    int v = base+k;
    cntg[b*NN+v]=lc[k];
    offg[b*NN+v]=run;
    for (int j=0;j<lc[k];j++) sl[b*NN+run+j]=v;
    run += lc[k];
  }
}

__global__ void kw(const float* __restrict__ LLF, const float* __restrict__ HLF,
                   const float* __restrict__ nl, const float* __restrict__ nh,
                   const int* __restrict__ sl, float* __restrict__ w){
  int g = blockIdx.x*4 + (threadIdx.x>>6);
  int lane = threadIdx.x & 63;
  int b = g >> 11;
  int s = sl[g];
  float4 a = ((const float4*)(HLF + ((size_t)b*NN + s)*ND))[lane];
  float4 l = ((const float4*)(LLF + (size_t)g*ND))[lane];
  float d = a.x*l.x + a.y*l.y + a.z*l.z + a.w*l.w;
  for (int o=32;o;o>>=1) d += __shfl_down(d,o);
  if (lane==0){
    float denom = fmaxf(nh[b*NN+s]*nl[g], 1e-8f);
    w[g] = d/denom;
  }
}

__global__ void knoise(const float* __restrict__ w, float* __restrict__ nz){
  int b = blockIdx.x, tid = threadIdx.x;
  __shared__ float sred[4];
  float x[8]; float mx = -INFINITY;
  #pragma unroll
  for (int k=0;k<8;k++){ x[k] = w[b*NN + tid*8 + k] / 0.1f; mx = fmaxf(mx, x[k]); }
  for (int o=32;o;o>>=1) mx = fmaxf(mx, __shfl_down(mx,o));
  mx = __shfl(mx, 0);
  if ((tid&63)==0) sred[tid>>6] = mx;
  __syncthreads();
  mx = fmaxf(fmaxf(sred[0],sred[1]), fmaxf(sred[2],sred[3]));
  __syncthreads();
  float e[8]; float s = 0.f;
  #pragma unroll
  for (int k=0;k<8;k++){ e[k] = expf(x[k]-mx); s += e[k]; }
  for (int o=32;o;o>>=1) s += __shfl_down(s,o);
  s = __shfl(s, 0);
  if ((tid&63)==0) sred[tid>>6] = s;
  __syncthreads();
  s = sred[0]+sred[1]+sred[2]+sred[3];
  #pragma unroll
  for (int k=0;k<8;k++) nz[b*NN + tid*8 + k] = e[k]/s;
}

__global__ void kfinal(const float* __restrict__ LLF, const float* __restrict__ HLF,
                       const int* __restrict__ cnt, const int* __restrict__ off,
                       const float* __restrict__ nz, float* __restrict__ out){
  int row = blockIdx.x;
  int lane = threadIdx.x;
  int b = row >> 11;
  float4 h = ((const float4*)(HLF + (size_t)row*ND))[lane];
  int c = cnt[row];
  if (c > 0){
    int i = off[row] + c - 1;
    float ns = nz[b*NN + i];
    float4 l = ((const float4*)(LLF + ((size_t)(b*NN + i))*ND))[lane];
    h.x += l.x*ns; h.y += l.y*ns; h.z += l.z*ns; h.w += l.w*ns;
  }
  ((float4*)(out + (size_t)row*ND))[lane] = h;
}

extern "C" void kernel_launch(void* const* d_in, const int* in_sizes, int n_in,
                              void* d_out, int out_size, void* d_ws, size_t ws_size,
                              hipStream_t stream){
  const float* LLF = (const float*)d_in[0];
  const float* HLF = (const float*)d_in[1];
  float* out = (float*)d_out;
  float* ws = (float*)d_ws;

  // workspace (floats): 9 small arrays + partS[16][BNtot] + pcv/pci[8][16][2048][4]
  float* nl  = ws;
  float* nh  = ws + 1*(size_t)BNtot;
  float* iS  = ws + 2*(size_t)BNtot;
  int*   idx = (int*)(ws + 3*(size_t)BNtot);
  int*   cnt = (int*)(ws + 4*(size_t)BNtot);
  int*   off = (int*)(ws + 5*(size_t)BNtot);
  int*   sl  = (int*)(ws + 6*(size_t)BNtot);
  float* wv  = ws + 7*(size_t)BNtot;
  float* nz  = ws + 8*(size_t)BNtot;
  float* partS = ws + 9*(size_t)BNtot;                 // 16*BNtot
  float* pcv   = partS + 16*(size_t)BNtot;             // 32*BNtot
  int*   pci   = (int*)(pcv + 32*(size_t)BNtot);       // 32*BNtot
  const size_t needBytes = (9 + 16 + 32 + 32) * (size_t)BNtot * 4;   // ~11.7 MB

  hipLaunchKernelGGL(knorms, dim3(BNtot), dim3(128), 0, stream, LLF, HLF, nl, nh);

  if (ws_size >= needBytes){
    hipLaunchKernelGGL(kgemm,    dim3(16,16,16), dim3(256), 0, stream, LLF, HLF, nl, nh, partS);
    hipLaunchKernelGGL(kScomb,   dim3(BNtot/256),dim3(256), 0, stream, partS, iS);
    hipLaunchKernelGGL(kgumbel,  dim3(512),      dim3(256), 0, stream, pcv, pci);
    hipLaunchKernelGGL(kresolve, dim3(BNtot/4),  dim3(256), 0, stream, LLF, HLF, nl, nh, iS, pcv, pci, idx);
  } else {
    float* Mv = ws + 9*(size_t)BNtot;
    hipLaunchKernelGGL(kstats,  dim3(NB*32), dim3(256), 0, stream, LLF, HLF, nl, nh, Mv, iS);
    hipLaunchKernelGGL(kargmax, dim3(NB*32), dim3(256), 0, stream, LLF, HLF, nl, nh, Mv, iS, idx);
  }

  hipLaunchKernelGGL(ksort,  dim3(NB),      dim3(256), 0, stream, idx, cnt, off, sl);
  hipLaunchKernelGGL(kw,     dim3(BNtot/4), dim3(256), 0, stream, LLF, HLF, nl, nh, sl, wv);
  hipLaunchKernelGGL(knoise, dim3(NB),      dim3(256), 0, stream, wv, nz);
  hipLaunchKernelGGL(kfinal, dim3(BNtot),   dim3(64),  0, stream, LLF, HLF, cnt, off, nz, out);
}

// Round 4
// 392.204 us; speedup vs baseline: 5.1110x; 1.8722x over previous
//
#include <hip/hip_runtime.h>
#include <math.h>

#define NB 16
#define NN 2048
#define ND 256
#define BNtot (NB*NN)
#define HH 33554432u   // 2^25 = half of 16*2048*2048 (threefry counter split)

typedef __attribute__((ext_vector_type(8))) short bf16x8;
typedef __attribute__((ext_vector_type(4))) float f32x4;

// ---------------- threefry2x32, bit-exact vs jax.random.key(42) ----------------
__device__ __forceinline__ float gumbelv(unsigned b, unsigned n, unsigned m){
  unsigned f = (b<<22) | (n<<11) | m;
  unsigned x0 = (b < 8u) ? f : (f - HH);
  unsigned x1 = x0 + HH;
  const unsigned ks0=0u, ks1=42u, ks2=0u^42u^0x1BD11BDAu;
  unsigned v0 = x0 + ks0;
  unsigned v1 = x1 + ks1;
#define TFR(r) { v0 += v1; v1 = (v1<<(r))|(v1>>(32-(r))); v1 ^= v0; }
  TFR(13) TFR(15) TFR(26) TFR(6)
  v0 += ks1; v1 += ks2 + 1u;
  TFR(17) TFR(29) TFR(16) TFR(24)
  v0 += ks2; v1 += ks0 + 2u;
  TFR(13) TFR(15) TFR(26) TFR(6)
  v0 += ks0; v1 += ks1 + 3u;
  TFR(17) TFR(29) TFR(16) TFR(24)
  v0 += ks1; v1 += ks2 + 4u;
  TFR(13) TFR(15) TFR(26) TFR(6)
  v0 += ks2; v1 += ks0 + 5u;
#undef TFR
  unsigned bits = (b < 8u) ? v0 : v1;
  float fl = __uint_as_float((bits>>9) | 0x3F800000u) - 1.0f;
  float u = fmaxf(1e-10f, fl + 1e-10f);
  return -logf(-logf(u));
}

// Paired: one threefry eval serves batches bl and bl+8 (counter pair f, f+2^25)
__device__ __forceinline__ float2 gumbel2(unsigned bl, unsigned n, unsigned m){
  unsigned x0 = (bl<<22) | (n<<11) | m;
  unsigned x1 = x0 + HH;
  const unsigned ks0=0u, ks1=42u, ks2=0u^42u^0x1BD11BDAu;
  unsigned v0 = x0 + ks0;
  unsigned v1 = x1 + ks1;
#define TFR(r) { v0 += v1; v1 = (v1<<(r))|(v1>>(32-(r))); v1 ^= v0; }
  TFR(13) TFR(15) TFR(26) TFR(6)
  v0 += ks1; v1 += ks2 + 1u;
  TFR(17) TFR(29) TFR(16) TFR(24)
  v0 += ks2; v1 += ks0 + 2u;
  TFR(13) TFR(15) TFR(26) TFR(6)
  v0 += ks0; v1 += ks1 + 3u;
  TFR(17) TFR(29) TFR(16) TFR(24)
  v0 += ks1; v1 += ks2 + 4u;
  TFR(13) TFR(15) TFR(26) TFR(6)
  v0 += ks2; v1 += ks0 + 5u;
#undef TFR
  float f0 = __uint_as_float((v0>>9) | 0x3F800000u) - 1.0f;
  float f1 = __uint_as_float((v1>>9) | 0x3F800000u) - 1.0f;
  float u0 = fmaxf(1e-10f, f0 + 1e-10f);
  float u1 = fmaxf(1e-10f, f1 + 1e-10f);
  return make_float2(-logf(-logf(u0)), -logf(-logf(u1)));
}

// ---------------- row norms ----------------
__global__ void knorms(const float* __restrict__ LLF, const float* __restrict__ HLF,
                       float* __restrict__ nl, float* __restrict__ nh){
  int row = blockIdx.x;
  int wave = threadIdx.x >> 6;
  int lane = threadIdx.x & 63;
  const float* src = wave ? HLF : LLF;
  float4 v = ((const float4*)(src + (size_t)row*ND))[lane];
  float s = v.x*v.x + v.y*v.y + v.z*v.z + v.w*v.w;
  for (int o=32;o;o>>=1) s += __shfl_down(s,o);
  if (lane==0) (wave? nh: nl)[row] = sqrtf(s);
}

// ---------------- bf16 MFMA GEMM -> column sum-of-exp only ----------------
// S needs only ~1e-3 relative accuracy (it shifts all candidates in a column
// equally; see kresolve). So: truncate fp32->bf16 during staging, MFMA
// 16x16x32_bf16, epilogue computes exp2(acc*(0.0625*log2e/nl)/nh - 0.0625*log2e)
// and reduces column sums. Per-element sims are never materialized.
#define K1 0.09016844f   /* 0.0625 * log2(e) */
__launch_bounds__(256)
__global__ void kgemm_mfma(const float* __restrict__ LLF, const float* __restrict__ HLF,
                           const float* __restrict__ nl, const float* __restrict__ nh,
                           float* __restrict__ partS){
  __shared__ ushort As[128][72];   // [row][k] bf16, stride 144B (16B-aligned, 2-way banks)
  __shared__ ushort Bs[128][72];
  __shared__ float colsum[128];
  const int b  = blockIdx.z;
  const int n0 = blockIdx.y << 7;
  const int m0 = blockIdx.x << 7;
  const float* Ab = LLF + (size_t)b*NN*ND;
  const float* Bb = HLF + (size_t)b*NN*ND;
  const int tid  = threadIdx.x;
  const int lane = tid & 63;
  const int w    = tid >> 6;
  const int wn   = w >> 1, wm = w & 1;     // wave covers n[wn*64..), m[wm*64..)
  const int quad = lane >> 4, l15 = lane & 15;
  if (tid < 128) colsum[tid] = 0.0f;

  f32x4 acc[4][4];
  #pragma unroll
  for (int i=0;i<4;i++)
    #pragma unroll
    for (int j=0;j<4;j++) acc[i][j] = (f32x4){0.f,0.f,0.f,0.f};

  const int rbase = tid >> 3;          // staging row base 0..31
  const int kq    = (tid & 7) << 3;    // k offset 0..56

  for (int ck=0; ck<4; ck++){
    const int k0 = ck << 6;
    __syncthreads();
    #pragma unroll
    for (int pi=0; pi<4; pi++){
      int row = rbase + (pi<<5);
      const float* pa = Ab + (size_t)(n0+row)*ND + k0 + kq;
      float4 a0 = *(const float4*)pa;
      float4 a1 = *(const float4*)(pa+4);
      uint4 ua;
      ua.x = (__float_as_uint(a0.y)&0xFFFF0000u)|(__float_as_uint(a0.x)>>16);
      ua.y = (__float_as_uint(a0.w)&0xFFFF0000u)|(__float_as_uint(a0.z)>>16);
      ua.z = (__float_as_uint(a1.y)&0xFFFF0000u)|(__float_as_uint(a1.x)>>16);
      ua.w = (__float_as_uint(a1.w)&0xFFFF0000u)|(__float_as_uint(a1.z)>>16);
      *(uint4*)(&As[row][kq]) = ua;
      const float* pb = Bb + (size_t)(m0+row)*ND + k0 + kq;
      float4 b0 = *(const float4*)pb;
      float4 b1 = *(const float4*)(pb+4);
      uint4 ub;
      ub.x = (__float_as_uint(b0.y)&0xFFFF0000u)|(__float_as_uint(b0.x)>>16);
      ub.y = (__float_as_uint(b0.w)&0xFFFF0000u)|(__float_as_uint(b0.z)>>16);
      ub.z = (__float_as_uint(b1.y)&0xFFFF0000u)|(__float_as_uint(b1.x)>>16);
      ub.w = (__float_as_uint(b1.w)&0xFFFF0000u)|(__float_as_uint(b1.z)>>16);
      *(uint4*)(&Bs[row][kq]) = ub;
    }
    __syncthreads();
    #pragma unroll
    for (int ks=0; ks<64; ks+=32){
      bf16x8 af[4], bf[4];
      #pragma unroll
      for (int t=0;t<4;t++)
        af[t] = *(const bf16x8*)(&As[wn*64 + t*16 + l15][ks + quad*8]);
      #pragma unroll
      for (int t=0;t<4;t++)
        bf[t] = *(const bf16x8*)(&Bs[wm*64 + t*16 + l15][ks + quad*8]);
      #pragma unroll
      for (int ti=0;ti<4;ti++)
        #pragma unroll
        for (int tj=0;tj<4;tj++)
          acc[ti][tj] = __builtin_amdgcn_mfma_f32_16x16x32_bf16(af[ti], bf[tj], acc[ti][tj], 0, 0, 0);
    }
  }

  // epilogue: D[row=n: quad*4+reg (+ti*16)][col=m: l15 (+tj*16)]  (m89/m91 layout)
  float an[4][4];
  #pragma unroll
  for (int ti=0;ti<4;ti++)
    #pragma unroll
    for (int r=0;r<4;r++)
      an[ti][r] = K1 / nl[b*NN + n0 + wn*64 + ti*16 + quad*4 + r];
  float bm[4];
  #pragma unroll
  for (int tj=0;tj<4;tj++)
    bm[tj] = 1.0f / nh[b*NN + m0 + wm*64 + tj*16 + l15];
  #pragma unroll
  for (int tj=0;tj<4;tj++){
    float s = 0.0f;
    #pragma unroll
    for (int ti=0;ti<4;ti++)
      #pragma unroll
      for (int r=0;r<4;r++)
        s += __builtin_amdgcn_exp2f(acc[ti][tj][r]*an[ti][r]*bm[tj] - K1);
    s += __shfl_down(s, 32);
    s += __shfl_down(s, 16);
    if (lane < 16) atomicAdd(&colsum[wm*64 + tj*16 + l15], s);
  }
  __syncthreads();
  if (tid < 128)
    partS[(size_t)blockIdx.y*BNtot + b*NN + m0 + tid] = colsum[tid];
}

__global__ void kScomb(const float* __restrict__ partS, float* __restrict__ iS){
  int g = blockIdx.x*256 + threadIdx.x;      // b*NN+m
  float s = 0.0f;
  #pragma unroll
  for (int nt=0; nt<16; nt++) s += partS[(size_t)nt*BNtot + g];
  iS[g] = 1.0f/s;
}

// ---------------- gumbel scan: windowed top-4 per (n-chunk, column) ----------------
// Winner needs g >= gmax - 0.1175/S >= gmax - 6.6e-5 (S >= 2048*e^-0.125, data-independent).
#define INS4(v0,v1,v2,v3,i0,i1,i2,i3,gv,nn) \
  if (gv > v3){ \
    if (gv > v1){ \
      v3=v2; i3=i2; v2=v1; i2=i1; \
      if (gv > v0){ v1=v0; i1=i0; v0=gv; i0=nn; } else { v1=gv; i1=nn; } \
    } else { \
      if (gv > v2){ v3=v2; i3=i2; v2=gv; i2=nn; } else { v3=gv; i3=nn; } \
    } \
  }

__global__ void kgumbel(float* __restrict__ pcv, int* __restrict__ pci){
  int t  = blockIdx.x*256 + threadIdx.x;     // 131072 threads
  int m  = t & 2047;
  int bl = (t >> 11) & 7;
  int nq = t >> 14;                          // 0..7, n-chunk of 256
  float a0=-INFINITY,a1=-INFINITY,a2=-INFINITY,a3=-INFINITY;
  float b0=-INFINITY,b1=-INFINITY,b2=-INFINITY,b3=-INFINITY;
  int   ai0=0,ai1=0,ai2=0,ai3=0, bi0=0,bi1=0,bi2=0,bi3=0;
  int nbase = nq << 8;
  for (int k=0;k<256;k++){
    int n = nbase + k;
    float2 g = gumbel2((unsigned)bl, (unsigned)n, (unsigned)m);
    INS4(a0,a1,a2,a3,ai0,ai1,ai2,ai3,g.x,n)
    INS4(b0,b1,b2,b3,bi0,bi1,bi2,bi3,g.y,n)
  }
  int baseA = (((nq*NB + bl  )*NN + m) << 2);
  int baseB = (((nq*NB + bl+8)*NN + m) << 2);
  pcv[baseA+0]=a0; pcv[baseA+1]=a1; pcv[baseA+2]=a2; pcv[baseA+3]=a3;
  pci[baseA+0]=ai0; pci[baseA+1]=ai1; pci[baseA+2]=ai2; pci[baseA+3]=ai3;
  pcv[baseB+0]=b0; pcv[baseB+1]=b1; pcv[baseB+2]=b2; pcv[baseB+3]=b3;
  pci[baseB+0]=bi0; pci[baseB+1]=bi1; pci[baseB+2]=bi2; pci[baseB+3]=bi3;
}

// ---------------- resolve: exact argmax among windowed candidates ----------------
__launch_bounds__(256)
__global__ void kresolve(const float* __restrict__ LLF, const float* __restrict__ HLF,
                         const float* __restrict__ nl, const float* __restrict__ nh,
                         const float* __restrict__ iS,
                         const float* __restrict__ pcv, const int* __restrict__ pci,
                         int* __restrict__ idx){
  int w    = threadIdx.x >> 6;               // wave within block
  int lane = threadIdx.x & 63;
  int g = blockIdx.x*4 + w;                  // b*NN+m
  int b = g >> 11, m = g & 2047;
  float pv = -INFINITY; int pn = 0;
  if (lane < 32){                            // nq = lane>>2, rank j = lane&3
    int base = ((((lane>>2)*NB + b)*NN + m) << 2) + (lane & 3);
    pv = pcv[base]; pn = pci[base];
  }
  float gmax = pv;
  for (int o=32;o;o>>=1) gmax = fmaxf(gmax, __shfl_down(gmax,o));
  gmax = __shfl(gmax, 0);
  unsigned long long mask = __ballot(pv >= gmax - 8e-5f);
  mask &= 0xFFFFFFFFull;
  float invS = iS[g];
  float bestQ = -INFINITY; int bestN = 1<<30;
  while (mask){
    int src = __builtin_ctzll(mask); mask &= mask-1;
    int   n  = __shfl(pn, src);
    float gv = __shfl(pv, src);
    float4 a = ((const float4*)(LLF + ((size_t)b*NN + n)*ND))[lane];
    float4 h = ((const float4*)(HLF + ((size_t)b*NN + m)*ND))[lane];
    float d = a.x*h.x + a.y*h.y + a.z*h.z + a.w*h.w;
    for (int o=32;o;o>>=1) d += __shfl_down(d,o);
    d = __shfl(d, 0);
    float sim = (d / fmaxf(nl[b*NN+n]*nh[g], 1e-8f)) * 0.0625f;
    float q = expf(sim - 0.0625f)*invS + gv;
    if (q > bestQ || (q == bestQ && n < bestN)){ bestQ = q; bestN = n; }
  }
  if (lane==0) idx[g] = bestN;
}

// ---------------- fallback path (only if ws too small; never expected) ----------------
__launch_bounds__(256)
__global__ void kstats(const float* __restrict__ A, const float* __restrict__ Bm,
                       const float* __restrict__ nl, const float* __restrict__ nh,
                       float* __restrict__ Mout, float* __restrict__ Sinv){
  __shared__ float As[64][33];
  __shared__ float Bs[64][33];
  __shared__ float Cs[64][65];
  const int b  = blockIdx.x >> 5;
  const int m0 = (blockIdx.x & 31) << 6;
  const float* Ab = A  + (size_t)b*NN*ND;
  const float* Bb = Bm + (size_t)b*NN*ND;
  const int tid = threadIdx.x;
  const int tx = tid & 15, ty = tid >> 4;
  float nhv[4];
  #pragma unroll
  for (int j=0;j<4;j++) nhv[j] = nh[b*NN + m0 + tx*4 + j];
  float Mr = -INFINITY, Sr = 0.0f;
  for (int nt=0; nt<NN; nt+=64){
    float acc[4][4] = {{0.f,0.f,0.f,0.f},{0.f,0.f,0.f,0.f},{0.f,0.f,0.f,0.f},{0.f,0.f,0.f,0.f}};
    for (int kc=0; kc<ND; kc+=32){
      __syncthreads();
      #pragma unroll
      for (int s=0;s<2;s++){
        int f = tid + (s<<8);
        int r = f >> 3;
        int c = (f & 7) << 2;
        float4 va = *(const float4*)(Ab + (size_t)(nt+r)*ND + kc + c);
        As[r][c]=va.x; As[r][c+1]=va.y; As[r][c+2]=va.z; As[r][c+3]=va.w;
        float4 vb = *(const float4*)(Bb + (size_t)(m0+r)*ND + kc + c);
        Bs[r][c]=vb.x; Bs[r][c+1]=vb.y; Bs[r][c+2]=vb.z; Bs[r][c+3]=vb.w;
      }
      __syncthreads();
      #pragma unroll 4
      for (int k=0;k<32;k++){
        float a0=As[ty*4+0][k], a1=As[ty*4+1][k], a2=As[ty*4+2][k], a3=As[ty*4+3][k];
        float b0=Bs[tx*4+0][k], b1=Bs[tx*4+1][k], b2=Bs[tx*4+2][k], b3=Bs[tx*4+3][k];
        acc[0][0]+=a0*b0; acc[0][1]+=a0*b1; acc[0][2]+=a0*b2; acc[0][3]+=a0*b3;
        acc[1][0]+=a1*b0; acc[1][1]+=a1*b1; acc[1][2]+=a1*b2; acc[1][3]+=a1*b3;
        acc[2][0]+=a2*b0; acc[2][1]+=a2*b1; acc[2][2]+=a2*b2; acc[2][3]+=a2*b3;
        acc[3][0]+=a3*b0; acc[3][1]+=a3*b1; acc[3][2]+=a3*b2; acc[3][3]+=a3*b3;
      }
    }
    float nlv[4];
    #pragma unroll
    for (int i=0;i<4;i++) nlv[i] = nl[b*NN + nt + ty*4 + i];
    __syncthreads();
    #pragma unroll
    for (int i=0;i<4;i++)
      #pragma unroll
      for (int j=0;j<4;j++){
        float denom = fmaxf(nlv[i]*nhv[j], 1e-8f);
        Cs[ty*4+i][tx*4+j] = (acc[i][j]/denom)*0.0625f;
      }
    __syncthreads();
    if (tid < 64){
      float tmax = -INFINITY;
      #pragma unroll 8
      for (int r=0;r<64;r++) tmax = fmaxf(tmax, Cs[r][tid]);
      float newM = fmaxf(Mr, tmax);
      float s = 0.0f;
      #pragma unroll 4
      for (int r=0;r<64;r++) s += expf(Cs[r][tid]-newM);
      Sr = Sr*expf(Mr-newM) + s;
      Mr = newM;
    }
  }
  if (tid < 64){
    Mout[b*NN+m0+tid] = Mr;
    Sinv[b*NN+m0+tid] = 1.0f/Sr;
  }
}

__launch_bounds__(256)
__global__ void kargmax(const float* __restrict__ A, const float* __restrict__ Bm,
                        const float* __restrict__ nl, const float* __restrict__ nh,
                        const float* __restrict__ Mv, const float* __restrict__ Sv,
                        int* __restrict__ idxout){
  __shared__ float As[64][33];
  __shared__ float Bs[64][33];
  __shared__ float Vs[16][64];
  __shared__ int   Is[16][64];
  const int b  = blockIdx.x >> 5;
  const int m0 = (blockIdx.x & 31) << 6;
  const float* Ab = A  + (size_t)b*NN*ND;
  const float* Bb = Bm + (size_t)b*NN*ND;
  const int tid = threadIdx.x;
  const int tx = tid & 15, ty = tid >> 4;
  float nhv[4], Mj[4], iSj[4];
  #pragma unroll
  for (int j=0;j<4;j++){
    int m = m0 + tx*4 + j;
    nhv[j] = nh[b*NN + m];
    Mj[j]  = Mv[b*NN + m];
    iSj[j] = Sv[b*NN + m];
  }
  float bestV = -INFINITY; int bestN = 0;
  for (int nt=0; nt<NN; nt+=64){
    float acc[4][4] = {{0.f,0.f,0.f,0.f},{0.f,0.f,0.f,0.f},{0.f,0.f,0.f,0.f},{0.f,0.f,0.f,0.f}};
    for (int kc=0; kc<ND; kc+=32){
      __syncthreads();
      #pragma unroll
      for (int s=0;s<2;s++){
        int f = tid + (s<<8);
        int r = f >> 3;
        int c = (f & 7) << 2;
        float4 va = *(const float4*)(Ab + (size_t)(nt+r)*ND + kc + c);
        As[r][c]=va.x; As[r][c+1]=va.y; As[r][c+2]=va.z; As[r][c+3]=va.w;
        float4 vb = *(const float4*)(Bb + (size_t)(m0+r)*ND + kc + c);
        Bs[r][c]=vb.x; Bs[r][c+1]=vb.y; Bs[r][c+2]=vb.z; Bs[r][c+3]=vb.w;
      }
      __syncthreads();
      #pragma unroll 4
      for (int k=0;k<32;k++){
        float a0=As[ty*4+0][k], a1=As[ty*4+1][k], a2=As[ty*4+2][k], a3=As[ty*4+3][k];
        float b0=Bs[tx*4+0][k], b1=Bs[tx*4+1][k], b2=Bs[tx*4+2][k], b3=Bs[tx*4+3][k];
        acc[0][0]+=a0*b0; acc[0][1]+=a0*b1; acc[0][2]+=a0*b2; acc[0][3]+=a0*b3;
        acc[1][0]+=a1*b0; acc[1][1]+=a1*b1; acc[1][2]+=a1*b2; acc[1][3]+=a1*b3;
        acc[2][0]+=a2*b0; acc[2][1]+=a2*b1; acc[2][2]+=a2*b2; acc[2][3]+=a2*b3;
        acc[3][0]+=a3*b0; acc[3][1]+=a3*b1; acc[3][2]+=a3*b2; acc[3][3]+=a3*b3;
      }
    }
    float nlv[4];
    #pragma unroll
    for (int i=0;i<4;i++) nlv[i] = nl[b*NN + nt + ty*4 + i];
    float lv[4]; int li[4];
    #pragma unroll
    for (int j=0;j<4;j++){ lv[j] = -INFINITY; li[j] = 0; }
    #pragma unroll
    for (int i=0;i<4;i++){
      int n = nt + ty*4 + i;
      #pragma unroll
      for (int j=0;j<4;j++){
        float denom = fmaxf(nlv[i]*nhv[j], 1e-8f);
        float sim = (acc[i][j]/denom)*0.0625f;
        float p = expf(sim - Mj[j]) * iSj[j];
        float v = p + gumbelv((unsigned)b, (unsigned)n, (unsigned)(m0 + tx*4 + j));
        if (v > lv[j]) { lv[j] = v; li[j] = n; }
      }
    }
    __syncthreads();
    #pragma unroll
    for (int j=0;j<4;j++){ Vs[ty][tx*4+j]=lv[j]; Is[ty][tx*4+j]=li[j]; }
    __syncthreads();
    if (tid < 64){
      #pragma unroll 4
      for (int t=0;t<16;t++){
        float v = Vs[t][tid];
        if (v > bestV){ bestV = v; bestN = Is[t][tid]; }
      }
    }
  }
  if (tid < 64) idxout[b*NN + m0 + tid] = bestN;
}

// ---------------- shared tail kernels ----------------
__global__ void ksort(const int* __restrict__ idx, int* __restrict__ cntg,
                      int* __restrict__ offg, int* __restrict__ sl){
  __shared__ int c[NN];
  __shared__ int part[256];
  int b = blockIdx.x, tid = threadIdx.x;
  for (int v=tid; v<NN; v+=256) c[v]=0;
  __syncthreads();
  for (int j=tid; j<NN; j+=256) atomicAdd(&c[idx[b*NN+j]], 1);
  __syncthreads();
  int base = tid*8, s=0, lc[8];
  #pragma unroll
  for (int k=0;k<8;k++){ lc[k]=c[base+k]; s+=lc[k]; }
  part[tid]=s; __syncthreads();
  for (int o=1;o<256;o<<=1){
    int v = (tid>=o)? part[tid-o] : 0;
    __syncthreads();
    part[tid]+=v;
    __syncthreads();
  }
  int run = part[tid]-s;
  #pragma unroll
  for (int k=0;k<8;k++){
    int v = base+k;
    cntg[b*NN+v]=lc[k];
    offg[b*NN+v]=run;
    for (int j=0;j<lc[k];j++) sl[b*NN+run+j]=v;
    run += lc[k];
  }
}

__global__ void kw(const float* __restrict__ LLF, const float* __restrict__ HLF,
                   const float* __restrict__ nl, const float* __restrict__ nh,
                   const int* __restrict__ sl, float* __restrict__ w){
  int g = blockIdx.x*4 + (threadIdx.x>>6);
  int lane = threadIdx.x & 63;
  int b = g >> 11;
  int s = sl[g];
  float4 a = ((const float4*)(HLF + ((size_t)b*NN + s)*ND))[lane];
  float4 l = ((const float4*)(LLF + (size_t)g*ND))[lane];
  float d = a.x*l.x + a.y*l.y + a.z*l.z + a.w*l.w;
  for (int o=32;o;o>>=1) d += __shfl_down(d,o);
  if (lane==0){
    float denom = fmaxf(nh[b*NN+s]*nl[g], 1e-8f);
    w[g] = d/denom;
  }
}

__global__ void knoise(const float* __restrict__ w, float* __restrict__ nz){
  int b = blockIdx.x, tid = threadIdx.x;
  __shared__ float sred[4];
  float x[8]; float mx = -INFINITY;
  #pragma unroll
  for (int k=0;k<8;k++){ x[k] = w[b*NN + tid*8 + k] / 0.1f; mx = fmaxf(mx, x[k]); }
  for (int o=32;o;o>>=1) mx = fmaxf(mx, __shfl_down(mx,o));
  mx = __shfl(mx, 0);
  if ((tid&63)==0) sred[tid>>6] = mx;
  __syncthreads();
  mx = fmaxf(fmaxf(sred[0],sred[1]), fmaxf(sred[2],sred[3]));
  __syncthreads();
  float e[8]; float s = 0.f;
  #pragma unroll
  for (int k=0;k<8;k++){ e[k] = expf(x[k]-mx); s += e[k]; }
  for (int o=32;o;o>>=1) s += __shfl_down(s,o);
  s = __shfl(s, 0);
  if ((tid&63)==0) sred[tid>>6] = s;
  __syncthreads();
  s = sred[0]+sred[1]+sred[2]+sred[3];
  #pragma unroll
  for (int k=0;k<8;k++) nz[b*NN + tid*8 + k] = e[k]/s;
}

__global__ void kfinal(const float* __restrict__ LLF, const float* __restrict__ HLF,
                       const int* __restrict__ cnt, const int* __restrict__ off,
                       const float* __restrict__ nz, float* __restrict__ out){
  int row = blockIdx.x;
  int lane = threadIdx.x;
  int b = row >> 11;
  float4 h = ((const float4*)(HLF + (size_t)row*ND))[lane];
  int c = cnt[row];
  if (c > 0){
    int i = off[row] + c - 1;
    float ns = nz[b*NN + i];
    float4 l = ((const float4*)(LLF + ((size_t)(b*NN + i))*ND))[lane];
    h.x += l.x*ns; h.y += l.y*ns; h.z += l.z*ns; h.w += l.w*ns;
  }
  ((float4*)(out + (size_t)row*ND))[lane] = h;
}

extern "C" void kernel_launch(void* const* d_in, const int* in_sizes, int n_in,
                              void* d_out, int out_size, void* d_ws, size_t ws_size,
                              hipStream_t stream){
  const float* LLF = (const float*)d_in[0];
  const float* HLF = (const float*)d_in[1];
  float* out = (float*)d_out;
  float* ws = (float*)d_ws;

  // workspace (floats): 9 small arrays + partS[16][BNtot] + pcv/pci[8][16][2048][4]
  float* nl  = ws;
  float* nh  = ws + 1*(size_t)BNtot;
  float* iS  = ws + 2*(size_t)BNtot;
  int*   idx = (int*)(ws + 3*(size_t)BNtot);
  int*   cnt = (int*)(ws + 4*(size_t)BNtot);
  int*   off = (int*)(ws + 5*(size_t)BNtot);
  int*   sl  = (int*)(ws + 6*(size_t)BNtot);
  float* wv  = ws + 7*(size_t)BNtot;
  float* nz  = ws + 8*(size_t)BNtot;
  float* partS = ws + 9*(size_t)BNtot;                 // 16*BNtot
  float* pcv   = partS + 16*(size_t)BNtot;             // 32*BNtot
  int*   pci   = (int*)(pcv + 32*(size_t)BNtot);       // 32*BNtot
  const size_t needBytes = (9 + 16 + 32 + 32) * (size_t)BNtot * 4;   // ~11.7 MB

  hipLaunchKernelGGL(knorms, dim3(BNtot), dim3(128), 0, stream, LLF, HLF, nl, nh);

  if (ws_size >= needBytes){
    hipLaunchKernelGGL(kgemm_mfma, dim3(16,16,16), dim3(256), 0, stream, LLF, HLF, nl, nh, partS);
    hipLaunchKernelGGL(kScomb,   dim3(BNtot/256),dim3(256), 0, stream, partS, iS);
    hipLaunchKernelGGL(kgumbel,  dim3(512),      dim3(256), 0, stream, pcv, pci);
    hipLaunchKernelGGL(kresolve, dim3(BNtot/4),  dim3(256), 0, stream, LLF, HLF, nl, nh, iS, pcv, pci, idx);
  } else {
    float* Mv = ws + 9*(size_t)BNtot;
    hipLaunchKernelGGL(kstats,  dim3(NB*32), dim3(256), 0, stream, LLF, HLF, nl, nh, Mv, iS);
    hipLaunchKernelGGL(kargmax, dim3(NB*32), dim3(256), 0, stream, LLF, HLF, nl, nh, Mv, iS, idx);
  }

  hipLaunchKernelGGL(ksort,  dim3(NB),      dim3(256), 0, stream, idx, cnt, off, sl);
  hipLaunchKernelGGL(kw,     dim3(BNtot/4), dim3(256), 0, stream, LLF, HLF, nl, nh, sl, wv);
  hipLaunchKernelGGL(knoise, dim3(NB),      dim3(256), 0, stream, wv, nz);
  hipLaunchKernelGGL(kfinal, dim3(BNtot),   dim3(64),  0, stream, LLF, HLF, cnt, off, nz, out);
}

// Round 5
// 339.306 us; speedup vs baseline: 5.9078x; 1.1559x over previous
//
#include <hip/hip_runtime.h>
#include <math.h>

#define NB 16
#define NN 2048
#define ND 256
#define BNtot (NB*NN)
#define HH 33554432u   // 2^25 = half of 16*2048*2048 (threefry counter split)

typedef __attribute__((ext_vector_type(8))) short bf16x8;
typedef __attribute__((ext_vector_type(4))) float f32x4;

// ---------------- threefry2x32, bit-exact vs jax.random.key(42) ----------------
__device__ __forceinline__ float gumbelv(unsigned b, unsigned n, unsigned m){
  unsigned f = (b<<22) | (n<<11) | m;
  unsigned x0 = (b < 8u) ? f : (f - HH);
  unsigned x1 = x0 + HH;
  const unsigned ks0=0u, ks1=42u, ks2=0u^42u^0x1BD11BDAu;
  unsigned v0 = x0 + ks0;
  unsigned v1 = x1 + ks1;
#define TFR(r) { v0 += v1; v1 = (v1<<(r))|(v1>>(32-(r))); v1 ^= v0; }
  TFR(13) TFR(15) TFR(26) TFR(6)
  v0 += ks1; v1 += ks2 + 1u;
  TFR(17) TFR(29) TFR(16) TFR(24)
  v0 += ks2; v1 += ks0 + 2u;
  TFR(13) TFR(15) TFR(26) TFR(6)
  v0 += ks0; v1 += ks1 + 3u;
  TFR(17) TFR(29) TFR(16) TFR(24)
  v0 += ks1; v1 += ks2 + 4u;
  TFR(13) TFR(15) TFR(26) TFR(6)
  v0 += ks2; v1 += ks0 + 5u;
#undef TFR
  unsigned bits = (b < 8u) ? v0 : v1;
  float fl = __uint_as_float((bits>>9) | 0x3F800000u) - 1.0f;
  float u = fmaxf(1e-10f, fl + 1e-10f);
  return -logf(-logf(u));
}

// Paired raw-bits version: one threefry eval serves batches bl and bl+8
__device__ __forceinline__ uint2 three2(unsigned bl, unsigned n, unsigned m){
  unsigned x0 = (bl<<22) | (n<<11) | m;
  unsigned x1 = x0 + HH;
  const unsigned ks0=0u, ks1=42u, ks2=0u^42u^0x1BD11BDAu;
  unsigned v0 = x0 + ks0;
  unsigned v1 = x1 + ks1;
#define TFR(r) { v0 += v1; v1 = (v1<<(r))|(v1>>(32-(r))); v1 ^= v0; }
  TFR(13) TFR(15) TFR(26) TFR(6)
  v0 += ks1; v1 += ks2 + 1u;
  TFR(17) TFR(29) TFR(16) TFR(24)
  v0 += ks2; v1 += ks0 + 2u;
  TFR(13) TFR(15) TFR(26) TFR(6)
  v0 += ks0; v1 += ks1 + 3u;
  TFR(17) TFR(29) TFR(16) TFR(24)
  v0 += ks1; v1 += ks2 + 4u;
  TFR(13) TFR(15) TFR(26) TFR(6)
  v0 += ks2; v1 += ks0 + 5u;
#undef TFR
  return make_uint2(v0, v1);
}

// g from 23-bit key, exactly as JAX: fl = as_float(key|0x3f800000)-1
__device__ __forceinline__ float gfromkey(unsigned key){
  float fl = __uint_as_float(key | 0x3F800000u) - 1.0f;
  float u = fmaxf(1e-10f, fl + 1e-10f);
  return -logf(-logf(u));
}

// ---------------- row norms ----------------
__global__ void knorms(const float* __restrict__ LLF, const float* __restrict__ HLF,
                       float* __restrict__ nl, float* __restrict__ nh){
  int row = blockIdx.x;
  int wave = threadIdx.x >> 6;
  int lane = threadIdx.x & 63;
  const float* src = wave ? HLF : LLF;
  float4 v = ((const float4*)(src + (size_t)row*ND))[lane];
  float s = v.x*v.x + v.y*v.y + v.z*v.z + v.w*v.w;
  for (int o=32;o;o>>=1) s += __shfl_down(s,o);
  if (lane==0) (wave? nh: nl)[row] = sqrtf(s);
}

// ---------------- bf16 MFMA GEMM -> column sum-of-exp only ----------------
#define K1 0.09016844f   /* 0.0625 * log2(e) */
__launch_bounds__(256)
__global__ void kgemm_mfma(const float* __restrict__ LLF, const float* __restrict__ HLF,
                           const float* __restrict__ nl, const float* __restrict__ nh,
                           float* __restrict__ partS){
  __shared__ ushort As[128][72];   // [row][k] bf16, stride 144B
  __shared__ ushort Bs[128][72];
  __shared__ float colsum[128];
  const int b  = blockIdx.z;
  const int n0 = blockIdx.y << 7;
  const int m0 = blockIdx.x << 7;
  const float* Ab = LLF + (size_t)b*NN*ND;
  const float* Bb = HLF + (size_t)b*NN*ND;
  const int tid  = threadIdx.x;
  const int lane = tid & 63;
  const int w    = tid >> 6;
  const int wn   = w >> 1, wm = w & 1;
  const int quad = lane >> 4, l15 = lane & 15;
  if (tid < 128) colsum[tid] = 0.0f;

  f32x4 acc[4][4];
  #pragma unroll
  for (int i=0;i<4;i++)
    #pragma unroll
    for (int j=0;j<4;j++) acc[i][j] = (f32x4){0.f,0.f,0.f,0.f};

  const int rbase = tid >> 3;
  const int kq    = (tid & 7) << 3;

  for (int ck=0; ck<4; ck++){
    const int k0 = ck << 6;
    __syncthreads();
    #pragma unroll
    for (int pi=0; pi<4; pi++){
      int row = rbase + (pi<<5);
      const float* pa = Ab + (size_t)(n0+row)*ND + k0 + kq;
      float4 a0 = *(const float4*)pa;
      float4 a1 = *(const float4*)(pa+4);
      uint4 ua;
      ua.x = (__float_as_uint(a0.y)&0xFFFF0000u)|(__float_as_uint(a0.x)>>16);
      ua.y = (__float_as_uint(a0.w)&0xFFFF0000u)|(__float_as_uint(a0.z)>>16);
      ua.z = (__float_as_uint(a1.y)&0xFFFF0000u)|(__float_as_uint(a1.x)>>16);
      ua.w = (__float_as_uint(a1.w)&0xFFFF0000u)|(__float_as_uint(a1.z)>>16);
      *(uint4*)(&As[row][kq]) = ua;
      const float* pb = Bb + (size_t)(m0+row)*ND + k0 + kq;
      float4 b0 = *(const float4*)pb;
      float4 b1 = *(const float4*)(pb+4);
      uint4 ub;
      ub.x = (__float_as_uint(b0.y)&0xFFFF0000u)|(__float_as_uint(b0.x)>>16);
      ub.y = (__float_as_uint(b0.w)&0xFFFF0000u)|(__float_as_uint(b0.z)>>16);
      ub.z = (__float_as_uint(b1.y)&0xFFFF0000u)|(__float_as_uint(b1.x)>>16);
      ub.w = (__float_as_uint(b1.w)&0xFFFF0000u)|(__float_as_uint(b1.z)>>16);
      *(uint4*)(&Bs[row][kq]) = ub;
    }
    __syncthreads();
    #pragma unroll
    for (int ks=0; ks<64; ks+=32){
      bf16x8 af[4], bf[4];
      #pragma unroll
      for (int t=0;t<4;t++)
        af[t] = *(const bf16x8*)(&As[wn*64 + t*16 + l15][ks + quad*8]);
      #pragma unroll
      for (int t=0;t<4;t++)
        bf[t] = *(const bf16x8*)(&Bs[wm*64 + t*16 + l15][ks + quad*8]);
      #pragma unroll
      for (int ti=0;ti<4;ti++)
        #pragma unroll
        for (int tj=0;tj<4;tj++)
          acc[ti][tj] = __builtin_amdgcn_mfma_f32_16x16x32_bf16(af[ti], bf[tj], acc[ti][tj], 0, 0, 0);
    }
  }

  float an[4][4];
  #pragma unroll
  for (int ti=0;ti<4;ti++)
    #pragma unroll
    for (int r=0;r<4;r++)
      an[ti][r] = K1 / nl[b*NN + n0 + wn*64 + ti*16 + quad*4 + r];
  float bm[4];
  #pragma unroll
  for (int tj=0;tj<4;tj++)
    bm[tj] = 1.0f / nh[b*NN + m0 + wm*64 + tj*16 + l15];
  #pragma unroll
  for (int tj=0;tj<4;tj++){
    float s = 0.0f;
    #pragma unroll
    for (int ti=0;ti<4;ti++)
      #pragma unroll
      for (int r=0;r<4;r++)
        s += __builtin_amdgcn_exp2f(acc[ti][tj][r]*an[ti][r]*bm[tj] - K1);
    s += __shfl_down(s, 32);
    s += __shfl_down(s, 16);
    if (lane < 16) atomicAdd(&colsum[wm*64 + tj*16 + l15], s);
  }
  __syncthreads();
  if (tid < 128)
    partS[(size_t)blockIdx.y*BNtot + b*NN + m0 + tid] = colsum[tid];
}

__global__ void kScomb(const float* __restrict__ partS, float* __restrict__ iS){
  int g = blockIdx.x*256 + threadIdx.x;      // b*NN+m
  float s = 0.0f;
  #pragma unroll
  for (int nt=0; nt<16; nt++) s += partS[(size_t)nt*BNtot + g];
  iS[g] = 1.0f/s;
}

// ---------------- gumbel scan: integer-key windowed top-4 ----------------
// g = -log(-log(u)) is monotone in the 23-bit key (bits>>9), with identical
// equivalence classes (equal key <=> equal g). So the top-4 window is selected
// with integer compares; the expensive double-log runs only on the 4 survivors.
#define INS4U(v0,v1,v2,v3,i0,i1,i2,i3,gv,nn) \
  if (gv > v3){ \
    if (gv > v1){ \
      v3=v2; i3=i2; v2=v1; i2=i1; \
      if (gv > v0){ v1=v0; i1=i0; v0=gv; i0=nn; } else { v1=gv; i1=nn; } \
    } else { \
      if (gv > v2){ v3=v2; i3=i2; v2=gv; i2=nn; } else { v3=gv; i3=nn; } \
    } \
  }

__global__ void kgumbel(float* __restrict__ pcv, int* __restrict__ pci){
  int t  = blockIdx.x*256 + threadIdx.x;     // 131072 threads
  int m  = t & 2047;
  int bl = (t >> 11) & 7;
  int nq = t >> 14;                          // 0..7, n-chunk of 256
  int nbase = nq << 8;
  // keys init 0: a real key 0 maps to the minimal gumbel (never a winner)
  unsigned a0=0,a1=0,a2=0,a3=0, c0=0,c1=0,c2=0,c3=0;
  int ai0=nbase,ai1=nbase,ai2=nbase,ai3=nbase;
  int bi0=nbase,bi1=nbase,bi2=nbase,bi3=nbase;
  #pragma unroll 2
  for (int k=0;k<256;k++){
    int n = nbase + k;
    uint2 r = three2((unsigned)bl, (unsigned)n, (unsigned)m);
    unsigned ka = r.x >> 9, kb = r.y >> 9;
    INS4U(a0,a1,a2,a3,ai0,ai1,ai2,ai3,ka,n)
    INS4U(c0,c1,c2,c3,bi0,bi1,bi2,bi3,kb,n)
  }
  int baseA = (((nq*NB + bl  )*NN + m) << 2);
  int baseB = (((nq*NB + bl+8)*NN + m) << 2);
  pcv[baseA+0]=gfromkey(a0); pcv[baseA+1]=gfromkey(a1);
  pcv[baseA+2]=gfromkey(a2); pcv[baseA+3]=gfromkey(a3);
  pci[baseA+0]=ai0; pci[baseA+1]=ai1; pci[baseA+2]=ai2; pci[baseA+3]=ai3;
  pcv[baseB+0]=gfromkey(c0); pcv[baseB+1]=gfromkey(c1);
  pcv[baseB+2]=gfromkey(c2); pcv[baseB+3]=gfromkey(c3);
  pci[baseB+0]=bi0; pci[baseB+1]=bi1; pci[baseB+2]=bi2; pci[baseB+3]=bi3;
}

// ---------------- resolve: exact argmax among windowed candidates ----------------
__launch_bounds__(256)
__global__ void kresolve(const float* __restrict__ LLF, const float* __restrict__ HLF,
                         const float* __restrict__ nl, const float* __restrict__ nh,
                         const float* __restrict__ iS,
                         const float* __restrict__ pcv, const int* __restrict__ pci,
                         int* __restrict__ idx){
  int w    = threadIdx.x >> 6;               // wave within block
  int lane = threadIdx.x & 63;
  int g = blockIdx.x*4 + w;                  // b*NN+m
  int b = g >> 11, m = g & 2047;
  float pv = -INFINITY; int pn = 0;
  if (lane < 32){                            // nq = lane>>2, rank j = lane&3
    int base = ((((lane>>2)*NB + b)*NN + m) << 2) + (lane & 3);
    pv = pcv[base]; pn = pci[base];
  }
  float gmax = pv;
  for (int o=32;o;o>>=1) gmax = fmaxf(gmax, __shfl_down(gmax,o));
  gmax = __shfl(gmax, 0);
  unsigned long long mask = __ballot(pv >= gmax - 8e-5f);
  mask &= 0xFFFFFFFFull;
  float invS = iS[g];
  float bestQ = -INFINITY; int bestN = 1<<30;
  while (mask){
    int src = __builtin_ctzll(mask); mask &= mask-1;
    int   n  = __shfl(pn, src);
    float gv = __shfl(pv, src);
    float4 a = ((const float4*)(LLF + ((size_t)b*NN + n)*ND))[lane];
    float4 h = ((const float4*)(HLF + ((size_t)b*NN + m)*ND))[lane];
    float d = a.x*h.x + a.y*h.y + a.z*h.z + a.w*h.w;
    for (int o=32;o;o>>=1) d += __shfl_down(d,o);
    d = __shfl(d, 0);
    float sim = (d / fmaxf(nl[b*NN+n]*nh[g], 1e-8f)) * 0.0625f;
    float q = expf(sim - 0.0625f)*invS + gv;
    if (q > bestQ || (q == bestQ && n < bestN)){ bestQ = q; bestN = n; }
  }
  if (lane==0) idx[g] = bestN;
}

// ---------------- fallback path (only if ws too small; never expected) ----------------
__launch_bounds__(256)
__global__ void kstats(const float* __restrict__ A, const float* __restrict__ Bm,
                       const float* __restrict__ nl, const float* __restrict__ nh,
                       float* __restrict__ Mout, float* __restrict__ Sinv){
  __shared__ float As[64][33];
  __shared__ float Bs[64][33];
  __shared__ float Cs[64][65];
  const int b  = blockIdx.x >> 5;
  const int m0 = (blockIdx.x & 31) << 6;
  const float* Ab = A  + (size_t)b*NN*ND;
  const float* Bb = Bm + (size_t)b*NN*ND;
  const int tid = threadIdx.x;
  const int tx = tid & 15, ty = tid >> 4;
  float nhv[4];
  #pragma unroll
  for (int j=0;j<4;j++) nhv[j] = nh[b*NN + m0 + tx*4 + j];
  float Mr = -INFINITY, Sr = 0.0f;
  for (int nt=0; nt<NN; nt+=64){
    float acc[4][4] = {{0.f,0.f,0.f,0.f},{0.f,0.f,0.f,0.f},{0.f,0.f,0.f,0.f},{0.f,0.f,0.f,0.f}};
    for (int kc=0; kc<ND; kc+=32){
      __syncthreads();
      #pragma unroll
      for (int s=0;s<2;s++){
        int f = tid + (s<<8);
        int r = f >> 3;
        int c = (f & 7) << 2;
        float4 va = *(const float4*)(Ab + (size_t)(nt+r)*ND + kc + c);
        As[r][c]=va.x; As[r][c+1]=va.y; As[r][c+2]=va.z; As[r][c+3]=va.w;
        float4 vb = *(const float4*)(Bb + (size_t)(m0+r)*ND + kc + c);
        Bs[r][c]=vb.x; Bs[r][c+1]=vb.y; Bs[r][c+2]=vb.z; Bs[r][c+3]=vb.w;
      }
      __syncthreads();
      #pragma unroll 4
      for (int k=0;k<32;k++){
        float a0=As[ty*4+0][k], a1=As[ty*4+1][k], a2=As[ty*4+2][k], a3=As[ty*4+3][k];
        float b0=Bs[tx*4+0][k], b1=Bs[tx*4+1][k], b2=Bs[tx*4+2][k], b3=Bs[tx*4+3][k];
        acc[0][0]+=a0*b0; acc[0][1]+=a0*b1; acc[0][2]+=a0*b2; acc[0][3]+=a0*b3;
        acc[1][0]+=a1*b0; acc[1][1]+=a1*b1; acc[1][2]+=a1*b2; acc[1][3]+=a1*b3;
        acc[2][0]+=a2*b0; acc[2][1]+=a2*b1; acc[2][2]+=a2*b2; acc[2][3]+=a2*b3;
        acc[3][0]+=a3*b0; acc[3][1]+=a3*b1; acc[3][2]+=a3*b2; acc[3][3]+=a3*b3;
      }
    }
    float nlv[4];
    #pragma unroll
    for (int i=0;i<4;i++) nlv[i] = nl[b*NN + nt + ty*4 + i];
    __syncthreads();
    #pragma unroll
    for (int i=0;i<4;i++)
      #pragma unroll
      for (int j=0;j<4;j++){
        float denom = fmaxf(nlv[i]*nhv[j], 1e-8f);
        Cs[ty*4+i][tx*4+j] = (acc[i][j]/denom)*0.0625f;
      }
    __syncthreads();
    if (tid < 64){
      float tmax = -INFINITY;
      #pragma unroll 8
      for (int r=0;r<64;r++) tmax = fmaxf(tmax, Cs[r][tid]);
      float newM = fmaxf(Mr, tmax);
      float s = 0.0f;
      #pragma unroll 4
      for (int r=0;r<64;r++) s += expf(Cs[r][tid]-newM);
      Sr = Sr*expf(Mr-newM) + s;
      Mr = newM;
    }
  }
  if (tid < 64){
    Mout[b*NN+m0+tid] = Mr;
    Sinv[b*NN+m0+tid] = 1.0f/Sr;
  }
}

__launch_bounds__(256)
__global__ void kargmax(const float* __restrict__ A, const float* __restrict__ Bm,
                        const float* __restrict__ nl, const float* __restrict__ nh,
                        const float* __restrict__ Mv, const float* __restrict__ Sv,
                        int* __restrict__ idxout){
  __shared__ float As[64][33];
  __shared__ float Bs[64][33];
  __shared__ float Vs[16][64];
  __shared__ int   Is[16][64];
  const int b  = blockIdx.x >> 5;
  const int m0 = (blockIdx.x & 31) << 6;
  const float* Ab = A  + (size_t)b*NN*ND;
  const float* Bb = Bm + (size_t)b*NN*ND;
  const int tid = threadIdx.x;
  const int tx = tid & 15, ty = tid >> 4;
  float nhv[4], Mj[4], iSj[4];
  #pragma unroll
  for (int j=0;j<4;j++){
    int m = m0 + tx*4 + j;
    nhv[j] = nh[b*NN + m];
    Mj[j]  = Mv[b*NN + m];
    iSj[j] = Sv[b*NN + m];
  }
  float bestV = -INFINITY; int bestN = 0;
  for (int nt=0; nt<NN; nt+=64){
    float acc[4][4] = {{0.f,0.f,0.f,0.f},{0.f,0.f,0.f,0.f},{0.f,0.f,0.f,0.f},{0.f,0.f,0.f,0.f}};
    for (int kc=0; kc<ND; kc+=32){
      __syncthreads();
      #pragma unroll
      for (int s=0;s<2;s++){
        int f = tid + (s<<8);
        int r = f >> 3;
        int c = (f & 7) << 2;
        float4 va = *(const float4*)(Ab + (size_t)(nt+r)*ND + kc + c);
        As[r][c]=va.x; As[r][c+1]=va.y; As[r][c+2]=va.z; As[r][c+3]=va.w;
        float4 vb = *(const float4*)(Bb + (size_t)(m0+r)*ND + kc + c);
        Bs[r][c]=vb.x; Bs[r][c+1]=vb.y; Bs[r][c+2]=vb.z; Bs[r][c+3]=vb.w;
      }
      __syncthreads();
      #pragma unroll 4
      for (int k=0;k<32;k++){
        float a0=As[ty*4+0][k], a1=As[ty*4+1][k], a2=As[ty*4+2][k], a3=As[ty*4+3][k];
        float b0=Bs[tx*4+0][k], b1=Bs[tx*4+1][k], b2=Bs[tx*4+2][k], b3=Bs[tx*4+3][k];
        acc[0][0]+=a0*b0; acc[0][1]+=a0*b1; acc[0][2]+=a0*b2; acc[0][3]+=a0*b3;
        acc[1][0]+=a1*b0; acc[1][1]+=a1*b1; acc[1][2]+=a1*b2; acc[1][3]+=a1*b3;
        acc[2][0]+=a2*b0; acc[2][1]+=a2*b1; acc[2][2]+=a2*b2; acc[2][3]+=a2*b3;
        acc[3][0]+=a3*b0; acc[3][1]+=a3*b1; acc[3][2]+=a3*b2; acc[3][3]+=a3*b3;
      }
    }
    float nlv[4];
    #pragma unroll
    for (int i=0;i<4;i++) nlv[i] = nl[b*NN + nt + ty*4 + i];
    float lv[4]; int li[4];
    #pragma unroll
    for (int j=0;j<4;j++){ lv[j] = -INFINITY; li[j] = 0; }
    #pragma unroll
    for (int i=0;i<4;i++){
      int n = nt + ty*4 + i;
      #pragma unroll
      for (int j=0;j<4;j++){
        float denom = fmaxf(nlv[i]*nhv[j], 1e-8f);
        float sim = (acc[i][j]/denom)*0.0625f;
        float p = expf(sim - Mj[j]) * iSj[j];
        float v = p + gumbelv((unsigned)b, (unsigned)n, (unsigned)(m0 + tx*4 + j));
        if (v > lv[j]) { lv[j] = v; li[j] = n; }
      }
    }
    __syncthreads();
    #pragma unroll
    for (int j=0;j<4;j++){ Vs[ty][tx*4+j]=lv[j]; Is[ty][tx*4+j]=li[j]; }
    __syncthreads();
    if (tid < 64){
      #pragma unroll 4
      for (int t=0;t<16;t++){
        float v = Vs[t][tid];
        if (v > bestV){ bestV = v; bestN = Is[t][tid]; }
      }
    }
  }
  if (tid < 64) idxout[b*NN + m0 + tid] = bestN;
}

// ---------------- shared tail kernels ----------------
__global__ void ksort(const int* __restrict__ idx, int* __restrict__ cntg,
                      int* __restrict__ offg, int* __restrict__ sl){
  __shared__ int c[NN];
  __shared__ int part[256];
  int b = blockIdx.x, tid = threadIdx.x;
  for (int v=tid; v<NN; v+=256) c[v]=0;
  __syncthreads();
  for (int j=tid; j<NN; j+=256) atomicAdd(&c[idx[b*NN+j]], 1);
  __syncthreads();
  int base = tid*8, s=0, lc[8];
  #pragma unroll
  for (int k=0;k<8;k++){ lc[k]=c[base+k]; s+=lc[k]; }
  part[tid]=s; __syncthreads();
  for (int o=1;o<256;o<<=1){
    int v = (tid>=o)? part[tid-o] : 0;
    __syncthreads();
    part[tid]+=v;
    __syncthreads();
  }
  int run = part[tid]-s;
  #pragma unroll
  for (int k=0;k<8;k++){
    int v = base+k;
    cntg[b*NN+v]=lc[k];
    offg[b*NN+v]=run;
    for (int j=0;j<lc[k];j++) sl[b*NN+run+j]=v;
    run += lc[k];
  }
}

__global__ void kw(const float* __restrict__ LLF, const float* __restrict__ HLF,
                   const float* __restrict__ nl, const float* __restrict__ nh,
                   const int* __restrict__ sl, float* __restrict__ w){
  int g = blockIdx.x*4 + (threadIdx.x>>6);
  int lane = threadIdx.x & 63;
  int b = g >> 11;
  int s = sl[g];
  float4 a = ((const float4*)(HLF + ((size_t)b*NN + s)*ND))[lane];
  float4 l = ((const float4*)(LLF + (size_t)g*ND))[lane];
  float d = a.x*l.x + a.y*l.y + a.z*l.z + a.w*l.w;
  for (int o=32;o;o>>=1) d += __shfl_down(d,o);
  if (lane==0){
    float denom = fmaxf(nh[b*NN+s]*nl[g], 1e-8f);
    w[g] = d/denom;
  }
}

__global__ void knoise(const float* __restrict__ w, float* __restrict__ nz){
  int b = blockIdx.x, tid = threadIdx.x;
  __shared__ float sred[4];
  float x[8]; float mx = -INFINITY;
  #pragma unroll
  for (int k=0;k<8;k++){ x[k] = w[b*NN + tid*8 + k] / 0.1f; mx = fmaxf(mx, x[k]); }
  for (int o=32;o;o>>=1) mx = fmaxf(mx, __shfl_down(mx,o));
  mx = __shfl(mx, 0);
  if ((tid&63)==0) sred[tid>>6] = mx;
  __syncthreads();
  mx = fmaxf(fmaxf(sred[0],sred[1]), fmaxf(sred[2],sred[3]));
  __syncthreads();
  float e[8]; float s = 0.f;
  #pragma unroll
  for (int k=0;k<8;k++){ e[k] = expf(x[k]-mx); s += e[k]; }
  for (int o=32;o;o>>=1) s += __shfl_down(s,o);
  s = __shfl(s, 0);
  if ((tid&63)==0) sred[tid>>6] = s;
  __syncthreads();
  s = sred[0]+sred[1]+sred[2]+sred[3];
  #pragma unroll
  for (int k=0;k<8;k++) nz[b*NN + tid*8 + k] = e[k]/s;
}

__global__ void kfinal(const float* __restrict__ LLF, const float* __restrict__ HLF,
                       const int* __restrict__ cnt, const int* __restrict__ off,
                       const float* __restrict__ nz, float* __restrict__ out){
  int row = blockIdx.x;
  int lane = threadIdx.x;
  int b = row >> 11;
  float4 h = ((const float4*)(HLF + (size_t)row*ND))[lane];
  int c = cnt[row];
  if (c > 0){
    int i = off[row] + c - 1;
    float ns = nz[b*NN + i];
    float4 l = ((const float4*)(LLF + ((size_t)(b*NN + i))*ND))[lane];
    h.x += l.x*ns; h.y += l.y*ns; h.z += l.z*ns; h.w += l.w*ns;
  }
  ((float4*)(out + (size_t)row*ND))[lane] = h;
}

extern "C" void kernel_launch(void* const* d_in, const int* in_sizes, int n_in,
                              void* d_out, int out_size, void* d_ws, size_t ws_size,
                              hipStream_t stream){
  const float* LLF = (const float*)d_in[0];
  const float* HLF = (const float*)d_in[1];
  float* out = (float*)d_out;
  float* ws = (float*)d_ws;

  float* nl  = ws;
  float* nh  = ws + 1*(size_t)BNtot;
  float* iS  = ws + 2*(size_t)BNtot;
  int*   idx = (int*)(ws + 3*(size_t)BNtot);
  int*   cnt = (int*)(ws + 4*(size_t)BNtot);
  int*   off = (int*)(ws + 5*(size_t)BNtot);
  int*   sl  = (int*)(ws + 6*(size_t)BNtot);
  float* wv  = ws + 7*(size_t)BNtot;
  float* nz  = ws + 8*(size_t)BNtot;
  float* partS = ws + 9*(size_t)BNtot;                 // 16*BNtot
  float* pcv   = partS + 16*(size_t)BNtot;             // 32*BNtot
  int*   pci   = (int*)(pcv + 32*(size_t)BNtot);       // 32*BNtot
  const size_t needBytes = (9 + 16 + 32 + 32) * (size_t)BNtot * 4;   // ~11.7 MB

  hipLaunchKernelGGL(knorms, dim3(BNtot), dim3(128), 0, stream, LLF, HLF, nl, nh);

  if (ws_size >= needBytes){
    hipLaunchKernelGGL(kgemm_mfma, dim3(16,16,16), dim3(256), 0, stream, LLF, HLF, nl, nh, partS);
    hipLaunchKernelGGL(kScomb,   dim3(BNtot/256),dim3(256), 0, stream, partS, iS);
    hipLaunchKernelGGL(kgumbel,  dim3(512),      dim3(256), 0, stream, pcv, pci);
    hipLaunchKernelGGL(kresolve, dim3(BNtot/4),  dim3(256), 0, stream, LLF, HLF, nl, nh, iS, pcv, pci, idx);
  } else {
    float* Mv = ws + 9*(size_t)BNtot;
    hipLaunchKernelGGL(kstats,  dim3(NB*32), dim3(256), 0, stream, LLF, HLF, nl, nh, Mv, iS);
    hipLaunchKernelGGL(kargmax, dim3(NB*32), dim3(256), 0, stream, LLF, HLF, nl, nh, Mv, iS, idx);
  }

  hipLaunchKernelGGL(ksort,  dim3(NB),      dim3(256), 0, stream, idx, cnt, off, sl);
  hipLaunchKernelGGL(kw,     dim3(BNtot/4), dim3(256), 0, stream, LLF, HLF, nl, nh, sl, wv);
  hipLaunchKernelGGL(knoise, dim3(NB),      dim3(256), 0, stream, wv, nz);
  hipLaunchKernelGGL(kfinal, dim3(BNtot),   dim3(64),  0, stream, LLF, HLF, cnt, off, nz, out);
}

// Round 6
// 321.345 us; speedup vs baseline: 6.2380x; 1.0559x over previous
//
#include <hip/hip_runtime.h>
#include <math.h>

#define NB 16
#define NN 2048
#define ND 256
#define BNtot (NB*NN)
#define HH 33554432u   // 2^25 = half of 16*2048*2048 (threefry counter split)

typedef __attribute__((ext_vector_type(8))) short bf16x8;
typedef __attribute__((ext_vector_type(4))) float f32x4;

// ---------------- threefry2x32, bit-exact vs jax.random.key(42) ----------------
__device__ __forceinline__ float gumbelv(unsigned b, unsigned n, unsigned m){
  unsigned f = (b<<22) | (n<<11) | m;
  unsigned x0 = (b < 8u) ? f : (f - HH);
  unsigned x1 = x0 + HH;
  const unsigned ks0=0u, ks1=42u, ks2=0u^42u^0x1BD11BDAu;
  unsigned v0 = x0 + ks0;
  unsigned v1 = x1 + ks1;
#define TFR(r) { v0 += v1; v1 = __builtin_rotateleft32(v1,(r)); v1 ^= v0; }
  TFR(13) TFR(15) TFR(26) TFR(6)
  v0 += ks1; v1 += ks2 + 1u;
  TFR(17) TFR(29) TFR(16) TFR(24)
  v0 += ks2; v1 += ks0 + 2u;
  TFR(13) TFR(15) TFR(26) TFR(6)
  v0 += ks0; v1 += ks1 + 3u;
  TFR(17) TFR(29) TFR(16) TFR(24)
  v0 += ks1; v1 += ks2 + 4u;
  TFR(13) TFR(15) TFR(26) TFR(6)
  v0 += ks2; v1 += ks0 + 5u;
#undef TFR
  unsigned bits = (b < 8u) ? v0 : v1;
  float fl = __uint_as_float((bits>>9) | 0x3F800000u) - 1.0f;
  float u = fmaxf(1e-10f, fl + 1e-10f);
  return -logf(-logf(u));
}

// Paired raw-bits version: one threefry eval serves batches bl and bl+8
__device__ __forceinline__ uint2 three2(unsigned bl, unsigned n, unsigned m){
  unsigned x0 = (bl<<22) | (n<<11) | m;
  unsigned x1 = x0 + HH;
  const unsigned ks0=0u, ks1=42u, ks2=0u^42u^0x1BD11BDAu;
  unsigned v0 = x0 + ks0;
  unsigned v1 = x1 + ks1;
#define TFR(r) { v0 += v1; v1 = __builtin_rotateleft32(v1,(r)); v1 ^= v0; }
  TFR(13) TFR(15) TFR(26) TFR(6)
  v0 += ks1; v1 += ks2 + 1u;
  TFR(17) TFR(29) TFR(16) TFR(24)
  v0 += ks2; v1 += ks0 + 2u;
  TFR(13) TFR(15) TFR(26) TFR(6)
  v0 += ks0; v1 += ks1 + 3u;
  TFR(17) TFR(29) TFR(16) TFR(24)
  v0 += ks1; v1 += ks2 + 4u;
  TFR(13) TFR(15) TFR(26) TFR(6)
  v0 += ks2; v1 += ks0 + 5u;
#undef TFR
  return make_uint2(v0, v1);
}

// g from 23-bit key, exactly as JAX: fl = as_float(key|0x3f800000)-1
__device__ __forceinline__ float gfromkey(unsigned key){
  float fl = __uint_as_float(key | 0x3F800000u) - 1.0f;
  float u = fmaxf(1e-10f, fl + 1e-10f);
  return -logf(-logf(u));
}

// ---------------- row norms ----------------
__global__ void knorms(const float* __restrict__ LLF, const float* __restrict__ HLF,
                       float* __restrict__ nl, float* __restrict__ nh){
  int row = blockIdx.x;
  int wave = threadIdx.x >> 6;
  int lane = threadIdx.x & 63;
  const float* src = wave ? HLF : LLF;
  float4 v = ((const float4*)(src + (size_t)row*ND))[lane];
  float s = v.x*v.x + v.y*v.y + v.z*v.z + v.w*v.w;
  for (int o=32;o;o>>=1) s += __shfl_down(s,o);
  if (lane==0) (wave? nh: nl)[row] = sqrtf(s);
}

// ---------------- bf16 MFMA GEMM -> column sum-of-exp only ----------------
#define K1 0.09016844f   /* 0.0625 * log2(e) */
__launch_bounds__(256)
__global__ void kgemm_mfma(const float* __restrict__ LLF, const float* __restrict__ HLF,
                           const float* __restrict__ nl, const float* __restrict__ nh,
                           float* __restrict__ partS){
  __shared__ ushort As[128][72];   // [row][k] bf16, stride 144B
  __shared__ ushort Bs[128][72];
  __shared__ float colsum[128];
  const int b  = blockIdx.z;
  const int n0 = blockIdx.y << 7;
  const int m0 = blockIdx.x << 7;
  const float* Ab = LLF + (size_t)b*NN*ND;
  const float* Bb = HLF + (size_t)b*NN*ND;
  const int tid  = threadIdx.x;
  const int lane = tid & 63;
  const int w    = tid >> 6;
  const int wn   = w >> 1, wm = w & 1;
  const int quad = lane >> 4, l15 = lane & 15;
  if (tid < 128) colsum[tid] = 0.0f;

  f32x4 acc[4][4];
  #pragma unroll
  for (int i=0;i<4;i++)
    #pragma unroll
    for (int j=0;j<4;j++) acc[i][j] = (f32x4){0.f,0.f,0.f,0.f};

  const int rbase = tid >> 3;
  const int kq    = (tid & 7) << 3;

  for (int ck=0; ck<4; ck++){
    const int k0 = ck << 6;
    __syncthreads();
    #pragma unroll
    for (int pi=0; pi<4; pi++){
      int row = rbase + (pi<<5);
      const float* pa = Ab + (size_t)(n0+row)*ND + k0 + kq;
      float4 a0 = *(const float4*)pa;
      float4 a1 = *(const float4*)(pa+4);
      uint4 ua;
      ua.x = (__float_as_uint(a0.y)&0xFFFF0000u)|(__float_as_uint(a0.x)>>16);
      ua.y = (__float_as_uint(a0.w)&0xFFFF0000u)|(__float_as_uint(a0.z)>>16);
      ua.z = (__float_as_uint(a1.y)&0xFFFF0000u)|(__float_as_uint(a1.x)>>16);
      ua.w = (__float_as_uint(a1.w)&0xFFFF0000u)|(__float_as_uint(a1.z)>>16);
      *(uint4*)(&As[row][kq]) = ua;
      const float* pb = Bb + (size_t)(m0+row)*ND + k0 + kq;
      float4 b0 = *(const float4*)pb;
      float4 b1 = *(const float4*)(pb+4);
      uint4 ub;
      ub.x = (__float_as_uint(b0.y)&0xFFFF0000u)|(__float_as_uint(b0.x)>>16);
      ub.y = (__float_as_uint(b0.w)&0xFFFF0000u)|(__float_as_uint(b0.z)>>16);
      ub.z = (__float_as_uint(b1.y)&0xFFFF0000u)|(__float_as_uint(b1.x)>>16);
      ub.w = (__float_as_uint(b1.w)&0xFFFF0000u)|(__float_as_uint(b1.z)>>16);
      *(uint4*)(&Bs[row][kq]) = ub;
    }
    __syncthreads();
    #pragma unroll
    for (int ks=0; ks<64; ks+=32){
      bf16x8 af[4], bf[4];
      #pragma unroll
      for (int t=0;t<4;t++)
        af[t] = *(const bf16x8*)(&As[wn*64 + t*16 + l15][ks + quad*8]);
      #pragma unroll
      for (int t=0;t<4;t++)
        bf[t] = *(const bf16x8*)(&Bs[wm*64 + t*16 + l15][ks + quad*8]);
      #pragma unroll
      for (int ti=0;ti<4;ti++)
        #pragma unroll
        for (int tj=0;tj<4;tj++)
          acc[ti][tj] = __builtin_amdgcn_mfma_f32_16x16x32_bf16(af[ti], bf[tj], acc[ti][tj], 0, 0, 0);
    }
  }

  float an[4][4];
  #pragma unroll
  for (int ti=0;ti<4;ti++)
    #pragma unroll
    for (int r=0;r<4;r++)
      an[ti][r] = K1 / nl[b*NN + n0 + wn*64 + ti*16 + quad*4 + r];
  float bm[4];
  #pragma unroll
  for (int tj=0;tj<4;tj++)
    bm[tj] = 1.0f / nh[b*NN + m0 + wm*64 + tj*16 + l15];
  #pragma unroll
  for (int tj=0;tj<4;tj++){
    float s = 0.0f;
    #pragma unroll
    for (int ti=0;ti<4;ti++)
      #pragma unroll
      for (int r=0;r<4;r++)
        s += __builtin_amdgcn_exp2f(acc[ti][tj][r]*an[ti][r]*bm[tj] - K1);
    s += __shfl_down(s, 32);
    s += __shfl_down(s, 16);
    if (lane < 16) atomicAdd(&colsum[wm*64 + tj*16 + l15], s);
  }
  __syncthreads();
  if (tid < 128)
    partS[(size_t)blockIdx.y*BNtot + b*NN + m0 + tid] = colsum[tid];
}

__global__ void kScomb(const float* __restrict__ partS, float* __restrict__ iS){
  int g = blockIdx.x*256 + threadIdx.x;      // b*NN+m
  float s = 0.0f;
  #pragma unroll
  for (int nt=0; nt<16; nt++) s += partS[(size_t)nt*BNtot + g];
  iS[g] = 1.0f/s;
}

// ---------------- gumbel scan: branchless packed top-2 per (128-chunk, column) ----
// packed = (key<<7) | (127-k): 23-bit key + 7-bit reversed index. Integer max =
// max gumbel, ties -> smallest n (equal key <=> equal gumbel; JAX first-max).
// Top-2 of each 128-chunk; miss requires 3 gumbels within 6.5e-5 of gmax in one
// chunk: P ~ 1e-4 per run. Branchless: t=min(m1,x); m1=max(m1,x); m2=max(m2,t).
__global__ void kgumbel(float* __restrict__ pcv, int* __restrict__ pci){
  int t  = blockIdx.x*256 + threadIdx.x;     // 262144 threads
  int m  = t & 2047;
  int bl = (t >> 11) & 7;
  int nq = t >> 14;                          // 0..15, n-chunk of 128
  int nbase = nq << 7;
  unsigned a1=0, a2=0, c1=0, c2=0;           // packed top-2 (A=batch bl, C=batch bl+8)
  #pragma unroll 2
  for (int k=0;k<128;k++){
    uint2 r = three2((unsigned)bl, (unsigned)(nbase+k), (unsigned)m);
    unsigned pa = ((r.x >> 9) << 7) | (127 - k);
    unsigned pb = ((r.y >> 9) << 7) | (127 - k);
    unsigned ta = (pa < a1) ? pa : a1;       // min
    a1 = (pa > a1) ? pa : a1;                // max
    a2 = (ta > a2) ? ta : a2;
    unsigned tc = (pb < c1) ? pb : c1;
    c1 = (pb > c1) ? pb : c1;
    c2 = (tc > c2) ? tc : c2;
  }
  int baseA = (((nq*NB + bl  )*NN + m) << 1);
  int baseB = (((nq*NB + bl+8)*NN + m) << 1);
  pcv[baseA+0] = gfromkey(a1 >> 7); pci[baseA+0] = nbase + 127 - (int)(a1 & 127u);
  pcv[baseA+1] = gfromkey(a2 >> 7); pci[baseA+1] = nbase + 127 - (int)(a2 & 127u);
  pcv[baseB+0] = gfromkey(c1 >> 7); pci[baseB+0] = nbase + 127 - (int)(c1 & 127u);
  pcv[baseB+1] = gfromkey(c2 >> 7); pci[baseB+1] = nbase + 127 - (int)(c2 & 127u);
}

// ---------------- resolve: exact argmax among windowed candidates ----------------
__launch_bounds__(256)
__global__ void kresolve(const float* __restrict__ LLF, const float* __restrict__ HLF,
                         const float* __restrict__ nl, const float* __restrict__ nh,
                         const float* __restrict__ iS,
                         const float* __restrict__ pcv, const int* __restrict__ pci,
                         int* __restrict__ idx){
  int w    = threadIdx.x >> 6;               // wave within block
  int lane = threadIdx.x & 63;
  int g = blockIdx.x*4 + w;                  // b*NN+m
  int b = g >> 11, m = g & 2047;
  float pv = -INFINITY; int pn = 0;
  if (lane < 32){                            // nq = lane>>1, rank = lane&1
    int base = ((((lane>>1)*NB + b)*NN + m) << 1) + (lane & 1);
    pv = pcv[base]; pn = pci[base];
  }
  float gmax = pv;
  for (int o=32;o;o>>=1) gmax = fmaxf(gmax, __shfl_down(gmax,o));
  gmax = __shfl(gmax, 0);
  unsigned long long mask = __ballot(pv >= gmax - 8e-5f);
  mask &= 0xFFFFFFFFull;
  float invS = iS[g];
  float bestQ = -INFINITY; int bestN = 1<<30;
  while (mask){
    int src = __builtin_ctzll(mask); mask &= mask-1;
    int   n  = __shfl(pn, src);
    float gv = __shfl(pv, src);
    float4 a = ((const float4*)(LLF + ((size_t)b*NN + n)*ND))[lane];
    float4 h = ((const float4*)(HLF + ((size_t)b*NN + m)*ND))[lane];
    float d = a.x*h.x + a.y*h.y + a.z*h.z + a.w*h.w;
    for (int o=32;o;o>>=1) d += __shfl_down(d,o);
    d = __shfl(d, 0);
    float sim = (d / fmaxf(nl[b*NN+n]*nh[g], 1e-8f)) * 0.0625f;
    float q = expf(sim - 0.0625f)*invS + gv;
    if (q > bestQ || (q == bestQ && n < bestN)){ bestQ = q; bestN = n; }
  }
  if (lane==0) idx[g] = bestN;
}

// ---------------- fallback path (only if ws too small; never expected) ----------------
__launch_bounds__(256)
__global__ void kstats(const float* __restrict__ A, const float* __restrict__ Bm,
                       const float* __restrict__ nl, const float* __restrict__ nh,
                       float* __restrict__ Mout, float* __restrict__ Sinv){
  __shared__ float As[64][33];
  __shared__ float Bs[64][33];
  __shared__ float Cs[64][65];
  const int b  = blockIdx.x >> 5;
  const int m0 = (blockIdx.x & 31) << 6;
  const float* Ab = A  + (size_t)b*NN*ND;
  const float* Bb = Bm + (size_t)b*NN*ND;
  const int tid = threadIdx.x;
  const int tx = tid & 15, ty = tid >> 4;
  float nhv[4];
  #pragma unroll
  for (int j=0;j<4;j++) nhv[j] = nh[b*NN + m0 + tx*4 + j];
  float Mr = -INFINITY, Sr = 0.0f;
  for (int nt=0; nt<NN; nt+=64){
    float acc[4][4] = {{0.f,0.f,0.f,0.f},{0.f,0.f,0.f,0.f},{0.f,0.f,0.f,0.f},{0.f,0.f,0.f,0.f}};
    for (int kc=0; kc<ND; kc+=32){
      __syncthreads();
      #pragma unroll
      for (int s=0;s<2;s++){
        int f = tid + (s<<8);
        int r = f >> 3;
        int c = (f & 7) << 2;
        float4 va = *(const float4*)(Ab + (size_t)(nt+r)*ND + kc + c);
        As[r][c]=va.x; As[r][c+1]=va.y; As[r][c+2]=va.z; As[r][c+3]=va.w;
        float4 vb = *(const float4*)(Bb + (size_t)(m0+r)*ND + kc + c);
        Bs[r][c]=vb.x; Bs[r][c+1]=vb.y; Bs[r][c+2]=vb.z; Bs[r][c+3]=vb.w;
      }
      __syncthreads();
      #pragma unroll 4
      for (int k=0;k<32;k++){
        float a0=As[ty*4+0][k], a1=As[ty*4+1][k], a2=As[ty*4+2][k], a3=As[ty*4+3][k];
        float b0=Bs[tx*4+0][k], b1=Bs[tx*4+1][k], b2=Bs[tx*4+2][k], b3=Bs[tx*4+3][k];
        acc[0][0]+=a0*b0; acc[0][1]+=a0*b1; acc[0][2]+=a0*b2; acc[0][3]+=a0*b3;
        acc[1][0]+=a1*b0; acc[1][1]+=a1*b1; acc[1][2]+=a1*b2; acc[1][3]+=a1*b3;
        acc[2][0]+=a2*b0; acc[2][1]+=a2*b1; acc[2][2]+=a2*b2; acc[2][3]+=a2*b3;
        acc[3][0]+=a3*b0; acc[3][1]+=a3*b1; acc[3][2]+=a3*b2; acc[3][3]+=a3*b3;
      }
    }
    float nlv[4];
    #pragma unroll
    for (int i=0;i<4;i++) nlv[i] = nl[b*NN + nt + ty*4 + i];
    __syncthreads();
    #pragma unroll
    for (int i=0;i<4;i++)
      #pragma unroll
      for (int j=0;j<4;j++){
        float denom = fmaxf(nlv[i]*nhv[j], 1e-8f);
        Cs[ty*4+i][tx*4+j] = (acc[i][j]/denom)*0.0625f;
      }
    __syncthreads();
    if (tid < 64){
      float tmax = -INFINITY;
      #pragma unroll 8
      for (int r=0;r<64;r++) tmax = fmaxf(tmax, Cs[r][tid]);
      float newM = fmaxf(Mr, tmax);
      float s = 0.0f;
      #pragma unroll 4
      for (int r=0;r<64;r++) s += expf(Cs[r][tid]-newM);
      Sr = Sr*expf(Mr-newM) + s;
      Mr = newM;
    }
  }
  if (tid < 64){
    Mout[b*NN+m0+tid] = Mr;
    Sinv[b*NN+m0+tid] = 1.0f/Sr;
  }
}

__launch_bounds__(256)
__global__ void kargmax(const float* __restrict__ A, const float* __restrict__ Bm,
                        const float* __restrict__ nl, const float* __restrict__ nh,
                        const float* __restrict__ Mv, const float* __restrict__ Sv,
                        int* __restrict__ idxout){
  __shared__ float As[64][33];
  __shared__ float Bs[64][33];
  __shared__ float Vs[16][64];
  __shared__ int   Is[16][64];
  const int b  = blockIdx.x >> 5;
  const int m0 = (blockIdx.x & 31) << 6;
  const float* Ab = A  + (size_t)b*NN*ND;
  const float* Bb = Bm + (size_t)b*NN*ND;
  const int tid = threadIdx.x;
  const int tx = tid & 15, ty = tid >> 4;
  float nhv[4], Mj[4], iSj[4];
  #pragma unroll
  for (int j=0;j<4;j++){
    int m = m0 + tx*4 + j;
    nhv[j] = nh[b*NN + m];
    Mj[j]  = Mv[b*NN + m];
    iSj[j] = Sv[b*NN + m];
  }
  float bestV = -INFINITY; int bestN = 0;
  for (int nt=0; nt<NN; nt+=64){
    float acc[4][4] = {{0.f,0.f,0.f,0.f},{0.f,0.f,0.f,0.f},{0.f,0.f,0.f,0.f},{0.f,0.f,0.f,0.f}};
    for (int kc=0; kc<ND; kc+=32){
      __syncthreads();
      #pragma unroll
      for (int s=0;s<2;s++){
        int f = tid + (s<<8);
        int r = f >> 3;
        int c = (f & 7) << 2;
        float4 va = *(const float4*)(Ab + (size_t)(nt+r)*ND + kc + c);
        As[r][c]=va.x; As[r][c+1]=va.y; As[r][c+2]=va.z; As[r][c+3]=va.w;
        float4 vb = *(const float4*)(Bb + (size_t)(m0+r)*ND + kc + c);
        Bs[r][c]=vb.x; Bs[r][c+1]=vb.y; Bs[r][c+2]=vb.z; Bs[r][c+3]=vb.w;
      }
      __syncthreads();
      #pragma unroll 4
      for (int k=0;k<32;k++){
        float a0=As[ty*4+0][k], a1=As[ty*4+1][k], a2=As[ty*4+2][k], a3=As[ty*4+3][k];
        float b0=Bs[tx*4+0][k], b1=Bs[tx*4+1][k], b2=Bs[tx*4+2][k], b3=Bs[tx*4+3][k];
        acc[0][0]+=a0*b0; acc[0][1]+=a0*b1; acc[0][2]+=a0*b2; acc[0][3]+=a0*b3;
        acc[1][0]+=a1*b0; acc[1][1]+=a1*b1; acc[1][2]+=a1*b2; acc[1][3]+=a1*b3;
        acc[2][0]+=a2*b0; acc[2][1]+=a2*b1; acc[2][2]+=a2*b2; acc[2][3]+=a2*b3;
        acc[3][0]+=a3*b0; acc[3][1]+=a3*b1; acc[3][2]+=a3*b2; acc[3][3]+=a3*b3;
      }
    }
    float nlv[4];
    #pragma unroll
    for (int i=0;i<4;i++) nlv[i] = nl[b*NN + nt + ty*4 + i];
    float lv[4]; int li[4];
    #pragma unroll
    for (int j=0;j<4;j++){ lv[j] = -INFINITY; li[j] = 0; }
    #pragma unroll
    for (int i=0;i<4;i++){
      int n = nt + ty*4 + i;
      #pragma unroll
      for (int j=0;j<4;j++){
        float denom = fmaxf(nlv[i]*nhv[j], 1e-8f);
        float sim = (acc[i][j]/denom)*0.0625f;
        float p = expf(sim - Mj[j]) * iSj[j];
        float v = p + gumbelv((unsigned)b, (unsigned)n, (unsigned)(m0 + tx*4 + j));
        if (v > lv[j]) { lv[j] = v; li[j] = n; }
      }
    }
    __syncthreads();
    #pragma unroll
    for (int j=0;j<4;j++){ Vs[ty][tx*4+j]=lv[j]; Is[ty][tx*4+j]=li[j]; }
    __syncthreads();
    if (tid < 64){
      #pragma unroll 4
      for (int t=0;t<16;t++){
        float v = Vs[t][tid];
        if (v > bestV){ bestV = v; bestN = Is[t][tid]; }
      }
    }
  }
  if (tid < 64) idxout[b*NN + m0 + tid] = bestN;
}

// ---------------- shared tail kernels ----------------
__global__ void ksort(const int* __restrict__ idx, int* __restrict__ cntg,
                      int* __restrict__ offg, int* __restrict__ sl){
  __shared__ int c[NN];
  __shared__ int part[256];
  int b = blockIdx.x, tid = threadIdx.x;
  for (int v=tid; v<NN; v+=256) c[v]=0;
  __syncthreads();
  for (int j=tid; j<NN; j+=256) atomicAdd(&c[idx[b*NN+j]], 1);
  __syncthreads();
  int base = tid*8, s=0, lc[8];
  #pragma unroll
  for (int k=0;k<8;k++){ lc[k]=c[base+k]; s+=lc[k]; }
  part[tid]=s; __syncthreads();
  for (int o=1;o<256;o<<=1){
    int v = (tid>=o)? part[tid-o] : 0;
    __syncthreads();
    part[tid]+=v;
    __syncthreads();
  }
  int run = part[tid]-s;
  #pragma unroll
  for (int k=0;k<8;k++){
    int v = base+k;
    cntg[b*NN+v]=lc[k];
    offg[b*NN+v]=run;
    for (int j=0;j<lc[k];j++) sl[b*NN+run+j]=v;
    run += lc[k];
  }
}

__global__ void kw(const float* __restrict__ LLF, const float* __restrict__ HLF,
                   const float* __restrict__ nl, const float* __restrict__ nh,
                   const int* __restrict__ sl, float* __restrict__ w){
  int g = blockIdx.x*4 + (threadIdx.x>>6);
  int lane = threadIdx.x & 63;
  int b = g >> 11;
  int s = sl[g];
  float4 a = ((const float4*)(HLF + ((size_t)b*NN + s)*ND))[lane];
  float4 l = ((const float4*)(LLF + (size_t)g*ND))[lane];
  float d = a.x*l.x + a.y*l.y + a.z*l.z + a.w*l.w;
  for (int o=32;o;o>>=1) d += __shfl_down(d,o);
  if (lane==0){
    float denom = fmaxf(nh[b*NN+s]*nl[g], 1e-8f);
    w[g] = d/denom;
  }
}

__global__ void knoise(const float* __restrict__ w, float* __restrict__ nz){
  int b = blockIdx.x, tid = threadIdx.x;
  __shared__ float sred[4];
  float x[8]; float mx = -INFINITY;
  #pragma unroll
  for (int k=0;k<8;k++){ x[k] = w[b*NN + tid*8 + k] / 0.1f; mx = fmaxf(mx, x[k]); }
  for (int o=32;o;o>>=1) mx = fmaxf(mx, __shfl_down(mx,o));
  mx = __shfl(mx, 0);
  if ((tid&63)==0) sred[tid>>6] = mx;
  __syncthreads();
  mx = fmaxf(fmaxf(sred[0],sred[1]), fmaxf(sred[2],sred[3]));
  __syncthreads();
  float e[8]; float s = 0.f;
  #pragma unroll
  for (int k=0;k<8;k++){ e[k] = expf(x[k]-mx); s += e[k]; }
  for (int o=32;o;o>>=1) s += __shfl_down(s,o);
  s = __shfl(s, 0);
  if ((tid&63)==0) sred[tid>>6] = s;
  __syncthreads();
  s = sred[0]+sred[1]+sred[2]+sred[3];
  #pragma unroll
  for (int k=0;k<8;k++) nz[b*NN + tid*8 + k] = e[k]/s;
}

__global__ void kfinal(const float* __restrict__ LLF, const float* __restrict__ HLF,
                       const int* __restrict__ cnt, const int* __restrict__ off,
                       const float* __restrict__ nz, float* __restrict__ out){
  int row = blockIdx.x;
  int lane = threadIdx.x;
  int b = row >> 11;
  float4 h = ((const float4*)(HLF + (size_t)row*ND))[lane];
  int c = cnt[row];
  if (c > 0){
    int i = off[row] + c - 1;
    float ns = nz[b*NN + i];
    float4 l = ((const float4*)(LLF + ((size_t)(b*NN + i))*ND))[lane];
    h.x += l.x*ns; h.y += l.y*ns; h.z += l.z*ns; h.w += l.w*ns;
  }
  ((float4*)(out + (size_t)row*ND))[lane] = h;
}

extern "C" void kernel_launch(void* const* d_in, const int* in_sizes, int n_in,
                              void* d_out, int out_size, void* d_ws, size_t ws_size,
                              hipStream_t stream){
  const float* LLF = (const float*)d_in[0];
  const float* HLF = (const float*)d_in[1];
  float* out = (float*)d_out;
  float* ws = (float*)d_ws;

  float* nl  = ws;
  float* nh  = ws + 1*(size_t)BNtot;
  float* iS  = ws + 2*(size_t)BNtot;
  int*   idx = (int*)(ws + 3*(size_t)BNtot);
  int*   cnt = (int*)(ws + 4*(size_t)BNtot);
  int*   off = (int*)(ws + 5*(size_t)BNtot);
  int*   sl  = (int*)(ws + 6*(size_t)BNtot);
  float* wv  = ws + 7*(size_t)BNtot;
  float* nz  = ws + 8*(size_t)BNtot;
  float* partS = ws + 9*(size_t)BNtot;                 // 16*BNtot
  float* pcv   = partS + 16*(size_t)BNtot;             // 32*BNtot (16 chunks x 2 ranks)
  int*   pci   = (int*)(pcv + 32*(size_t)BNtot);       // 32*BNtot
  const size_t needBytes = (9 + 16 + 32 + 32) * (size_t)BNtot * 4;   // ~11.7 MB

  hipLaunchKernelGGL(knorms, dim3(BNtot), dim3(128), 0, stream, LLF, HLF, nl, nh);

  if (ws_size >= needBytes){
    hipLaunchKernelGGL(kgemm_mfma, dim3(16,16,16), dim3(256), 0, stream, LLF, HLF, nl, nh, partS);
    hipLaunchKernelGGL(kScomb,   dim3(BNtot/256),dim3(256), 0, stream, partS, iS);
    hipLaunchKernelGGL(kgumbel,  dim3(1024),     dim3(256), 0, stream, pcv, pci);
    hipLaunchKernelGGL(kresolve, dim3(BNtot/4),  dim3(256), 0, stream, LLF, HLF, nl, nh, iS, pcv, pci, idx);
  } else {
    float* Mv = ws + 9*(size_t)BNtot;
    hipLaunchKernelGGL(kstats,  dim3(NB*32), dim3(256), 0, stream, LLF, HLF, nl, nh, Mv, iS);
    hipLaunchKernelGGL(kargmax, dim3(NB*32), dim3(256), 0, stream, LLF, HLF, nl, nh, Mv, iS, idx);
  }

  hipLaunchKernelGGL(ksort,  dim3(NB),      dim3(256), 0, stream, idx, cnt, off, sl);
  hipLaunchKernelGGL(kw,     dim3(BNtot/4), dim3(256), 0, stream, LLF, HLF, nl, nh, sl, wv);
  hipLaunchKernelGGL(knoise, dim3(NB),      dim3(256), 0, stream, wv, nz);
  hipLaunchKernelGGL(kfinal, dim3(BNtot),   dim3(64),  0, stream, LLF, HLF, cnt, off, nz, out);
}

// Round 7
// 302.771 us; speedup vs baseline: 6.6206x; 1.0613x over previous
//
#include <hip/hip_runtime.h>
#include <math.h>

#define NB 16
#define NN 2048
#define ND 256
#define BNtot (NB*NN)
#define HH 33554432u   // 2^25 = half of 16*2048*2048 (threefry counter split)

typedef __attribute__((ext_vector_type(8))) short bf16x8;
typedef __attribute__((ext_vector_type(4))) float f32x4;

// CK-style direct global->LDS DMA, 16B per lane. lds ptr must be wave-uniform.
__device__ __forceinline__ void gld16(const void* g, void* l){
  __builtin_amdgcn_global_load_lds((const __attribute__((address_space(1))) void*)g,
                                   (__attribute__((address_space(3))) void*)l, 16, 0, 0);
}

// ---------------- threefry2x32, bit-exact vs jax.random.key(42) ----------------
__device__ __forceinline__ float gumbelv(unsigned b, unsigned n, unsigned m){
  unsigned f = (b<<22) | (n<<11) | m;
  unsigned x0 = (b < 8u) ? f : (f - HH);
  unsigned x1 = x0 + HH;
  const unsigned ks0=0u, ks1=42u, ks2=0u^42u^0x1BD11BDAu;
  unsigned v0 = x0 + ks0;
  unsigned v1 = x1 + ks1;
#define TFR(r) { v0 += v1; v1 = __builtin_rotateleft32(v1,(r)); v1 ^= v0; }
  TFR(13) TFR(15) TFR(26) TFR(6)
  v0 += ks1; v1 += ks2 + 1u;
  TFR(17) TFR(29) TFR(16) TFR(24)
  v0 += ks2; v1 += ks0 + 2u;
  TFR(13) TFR(15) TFR(26) TFR(6)
  v0 += ks0; v1 += ks1 + 3u;
  TFR(17) TFR(29) TFR(16) TFR(24)
  v0 += ks1; v1 += ks2 + 4u;
  TFR(13) TFR(15) TFR(26) TFR(6)
  v0 += ks2; v1 += ks0 + 5u;
#undef TFR
  unsigned bits = (b < 8u) ? v0 : v1;
  float fl = __uint_as_float((bits>>9) | 0x3F800000u) - 1.0f;
  float u = fmaxf(1e-10f, fl + 1e-10f);
  return -logf(-logf(u));
}

// Paired raw-bits version: one threefry eval serves batches bl and bl+8
__device__ __forceinline__ uint2 three2(unsigned bl, unsigned n, unsigned m){
  unsigned x0 = (bl<<22) | (n<<11) | m;
  unsigned x1 = x0 + HH;
  const unsigned ks0=0u, ks1=42u, ks2=0u^42u^0x1BD11BDAu;
  unsigned v0 = x0 + ks0;
  unsigned v1 = x1 + ks1;
#define TFR(r) { v0 += v1; v1 = __builtin_rotateleft32(v1,(r)); v1 ^= v0; }
  TFR(13) TFR(15) TFR(26) TFR(6)
  v0 += ks1; v1 += ks2 + 1u;
  TFR(17) TFR(29) TFR(16) TFR(24)
  v0 += ks2; v1 += ks0 + 2u;
  TFR(13) TFR(15) TFR(26) TFR(6)
  v0 += ks0; v1 += ks1 + 3u;
  TFR(17) TFR(29) TFR(16) TFR(24)
  v0 += ks1; v1 += ks2 + 4u;
  TFR(13) TFR(15) TFR(26) TFR(6)
  v0 += ks2; v1 += ks0 + 5u;
#undef TFR
  return make_uint2(v0, v1);
}

// g from 23-bit key, exactly as JAX: fl = as_float(key|0x3f800000)-1
__device__ __forceinline__ float gfromkey(unsigned key){
  float fl = __uint_as_float(key | 0x3F800000u) - 1.0f;
  float u = fmaxf(1e-10f, fl + 1e-10f);
  return -logf(-logf(u));
}

// ---------------- row norms (fallback tier) ----------------
__global__ void knorms(const float* __restrict__ LLF, const float* __restrict__ HLF,
                       float* __restrict__ nl, float* __restrict__ nh){
  int row = blockIdx.x;
  int wave = threadIdx.x >> 6;
  int lane = threadIdx.x & 63;
  const float* src = wave ? HLF : LLF;
  float4 v = ((const float4*)(src + (size_t)row*ND))[lane];
  float s = v.x*v.x + v.y*v.y + v.z*v.z + v.w*v.w;
  for (int o=32;o;o>>=1) s += __shfl_down(s,o);
  if (lane==0) (wave? nh: nl)[row] = sqrtf(s);
}

// ---------------- kprep: norms + bf16 cast into tiled+swizzled layout ----------------
// Layout (ushorts): dst[b*524288 + ck*131072 + n*64 + ((qi^(n&7))<<3) + (j&7)]
// where k = ck*64 + j, qi = j>>3. Truncation cast (bit-identical to prior staging).
__launch_bounds__(256)
__global__ void kprep(const float* __restrict__ LLF, const float* __restrict__ HLF,
                      ushort* __restrict__ Abf, ushort* __restrict__ Bbf,
                      float* __restrict__ nl, float* __restrict__ nh){
  int w    = threadIdx.x >> 6;
  int lane = threadIdx.x & 63;
  int r = blockIdx.x*4 + w;                 // global row 0..BNtot-1
  const float* src = blockIdx.y ? HLF : LLF;
  ushort* dst      = blockIdx.y ? Bbf : Abf;
  float4 v = ((const float4*)(src + (size_t)r*ND))[lane];
  float s = v.x*v.x + v.y*v.y + v.z*v.z + v.w*v.w;
  for (int o=32;o;o>>=1) s += __shfl_down(s,o);
  if (lane==0) (blockIdx.y ? nh : nl)[r] = sqrtf(s);
  // pack 4 floats -> 4 bf16 (truncate)
  uint2 u;
  u.x = (__float_as_uint(v.y)&0xFFFF0000u)|(__float_as_uint(v.x)>>16);
  u.y = (__float_as_uint(v.w)&0xFFFF0000u)|(__float_as_uint(v.z)>>16);
  int b = r >> 11, nloc = r & 2047;
  int k = lane << 2;
  int ck = k >> 6;
  int j  = k & 63;
  int qi = j >> 3;
  size_t off = (size_t)b*524288 + (size_t)ck*131072 + (size_t)nloc*64
             + ((qi ^ (nloc & 7)) << 3) + (j & 7);
  *(uint2*)(dst + off) = u;
}

// ---------------- bf16 MFMA GEMM with global_load_lds staging ----------------
#define K1 0.09016844f   /* 0.0625 * log2(e) */
__launch_bounds__(256)
__global__ void kgemm_dma(const ushort* __restrict__ Abf, const ushort* __restrict__ Bbf,
                          const float* __restrict__ nl, const float* __restrict__ nh,
                          float* __restrict__ partS){
  __shared__ ushort As[128*64];   // 16 KB, [row][64] with XOR-swizzled quads
  __shared__ ushort Bs[128*64];
  __shared__ float colsum[128];
  const int b  = blockIdx.z;
  const int n0 = blockIdx.y << 7;
  const int m0 = blockIdx.x << 7;
  const int tid  = threadIdx.x;
  const int lane = tid & 63;
  const int w    = tid >> 6;
  const int wn   = w >> 1, wm = w & 1;
  const int quad = lane >> 4, l15 = lane & 15;
  if (tid < 128) colsum[tid] = 0.0f;

  const ushort* Ab = Abf + (size_t)b*524288;
  const ushort* Bb = Bbf + (size_t)b*524288;

  f32x4 acc[4][4];
  #pragma unroll
  for (int i=0;i<4;i++)
    #pragma unroll
    for (int j=0;j<4;j++) acc[i][j] = (f32x4){0.f,0.f,0.f,0.f};

  for (int ck=0; ck<4; ck++){
    __syncthreads();   // previous iteration's ds_reads done before DMA overwrite
    const ushort* ga = Ab + (size_t)ck*131072 + (size_t)n0*64;  // 16 KB contiguous
    const ushort* gb = Bb + (size_t)ck*131072 + (size_t)m0*64;
    #pragma unroll
    for (int t=0;t<4;t++){
      int seg = (w*4 + t) * 512;              // 512 ushorts = 1 KB per wave-load
      gld16(ga + seg + lane*8, &As[seg]);
      gld16(gb + seg + lane*8, &Bs[seg]);
    }
    __syncthreads();   // drains vmcnt (compiler emits waitcnt before barrier)
    #pragma unroll
    for (int ks=0; ks<64; ks+=32){
      bf16x8 af[4], bf[4];
      #pragma unroll
      for (int t=0;t<4;t++){
        int R = wn*64 + t*16 + l15;
        af[t] = *(const bf16x8*)(&As[R*64 + ((((ks>>3)+quad) ^ (R&7))<<3)]);
      }
      #pragma unroll
      for (int t=0;t<4;t++){
        int R = wm*64 + t*16 + l15;
        bf[t] = *(const bf16x8*)(&Bs[R*64 + ((((ks>>3)+quad) ^ (R&7))<<3)]);
      }
      #pragma unroll
      for (int ti=0;ti<4;ti++)
        #pragma unroll
        for (int tj=0;tj<4;tj++)
          acc[ti][tj] = __builtin_amdgcn_mfma_f32_16x16x32_bf16(af[ti], bf[tj], acc[ti][tj], 0, 0, 0);
    }
  }

  float an[4][4];
  #pragma unroll
  for (int ti=0;ti<4;ti++)
    #pragma unroll
    for (int r=0;r<4;r++)
      an[ti][r] = K1 / nl[b*NN + n0 + wn*64 + ti*16 + quad*4 + r];
  float bm[4];
  #pragma unroll
  for (int tj=0;tj<4;tj++)
    bm[tj] = 1.0f / nh[b*NN + m0 + wm*64 + tj*16 + l15];
  #pragma unroll
  for (int tj=0;tj<4;tj++){
    float s = 0.0f;
    #pragma unroll
    for (int ti=0;ti<4;ti++)
      #pragma unroll
      for (int r=0;r<4;r++)
        s += __builtin_amdgcn_exp2f(acc[ti][tj][r]*an[ti][r]*bm[tj] - K1);
    s += __shfl_down(s, 32);
    s += __shfl_down(s, 16);
    if (lane < 16) atomicAdd(&colsum[wm*64 + tj*16 + l15], s);
  }
  __syncthreads();
  if (tid < 128)
    partS[(size_t)blockIdx.y*BNtot + b*NN + m0 + tid] = colsum[tid];
}

// ---------------- middle-tier GEMM (round-6 path, in-kernel conversion) ----------------
__launch_bounds__(256)
__global__ void kgemm_mfma(const float* __restrict__ LLF, const float* __restrict__ HLF,
                           const float* __restrict__ nl, const float* __restrict__ nh,
                           float* __restrict__ partS){
  __shared__ ushort As[128][72];
  __shared__ ushort Bs[128][72];
  __shared__ float colsum[128];
  const int b  = blockIdx.z;
  const int n0 = blockIdx.y << 7;
  const int m0 = blockIdx.x << 7;
  const float* Ab = LLF + (size_t)b*NN*ND;
  const float* Bb = HLF + (size_t)b*NN*ND;
  const int tid  = threadIdx.x;
  const int lane = tid & 63;
  const int w    = tid >> 6;
  const int wn   = w >> 1, wm = w & 1;
  const int quad = lane >> 4, l15 = lane & 15;
  if (tid < 128) colsum[tid] = 0.0f;

  f32x4 acc[4][4];
  #pragma unroll
  for (int i=0;i<4;i++)
    #pragma unroll
    for (int j=0;j<4;j++) acc[i][j] = (f32x4){0.f,0.f,0.f,0.f};

  const int rbase = tid >> 3;
  const int kq    = (tid & 7) << 3;

  for (int ck=0; ck<4; ck++){
    const int k0 = ck << 6;
    __syncthreads();
    #pragma unroll
    for (int pi=0; pi<4; pi++){
      int row = rbase + (pi<<5);
      const float* pa = Ab + (size_t)(n0+row)*ND + k0 + kq;
      float4 a0 = *(const float4*)pa;
      float4 a1 = *(const float4*)(pa+4);
      uint4 ua;
      ua.x = (__float_as_uint(a0.y)&0xFFFF0000u)|(__float_as_uint(a0.x)>>16);
      ua.y = (__float_as_uint(a0.w)&0xFFFF0000u)|(__float_as_uint(a0.z)>>16);
      ua.z = (__float_as_uint(a1.y)&0xFFFF0000u)|(__float_as_uint(a1.x)>>16);
      ua.w = (__float_as_uint(a1.w)&0xFFFF0000u)|(__float_as_uint(a1.z)>>16);
      *(uint4*)(&As[row][kq]) = ua;
      const float* pb = Bb + (size_t)(m0+row)*ND + k0 + kq;
      float4 b0 = *(const float4*)pb;
      float4 b1 = *(const float4*)(pb+4);
      uint4 ub;
      ub.x = (__float_as_uint(b0.y)&0xFFFF0000u)|(__float_as_uint(b0.x)>>16);
      ub.y = (__float_as_uint(b0.w)&0xFFFF0000u)|(__float_as_uint(b0.z)>>16);
      ub.z = (__float_as_uint(b1.y)&0xFFFF0000u)|(__float_as_uint(b1.x)>>16);
      ub.w = (__float_as_uint(b1.w)&0xFFFF0000u)|(__float_as_uint(b1.z)>>16);
      *(uint4*)(&Bs[row][kq]) = ub;
    }
    __syncthreads();
    #pragma unroll
    for (int ks=0; ks<64; ks+=32){
      bf16x8 af[4], bf[4];
      #pragma unroll
      for (int t=0;t<4;t++)
        af[t] = *(const bf16x8*)(&As[wn*64 + t*16 + l15][ks + quad*8]);
      #pragma unroll
      for (int t=0;t<4;t++)
        bf[t] = *(const bf16x8*)(&Bs[wm*64 + t*16 + l15][ks + quad*8]);
      #pragma unroll
      for (int ti=0;ti<4;ti++)
        #pragma unroll
        for (int tj=0;tj<4;tj++)
          acc[ti][tj] = __builtin_amdgcn_mfma_f32_16x16x32_bf16(af[ti], bf[tj], acc[ti][tj], 0, 0, 0);
    }
  }

  float an[4][4];
  #pragma unroll
  for (int ti=0;ti<4;ti++)
    #pragma unroll
    for (int r=0;r<4;r++)
      an[ti][r] = K1 / nl[b*NN + n0 + wn*64 + ti*16 + quad*4 + r];
  float bm[4];
  #pragma unroll
  for (int tj=0;tj<4;tj++)
    bm[tj] = 1.0f / nh[b*NN + m0 + wm*64 + tj*16 + l15];
  #pragma unroll
  for (int tj=0;tj<4;tj++){
    float s = 0.0f;
    #pragma unroll
    for (int ti=0;ti<4;ti++)
      #pragma unroll
      for (int r=0;r<4;r++)
        s += __builtin_amdgcn_exp2f(acc[ti][tj][r]*an[ti][r]*bm[tj] - K1);
    s += __shfl_down(s, 32);
    s += __shfl_down(s, 16);
    if (lane < 16) atomicAdd(&colsum[wm*64 + tj*16 + l15], s);
  }
  __syncthreads();
  if (tid < 128)
    partS[(size_t)blockIdx.y*BNtot + b*NN + m0 + tid] = colsum[tid];
}

__global__ void kScomb(const float* __restrict__ partS, float* __restrict__ iS){
  int g = blockIdx.x*256 + threadIdx.x;      // b*NN+m
  float s = 0.0f;
  #pragma unroll
  for (int nt=0; nt<16; nt++) s += partS[(size_t)nt*BNtot + g];
  iS[g] = 1.0f/s;
}

// ---------------- gumbel scan: branchless packed top-2 per (128-chunk, column) ----
__global__ void kgumbel(float* __restrict__ pcv, int* __restrict__ pci){
  int t  = blockIdx.x*256 + threadIdx.x;     // 262144 threads
  int m  = t & 2047;
  int bl = (t >> 11) & 7;
  int nq = t >> 14;                          // 0..15, n-chunk of 128
  int nbase = nq << 7;
  unsigned a1=0, a2=0, c1=0, c2=0;           // packed top-2 (A=batch bl, C=batch bl+8)
  #pragma unroll 2
  for (int k=0;k<128;k++){
    uint2 r = three2((unsigned)bl, (unsigned)(nbase+k), (unsigned)m);
    unsigned pa = ((r.x >> 9) << 7) | (127 - k);
    unsigned pb = ((r.y >> 9) << 7) | (127 - k);
    unsigned ta = (pa < a1) ? pa : a1;
    a1 = (pa > a1) ? pa : a1;
    a2 = (ta > a2) ? ta : a2;
    unsigned tc = (pb < c1) ? pb : c1;
    c1 = (pb > c1) ? pb : c1;
    c2 = (tc > c2) ? tc : c2;
  }
  int baseA = (((nq*NB + bl  )*NN + m) << 1);
  int baseB = (((nq*NB + bl+8)*NN + m) << 1);
  pcv[baseA+0] = gfromkey(a1 >> 7); pci[baseA+0] = nbase + 127 - (int)(a1 & 127u);
  pcv[baseA+1] = gfromkey(a2 >> 7); pci[baseA+1] = nbase + 127 - (int)(a2 & 127u);
  pcv[baseB+0] = gfromkey(c1 >> 7); pci[baseB+0] = nbase + 127 - (int)(c1 & 127u);
  pcv[baseB+1] = gfromkey(c2 >> 7); pci[baseB+1] = nbase + 127 - (int)(c2 & 127u);
}

// ---------------- resolve: exact argmax among windowed candidates ----------------
__launch_bounds__(256)
__global__ void kresolve(const float* __restrict__ LLF, const float* __restrict__ HLF,
                         const float* __restrict__ nl, const float* __restrict__ nh,
                         const float* __restrict__ iS,
                         const float* __restrict__ pcv, const int* __restrict__ pci,
                         int* __restrict__ idx){
  int w    = threadIdx.x >> 6;               // wave within block
  int lane = threadIdx.x & 63;
  int g = blockIdx.x*4 + w;                  // b*NN+m
  int b = g >> 11, m = g & 2047;
  float pv = -INFINITY; int pn = 0;
  if (lane < 32){                            // nq = lane>>1, rank = lane&1
    int base = ((((lane>>1)*NB + b)*NN + m) << 1) + (lane & 1);
    pv = pcv[base]; pn = pci[base];
  }
  float gmax = pv;
  for (int o=32;o;o>>=1) gmax = fmaxf(gmax, __shfl_down(gmax,o));
  gmax = __shfl(gmax, 0);
  unsigned long long mask = __ballot(pv >= gmax - 8e-5f);
  mask &= 0xFFFFFFFFull;
  float invS = iS[g];
  float bestQ = -INFINITY; int bestN = 1<<30;
  while (mask){
    int src = __builtin_ctzll(mask); mask &= mask-1;
    int   n  = __shfl(pn, src);
    float gv = __shfl(pv, src);
    float4 a = ((const float4*)(LLF + ((size_t)b*NN + n)*ND))[lane];
    float4 h = ((const float4*)(HLF + ((size_t)b*NN + m)*ND))[lane];
    float d = a.x*h.x + a.y*h.y + a.z*h.z + a.w*h.w;
    for (int o=32;o;o>>=1) d += __shfl_down(d,o);
    d = __shfl(d, 0);
    float sim = (d / fmaxf(nl[b*NN+n]*nh[g], 1e-8f)) * 0.0625f;
    float q = expf(sim - 0.0625f)*invS + gv;
    if (q > bestQ || (q == bestQ && n < bestN)){ bestQ = q; bestN = n; }
  }
  if (lane==0) idx[g] = bestN;
}

// ---------------- last-resort fallback (tiny ws) ----------------
__launch_bounds__(256)
__global__ void kstats(const float* __restrict__ A, const float* __restrict__ Bm,
                       const float* __restrict__ nl, const float* __restrict__ nh,
                       float* __restrict__ Mout, float* __restrict__ Sinv){
  __shared__ float As[64][33];
  __shared__ float Bs[64][33];
  __shared__ float Cs[64][65];
  const int b  = blockIdx.x >> 5;
  const int m0 = (blockIdx.x & 31) << 6;
  const float* Ab = A  + (size_t)b*NN*ND;
  const float* Bb = Bm + (size_t)b*NN*ND;
  const int tid = threadIdx.x;
  const int tx = tid & 15, ty = tid >> 4;
  float nhv[4];
  #pragma unroll
  for (int j=0;j<4;j++) nhv[j] = nh[b*NN + m0 + tx*4 + j];
  float Mr = -INFINITY, Sr = 0.0f;
  for (int nt=0; nt<NN; nt+=64){
    float acc[4][4] = {{0.f,0.f,0.f,0.f},{0.f,0.f,0.f,0.f},{0.f,0.f,0.f,0.f},{0.f,0.f,0.f,0.f}};
    for (int kc=0; kc<ND; kc+=32){
      __syncthreads();
      #pragma unroll
      for (int s=0;s<2;s++){
        int f = tid + (s<<8);
        int r = f >> 3;
        int c = (f & 7) << 2;
        float4 va = *(const float4*)(Ab + (size_t)(nt+r)*ND + kc + c);
        As[r][c]=va.x; As[r][c+1]=va.y; As[r][c+2]=va.z; As[r][c+3]=va.w;
        float4 vb = *(const float4*)(Bb + (size_t)(m0+r)*ND + kc + c);
        Bs[r][c]=vb.x; Bs[r][c+1]=vb.y; Bs[r][c+2]=vb.z; Bs[r][c+3]=vb.w;
      }
      __syncthreads();
      #pragma unroll 4
      for (int k=0;k<32;k++){
        float a0=As[ty*4+0][k], a1=As[ty*4+1][k], a2=As[ty*4+2][k], a3=As[ty*4+3][k];
        float b0=Bs[tx*4+0][k], b1=Bs[tx*4+1][k], b2=Bs[tx*4+2][k], b3=Bs[tx*4+3][k];
        acc[0][0]+=a0*b0; acc[0][1]+=a0*b1; acc[0][2]+=a0*b2; acc[0][3]+=a0*b3;
        acc[1][0]+=a1*b0; acc[1][1]+=a1*b1; acc[1][2]+=a1*b2; acc[1][3]+=a1*b3;
        acc[2][0]+=a2*b0; acc[2][1]+=a2*b1; acc[2][2]+=a2*b2; acc[2][3]+=a2*b3;
        acc[3][0]+=a3*b0; acc[3][1]+=a3*b1; acc[3][2]+=a3*b2; acc[3][3]+=a3*b3;
      }
    }
    float nlv[4];
    #pragma unroll
    for (int i=0;i<4;i++) nlv[i] = nl[b*NN + nt + ty*4 + i];
    __syncthreads();
    #pragma unroll
    for (int i=0;i<4;i++)
      #pragma unroll
      for (int j=0;j<4;j++){
        float denom = fmaxf(nlv[i]*nhv[j], 1e-8f);
        Cs[ty*4+i][tx*4+j] = (acc[i][j]/denom)*0.0625f;
      }
    __syncthreads();
    if (tid < 64){
      float tmax = -INFINITY;
      #pragma unroll 8
      for (int r=0;r<64;r++) tmax = fmaxf(tmax, Cs[r][tid]);
      float newM = fmaxf(Mr, tmax);
      float s = 0.0f;
      #pragma unroll 4
      for (int r=0;r<64;r++) s += expf(Cs[r][tid]-newM);
      Sr = Sr*expf(Mr-newM) + s;
      Mr = newM;
    }
  }
  if (tid < 64){
    Mout[b*NN+m0+tid] = Mr;
    Sinv[b*NN+m0+tid] = 1.0f/Sr;
  }
}

__launch_bounds__(256)
__global__ void kargmax(const float* __restrict__ A, const float* __restrict__ Bm,
                        const float* __restrict__ nl, const float* __restrict__ nh,
                        const float* __restrict__ Mv, const float* __restrict__ Sv,
                        int* __restrict__ idxout){
  __shared__ float As[64][33];
  __shared__ float Bs[64][33];
  __shared__ float Vs[16][64];
  __shared__ int   Is[16][64];
  const int b  = blockIdx.x >> 5;
  const int m0 = (blockIdx.x & 31) << 6;
  const float* Ab = A  + (size_t)b*NN*ND;
  const float* Bb = Bm + (size_t)b*NN*ND;
  const int tid = threadIdx.x;
  const int tx = tid & 15, ty = tid >> 4;
  float nhv[4], Mj[4], iSj[4];
  #pragma unroll
  for (int j=0;j<4;j++){
    int m = m0 + tx*4 + j;
    nhv[j] = nh[b*NN + m];
    Mj[j]  = Mv[b*NN + m];
    iSj[j] = Sv[b*NN + m];
  }
  float bestV = -INFINITY; int bestN = 0;
  for (int nt=0; nt<NN; nt+=64){
    float acc[4][4] = {{0.f,0.f,0.f,0.f},{0.f,0.f,0.f,0.f},{0.f,0.f,0.f,0.f},{0.f,0.f,0.f,0.f}};
    for (int kc=0; kc<ND; kc+=32){
      __syncthreads();
      #pragma unroll
      for (int s=0;s<2;s++){
        int f = tid + (s<<8);
        int r = f >> 3;
        int c = (f & 7) << 2;
        float4 va = *(const float4*)(Ab + (size_t)(nt+r)*ND + kc + c);
        As[r][c]=va.x; As[r][c+1]=va.y; As[r][c+2]=va.z; As[r][c+3]=va.w;
        float4 vb = *(const float4*)(Bb + (size_t)(m0+r)*ND + kc + c);
        Bs[r][c]=vb.x; Bs[r][c+1]=vb.y; Bs[r][c+2]=vb.z; Bs[r][c+3]=vb.w;
      }
      __syncthreads();
      #pragma unroll 4
      for (int k=0;k<32;k++){
        float a0=As[ty*4+0][k], a1=As[ty*4+1][k], a2=As[ty*4+2][k], a3=As[ty*4+3][k];
        float b0=Bs[tx*4+0][k], b1=Bs[tx*4+1][k], b2=Bs[tx*4+2][k], b3=Bs[tx*4+3][k];
        acc[0][0]+=a0*b0; acc[0][1]+=a0*b1; acc[0][2]+=a0*b2; acc[0][3]+=a0*b3;
        acc[1][0]+=a1*b0; acc[1][1]+=a1*b1; acc[1][2]+=a1*b2; acc[1][3]+=a1*b3;
        acc[2][0]+=a2*b0; acc[2][1]+=a2*b1; acc[2][2]+=a2*b2; acc[2][3]+=a2*b3;
        acc[3][0]+=a3*b0; acc[3][1]+=a3*b1; acc[3][2]+=a3*b2; acc[3][3]+=a3*b3;
      }
    }
    float nlv[4];
    #pragma unroll
    for (int i=0;i<4;i++) nlv[i] = nl[b*NN + nt + ty*4 + i];
    float lv[4]; int li[4];
    #pragma unroll
    for (int j=0;j<4;j++){ lv[j] = -INFINITY; li[j] = 0; }
    #pragma unroll
    for (int i=0;i<4;i++){
      int n = nt + ty*4 + i;
      #pragma unroll
      for (int j=0;j<4;j++){
        float denom = fmaxf(nlv[i]*nhv[j], 1e-8f);
        float sim = (acc[i][j]/denom)*0.0625f;
        float p = expf(sim - Mj[j]) * iSj[j];
        float v = p + gumbelv((unsigned)b, (unsigned)n, (unsigned)(m0 + tx*4 + j));
        if (v > lv[j]) { lv[j] = v; li[j] = n; }
      }
    }
    __syncthreads();
    #pragma unroll
    for (int j=0;j<4;j++){ Vs[ty][tx*4+j]=lv[j]; Is[ty][tx*4+j]=li[j]; }
    __syncthreads();
    if (tid < 64){
      #pragma unroll 4
      for (int t=0;t<16;t++){
        float v = Vs[t][tid];
        if (v > bestV){ bestV = v; bestN = Is[t][tid]; }
      }
    }
  }
  if (tid < 64) idxout[b*NN + m0 + tid] = bestN;
}

// ---------------- shared tail kernels ----------------
__global__ void ksort(const int* __restrict__ idx, int* __restrict__ cntg,
                      int* __restrict__ offg, int* __restrict__ sl){
  __shared__ int c[NN];
  __shared__ int part[256];
  int b = blockIdx.x, tid = threadIdx.x;
  for (int v=tid; v<NN; v+=256) c[v]=0;
  __syncthreads();
  for (int j=tid; j<NN; j+=256) atomicAdd(&c[idx[b*NN+j]], 1);
  __syncthreads();
  int base = tid*8, s=0, lc[8];
  #pragma unroll
  for (int k=0;k<8;k++){ lc[k]=c[base+k]; s+=lc[k]; }
  part[tid]=s; __syncthreads();
  for (int o=1;o<256;o<<=1){
    int v = (tid>=o)? part[tid-o] : 0;
    __syncthreads();
    part[tid]+=v;
    __syncthreads();
  }
  int run = part[tid]-s;
  #pragma unroll
  for (int k=0;k<8;k++){
    int v = base+k;
    cntg[b*NN+v]=lc[k];
    offg[b*NN+v]=run;
    for (int j=0;j<lc[k];j++) sl[b*NN+run+j]=v;
    run += lc[k];
  }
}

__global__ void kw(const float* __restrict__ LLF, const float* __restrict__ HLF,
                   const float* __restrict__ nl, const float* __restrict__ nh,
                   const int* __restrict__ sl, float* __restrict__ w){
  int g = blockIdx.x*4 + (threadIdx.x>>6);
  int lane = threadIdx.x & 63;
  int b = g >> 11;
  int s = sl[g];
  float4 a = ((const float4*)(HLF + ((size_t)b*NN + s)*ND))[lane];
  float4 l = ((const float4*)(LLF + (size_t)g*ND))[lane];
  float d = a.x*l.x + a.y*l.y + a.z*l.z + a.w*l.w;
  for (int o=32;o;o>>=1) d += __shfl_down(d,o);
  if (lane==0){
    float denom = fmaxf(nh[b*NN+s]*nl[g], 1e-8f);
    w[g] = d/denom;
  }
}

__global__ void knoise(const float* __restrict__ w, float* __restrict__ nz){
  int b = blockIdx.x, tid = threadIdx.x;
  __shared__ float sred[4];
  float x[8]; float mx = -INFINITY;
  #pragma unroll
  for (int k=0;k<8;k++){ x[k] = w[b*NN + tid*8 + k] / 0.1f; mx = fmaxf(mx, x[k]); }
  for (int o=32;o;o>>=1) mx = fmaxf(mx, __shfl_down(mx,o));
  mx = __shfl(mx, 0);
  if ((tid&63)==0) sred[tid>>6] = mx;
  __syncthreads();
  mx = fmaxf(fmaxf(sred[0],sred[1]), fmaxf(sred[2],sred[3]));
  __syncthreads();
  float e[8]; float s = 0.f;
  #pragma unroll
  for (int k=0;k<8;k++){ e[k] = expf(x[k]-mx); s += e[k]; }
  for (int o=32;o;o>>=1) s += __shfl_down(s,o);
  s = __shfl(s, 0);
  if ((tid&63)==0) sred[tid>>6] = s;
  __syncthreads();
  s = sred[0]+sred[1]+sred[2]+sred[3];
  #pragma unroll
  for (int k=0;k<8;k++) nz[b*NN + tid*8 + k] = e[k]/s;
}

__global__ void kfinal(const float* __restrict__ LLF, const float* __restrict__ HLF,
                       const int* __restrict__ cnt, const int* __restrict__ off,
                       const float* __restrict__ nz, float* __restrict__ out){
  int row = blockIdx.x;
  int lane = threadIdx.x;
  int b = row >> 11;
  float4 h = ((const float4*)(HLF + (size_t)row*ND))[lane];
  int c = cnt[row];
  if (c > 0){
    int i = off[row] + c - 1;
    float ns = nz[b*NN + i];
    float4 l = ((const float4*)(LLF + ((size_t)(b*NN + i))*ND))[lane];
    h.x += l.x*ns; h.y += l.y*ns; h.z += l.z*ns; h.w += l.w*ns;
  }
  ((float4*)(out + (size_t)row*ND))[lane] = h;
}

extern "C" void kernel_launch(void* const* d_in, const int* in_sizes, int n_in,
                              void* d_out, int out_size, void* d_ws, size_t ws_size,
                              hipStream_t stream){
  const float* LLF = (const float*)d_in[0];
  const float* HLF = (const float*)d_in[1];
  float* out = (float*)d_out;
  float* ws = (float*)d_ws;

  float* nl  = ws;
  float* nh  = ws + 1*(size_t)BNtot;
  float* iS  = ws + 2*(size_t)BNtot;
  int*   idx = (int*)(ws + 3*(size_t)BNtot);
  int*   cnt = (int*)(ws + 4*(size_t)BNtot);
  int*   off = (int*)(ws + 5*(size_t)BNtot);
  int*   sl  = (int*)(ws + 6*(size_t)BNtot);
  float* wv  = ws + 7*(size_t)BNtot;
  float* nz  = ws + 8*(size_t)BNtot;
  float* partS = ws + 9*(size_t)BNtot;                 // 16*BNtot
  float* pcv   = partS + 16*(size_t)BNtot;             // 32*BNtot (16 chunks x 2 ranks)
  int*   pci   = (int*)(pcv + 32*(size_t)BNtot);       // 32*BNtot
  ushort* Abf  = (ushort*)(pci + 32*(size_t)BNtot);    // BNtot*256 bf16 (16.7 MB)
  ushort* Bbf  = Abf + (size_t)BNtot*ND;
  const size_t needBytes1 = (9 + 16 + 32 + 32) * (size_t)BNtot * 4;           // ~11.7 MB
  const size_t needBytes2 = needBytes1 + 2 * (size_t)BNtot * ND * 2;          // ~45.2 MB

  if (ws_size >= needBytes2){
    hipLaunchKernelGGL(kprep,    dim3(BNtot/4, 2), dim3(256), 0, stream, LLF, HLF, Abf, Bbf, nl, nh);
    hipLaunchKernelGGL(kgemm_dma,dim3(16,16,16),   dim3(256), 0, stream, Abf, Bbf, nl, nh, partS);
    hipLaunchKernelGGL(kScomb,   dim3(BNtot/256),  dim3(256), 0, stream, partS, iS);
    hipLaunchKernelGGL(kgumbel,  dim3(1024),       dim3(256), 0, stream, pcv, pci);
    hipLaunchKernelGGL(kresolve, dim3(BNtot/4),    dim3(256), 0, stream, LLF, HLF, nl, nh, iS, pcv, pci, idx);
  } else if (ws_size >= needBytes1){
    hipLaunchKernelGGL(knorms,   dim3(BNtot),      dim3(128), 0, stream, LLF, HLF, nl, nh);
    hipLaunchKernelGGL(kgemm_mfma,dim3(16,16,16),  dim3(256), 0, stream, LLF, HLF, nl, nh, partS);
    hipLaunchKernelGGL(kScomb,   dim3(BNtot/256),  dim3(256), 0, stream, partS, iS);
    hipLaunchKernelGGL(kgumbel,  dim3(1024),       dim3(256), 0, stream, pcv, pci);
    hipLaunchKernelGGL(kresolve, dim3(BNtot/4),    dim3(256), 0, stream, LLF, HLF, nl, nh, iS, pcv, pci, idx);
  } else {
    float* Mv = ws + 9*(size_t)BNtot;
    hipLaunchKernelGGL(knorms,   dim3(BNtot),      dim3(128), 0, stream, LLF, HLF, nl, nh);
    hipLaunchKernelGGL(kstats,   dim3(NB*32),      dim3(256), 0, stream, LLF, HLF, nl, nh, Mv, iS);
    hipLaunchKernelGGL(kargmax,  dim3(NB*32),      dim3(256), 0, stream, LLF, HLF, nl, nh, Mv, iS, idx);
  }

  hipLaunchKernelGGL(ksort,  dim3(NB),      dim3(256), 0, stream, idx, cnt, off, sl);
  hipLaunchKernelGGL(kw,     dim3(BNtot/4), dim3(256), 0, stream, LLF, HLF, nl, nh, sl, wv);
  hipLaunchKernelGGL(knoise, dim3(NB),      dim3(256), 0, stream, wv, nz);
  hipLaunchKernelGGL(kfinal, dim3(BNtot),   dim3(64),  0, stream, LLF, HLF, cnt, off, nz, out);
}

// Round 8
// 299.212 us; speedup vs baseline: 6.6994x; 1.0119x over previous
//
#include <hip/hip_runtime.h>
#include <math.h>

#define NB 16
#define NN 2048
#define ND 256
#define BNtot (NB*NN)
#define HH 33554432u   // 2^25 = half of 16*2048*2048 (threefry counter split)

typedef __attribute__((ext_vector_type(8))) short bf16x8;
typedef __attribute__((ext_vector_type(4))) float f32x4;

// CK-style direct global->LDS DMA, 16B per lane. lds ptr must be wave-uniform.
__device__ __forceinline__ void gld16(const void* g, void* l){
  __builtin_amdgcn_global_load_lds((const __attribute__((address_space(1))) void*)g,
                                   (__attribute__((address_space(3))) void*)l, 16, 0, 0);
}

__device__ __forceinline__ unsigned rotl(unsigned v, int r){
  return __builtin_amdgcn_alignbit(v, v, 32-r);   // single v_alignbit_b32
}
__device__ __forceinline__ unsigned umaxu(unsigned a, unsigned b){ return a > b ? a : b; }
__device__ __forceinline__ unsigned uminu(unsigned a, unsigned b){ return a < b ? a : b; }

// ---------------- threefry2x32, bit-exact vs jax.random.key(42) ----------------
__device__ __forceinline__ float gumbelv(unsigned b, unsigned n, unsigned m){
  unsigned f = (b<<22) | (n<<11) | m;
  unsigned x0 = (b < 8u) ? f : (f - HH);
  unsigned x1 = x0 + HH;
  const unsigned ks0=0u, ks1=42u, ks2=0u^42u^0x1BD11BDAu;
  unsigned v0 = x0 + ks0;
  unsigned v1 = x1 + ks1;
#define TFR(r) { v0 += v1; v1 = rotl(v1,(r)); v1 ^= v0; }
  TFR(13) TFR(15) TFR(26) TFR(6)
  v0 += ks1; v1 += ks2 + 1u;
  TFR(17) TFR(29) TFR(16) TFR(24)
  v0 += ks2; v1 += ks0 + 2u;
  TFR(13) TFR(15) TFR(26) TFR(6)
  v0 += ks0; v1 += ks1 + 3u;
  TFR(17) TFR(29) TFR(16) TFR(24)
  v0 += ks1; v1 += ks2 + 4u;
  TFR(13) TFR(15) TFR(26) TFR(6)
  v0 += ks2; v1 += ks0 + 5u;
#undef TFR
  unsigned bits = (b < 8u) ? v0 : v1;
  float fl = __uint_as_float((bits>>9) | 0x3F800000u) - 1.0f;
  float u = fmaxf(1e-10f, fl + 1e-10f);
  return -logf(-logf(u));
}

// g from 23-bit key, exactly as JAX: fl = as_float(key|0x3f800000)-1
__device__ __forceinline__ float gfromkey(unsigned key){
  float fl = __uint_as_float(key | 0x3F800000u) - 1.0f;
  float u = fmaxf(1e-10f, fl + 1e-10f);
  return -logf(-logf(u));
}

// ---------------- row norms (fallback tier) ----------------
__global__ void knorms(const float* __restrict__ LLF, const float* __restrict__ HLF,
                       float* __restrict__ nl, float* __restrict__ nh){
  int row = blockIdx.x;
  int wave = threadIdx.x >> 6;
  int lane = threadIdx.x & 63;
  const float* src = wave ? HLF : LLF;
  float4 v = ((const float4*)(src + (size_t)row*ND))[lane];
  float s = v.x*v.x + v.y*v.y + v.z*v.z + v.w*v.w;
  for (int o=32;o;o>>=1) s += __shfl_down(s,o);
  if (lane==0) (wave? nh: nl)[row] = sqrtf(s);
}

// ---------------- kprep: norms + bf16 cast into tiled+swizzled layout ----------------
__launch_bounds__(256)
__global__ void kprep(const float* __restrict__ LLF, const float* __restrict__ HLF,
                      ushort* __restrict__ Abf, ushort* __restrict__ Bbf,
                      float* __restrict__ nl, float* __restrict__ nh){
  int w    = threadIdx.x >> 6;
  int lane = threadIdx.x & 63;
  int r = blockIdx.x*4 + w;                 // global row 0..BNtot-1
  const float* src = blockIdx.y ? HLF : LLF;
  ushort* dst      = blockIdx.y ? Bbf : Abf;
  float4 v = ((const float4*)(src + (size_t)r*ND))[lane];
  float s = v.x*v.x + v.y*v.y + v.z*v.z + v.w*v.w;
  for (int o=32;o;o>>=1) s += __shfl_down(s,o);
  if (lane==0) (blockIdx.y ? nh : nl)[r] = sqrtf(s);
  uint2 u;
  u.x = (__float_as_uint(v.y)&0xFFFF0000u)|(__float_as_uint(v.x)>>16);
  u.y = (__float_as_uint(v.w)&0xFFFF0000u)|(__float_as_uint(v.z)>>16);
  int b = r >> 11, nloc = r & 2047;
  int k = lane << 2;
  int ck = k >> 6;
  int j  = k & 63;
  int qi = j >> 3;
  size_t off = (size_t)b*524288 + (size_t)ck*131072 + (size_t)nloc*64
             + ((qi ^ (nloc & 7)) << 3) + (j & 7);
  *(uint2*)(dst + off) = u;
}

// ---------------- bf16 MFMA GEMM with global_load_lds staging ----------------
#define K1 0.09016844f   /* 0.0625 * log2(e) */
__launch_bounds__(256)
__global__ void kgemm_dma(const ushort* __restrict__ Abf, const ushort* __restrict__ Bbf,
                          const float* __restrict__ nl, const float* __restrict__ nh,
                          float* __restrict__ partS){
  __shared__ ushort As[128*64];   // 16 KB, [row][64] with XOR-swizzled quads
  __shared__ ushort Bs[128*64];
  __shared__ float colsum[128];
  const int b  = blockIdx.z;
  const int n0 = blockIdx.y << 7;
  const int m0 = blockIdx.x << 7;
  const int tid  = threadIdx.x;
  const int lane = tid & 63;
  const int w    = tid >> 6;
  const int wn   = w >> 1, wm = w & 1;
  const int quad = lane >> 4, l15 = lane & 15;
  if (tid < 128) colsum[tid] = 0.0f;

  const ushort* Ab = Abf + (size_t)b*524288;
  const ushort* Bb = Bbf + (size_t)b*524288;

  f32x4 acc[4][4];
  #pragma unroll
  for (int i=0;i<4;i++)
    #pragma unroll
    for (int j=0;j<4;j++) acc[i][j] = (f32x4){0.f,0.f,0.f,0.f};

  for (int ck=0; ck<4; ck++){
    __syncthreads();
    const ushort* ga = Ab + (size_t)ck*131072 + (size_t)n0*64;  // 16 KB contiguous
    const ushort* gb = Bb + (size_t)ck*131072 + (size_t)m0*64;
    #pragma unroll
    for (int t=0;t<4;t++){
      int seg = (w*4 + t) * 512;              // 512 ushorts = 1 KB per wave-load
      gld16(ga + seg + lane*8, &As[seg]);
      gld16(gb + seg + lane*8, &Bs[seg]);
    }
    __syncthreads();
    #pragma unroll
    for (int ks=0; ks<64; ks+=32){
      bf16x8 af[4], bf[4];
      #pragma unroll
      for (int t=0;t<4;t++){
        int R = wn*64 + t*16 + l15;
        af[t] = *(const bf16x8*)(&As[R*64 + ((((ks>>3)+quad) ^ (R&7))<<3)]);
      }
      #pragma unroll
      for (int t=0;t<4;t++){
        int R = wm*64 + t*16 + l15;
        bf[t] = *(const bf16x8*)(&Bs[R*64 + ((((ks>>3)+quad) ^ (R&7))<<3)]);
      }
      #pragma unroll
      for (int ti=0;ti<4;ti++)
        #pragma unroll
        for (int tj=0;tj<4;tj++)
          acc[ti][tj] = __builtin_amdgcn_mfma_f32_16x16x32_bf16(af[ti], bf[tj], acc[ti][tj], 0, 0, 0);
    }
  }

  float an[4][4];
  #pragma unroll
  for (int ti=0;ti<4;ti++)
    #pragma unroll
    for (int r=0;r<4;r++)
      an[ti][r] = K1 / nl[b*NN + n0 + wn*64 + ti*16 + quad*4 + r];
  float bm[4];
  #pragma unroll
  for (int tj=0;tj<4;tj++)
    bm[tj] = 1.0f / nh[b*NN + m0 + wm*64 + tj*16 + l15];
  #pragma unroll
  for (int tj=0;tj<4;tj++){
    float s = 0.0f;
    #pragma unroll
    for (int ti=0;ti<4;ti++)
      #pragma unroll
      for (int r=0;r<4;r++)
        s += __builtin_amdgcn_exp2f(acc[ti][tj][r]*an[ti][r]*bm[tj] - K1);
    s += __shfl_down(s, 32);
    s += __shfl_down(s, 16);
    if (lane < 16) atomicAdd(&colsum[wm*64 + tj*16 + l15], s);
  }
  __syncthreads();
  if (tid < 128)
    partS[(size_t)blockIdx.y*BNtot + b*NN + m0 + tid] = colsum[tid];
}

// ---------------- middle-tier GEMM (in-kernel conversion) ----------------
__launch_bounds__(256)
__global__ void kgemm_mfma(const float* __restrict__ LLF, const float* __restrict__ HLF,
                           const float* __restrict__ nl, const float* __restrict__ nh,
                           float* __restrict__ partS){
  __shared__ ushort As[128][72];
  __shared__ ushort Bs[128][72];
  __shared__ float colsum[128];
  const int b  = blockIdx.z;
  const int n0 = blockIdx.y << 7;
  const int m0 = blockIdx.x << 7;
  const float* Ab = LLF + (size_t)b*NN*ND;
  const float* Bb = HLF + (size_t)b*NN*ND;
  const int tid  = threadIdx.x;
  const int lane = tid & 63;
  const int w    = tid >> 6;
  const int wn   = w >> 1, wm = w & 1;
  const int quad = lane >> 4, l15 = lane & 15;
  if (tid < 128) colsum[tid] = 0.0f;

  f32x4 acc[4][4];
  #pragma unroll
  for (int i=0;i<4;i++)
    #pragma unroll
    for (int j=0;j<4;j++) acc[i][j] = (f32x4){0.f,0.f,0.f,0.f};

  const int rbase = tid >> 3;
  const int kq    = (tid & 7) << 3;

  for (int ck=0; ck<4; ck++){
    const int k0 = ck << 6;
    __syncthreads();
    #pragma unroll
    for (int pi=0; pi<4; pi++){
      int row = rbase + (pi<<5);
      const float* pa = Ab + (size_t)(n0+row)*ND + k0 + kq;
      float4 a0 = *(const float4*)pa;
      float4 a1 = *(const float4*)(pa+4);
      uint4 ua;
      ua.x = (__float_as_uint(a0.y)&0xFFFF0000u)|(__float_as_uint(a0.x)>>16);
      ua.y = (__float_as_uint(a0.w)&0xFFFF0000u)|(__float_as_uint(a0.z)>>16);
      ua.z = (__float_as_uint(a1.y)&0xFFFF0000u)|(__float_as_uint(a1.x)>>16);
      ua.w = (__float_as_uint(a1.w)&0xFFFF0000u)|(__float_as_uint(a1.z)>>16);
      *(uint4*)(&As[row][kq]) = ua;
      const float* pb = Bb + (size_t)(m0+row)*ND + k0 + kq;
      float4 b0 = *(const float4*)pb;
      float4 b1 = *(const float4*)(pb+4);
      uint4 ub;
      ub.x = (__float_as_uint(b0.y)&0xFFFF0000u)|(__float_as_uint(b0.x)>>16);
      ub.y = (__float_as_uint(b0.w)&0xFFFF0000u)|(__float_as_uint(b0.z)>>16);
      ub.z = (__float_as_uint(b1.y)&0xFFFF0000u)|(__float_as_uint(b1.x)>>16);
      ub.w = (__float_as_uint(b1.w)&0xFFFF0000u)|(__float_as_uint(b1.z)>>16);
      *(uint4*)(&Bs[row][kq]) = ub;
    }
    __syncthreads();
    #pragma unroll
    for (int ks=0; ks<64; ks+=32){
      bf16x8 af[4], bf[4];
      #pragma unroll
      for (int t=0;t<4;t++)
        af[t] = *(const bf16x8*)(&As[wn*64 + t*16 + l15][ks + quad*8]);
      #pragma unroll
      for (int t=0;t<4;t++)
        bf[t] = *(const bf16x8*)(&Bs[wm*64 + t*16 + l15][ks + quad*8]);
      #pragma unroll
      for (int ti=0;ti<4;ti++)
        #pragma unroll
        for (int tj=0;tj<4;tj++)
          acc[ti][tj] = __builtin_amdgcn_mfma_f32_16x16x32_bf16(af[ti], bf[tj], acc[ti][tj], 0, 0, 0);
    }
  }

  float an[4][4];
  #pragma unroll
  for (int ti=0;ti<4;ti++)
    #pragma unroll
    for (int r=0;r<4;r++)
      an[ti][r] = K1 / nl[b*NN + n0 + wn*64 + ti*16 + quad*4 + r];
  float bm[4];
  #pragma unroll
  for (int tj=0;tj<4;tj++)
    bm[tj] = 1.0f / nh[b*NN + m0 + wm*64 + tj*16 + l15];
  #pragma unroll
  for (int tj=0;tj<4;tj++){
    float s = 0.0f;
    #pragma unroll
    for (int ti=0;ti<4;ti++)
      #pragma unroll
      for (int r=0;r<4;r++)
        s += __builtin_amdgcn_exp2f(acc[ti][tj][r]*an[ti][r]*bm[tj] - K1);
    s += __shfl_down(s, 32);
    s += __shfl_down(s, 16);
    if (lane < 16) atomicAdd(&colsum[wm*64 + tj*16 + l15], s);
  }
  __syncthreads();
  if (tid < 128)
    partS[(size_t)blockIdx.y*BNtot + b*NN + m0 + tid] = colsum[tid];
}

__global__ void kScomb(const float* __restrict__ partS, float* __restrict__ iS){
  int g = blockIdx.x*256 + threadIdx.x;      // b*NN+m
  float s = 0.0f;
  #pragma unroll
  for (int nt=0; nt<16; nt++) s += partS[(size_t)nt*BNtot + g];
  iS[g] = 1.0f/s;
}

// ---------------- gumbel scan: lane-paired branchless packed top-2 ----------------
// Each thread scans 64 values of a 128-chunk (half selected by t&1); lane-pairs
// merge top-2s via shfl_xor(1). packed = (key bits 31..9 in place) | kk where kk
// is the 7-bit *descending* loop counter (reversed index): integer max = max
// gumbel, ties -> smallest n (equal key <=> equal gumbel; JAX first-max).
__launch_bounds__(256)
__global__ void kgumbel(float* __restrict__ pcv, int* __restrict__ pci){
  int t    = blockIdx.x*256 + threadIdx.x;   // 524288 threads
  int half = t & 1;
  int m    = (t >> 1) & 2047;
  int bl   = (t >> 12) & 7;
  int nq   = t >> 15;                        // 0..15, chunk of 128
  int chunkbase = nq << 7;
  int nstart = chunkbase + (half << 6);      // this thread's 64 values
  unsigned x0 = ((unsigned)bl << 22) | ((unsigned)nstart << 11) | (unsigned)m;
  const unsigned KS2 = 42u ^ 0x1BD11BDAu;
  unsigned a1=0, a2=0, c1=0, c2=0;           // packed top-2 (A=batch bl, C=batch bl+8)
  // kk descends 127-(half*64) .. 64-(half*64); n = chunkbase + 127 - kk ascends
  #pragma unroll 2
  for (int kk = 127 - (half<<6); kk >= 64 - (half<<6); --kk){
    unsigned v0 = x0;
    unsigned v1 = x0 + (HH + 42u);
#define TFR(r) { v0 += v1; v1 = rotl(v1,(r)); v1 ^= v0; }
    TFR(13) TFR(15) TFR(26) TFR(6)
    v0 += 42u;  v1 += KS2 + 1u;
    TFR(17) TFR(29) TFR(16) TFR(24)
    v0 += KS2;  v1 += 2u;
    TFR(13) TFR(15) TFR(26) TFR(6)
    /* v0 += 0 */ v1 += 42u + 3u;
    TFR(17) TFR(29) TFR(16) TFR(24)
    v0 += 42u;  v1 += KS2 + 4u;
    TFR(13) TFR(15) TFR(26) TFR(6)
    v0 += KS2;  v1 += 5u;
#undef TFR
    unsigned pa = (v0 & 0xFFFFFE00u) | (unsigned)kk;
    unsigned pb = (v1 & 0xFFFFFE00u) | (unsigned)kk;
    unsigned ta = uminu(pa, a1);
    a1 = umaxu(pa, a1);
    a2 = umaxu(ta, a2);
    unsigned tc = uminu(pb, c1);
    c1 = umaxu(pb, c1);
    c2 = umaxu(tc, c2);
    x0 += 2048u;
  }
  // merge with partner lane (other half of the chunk)
  unsigned p1 = __shfl_xor((int)a1, 1), p2 = __shfl_xor((int)a2, 1);
  unsigned q1 = __shfl_xor((int)c1, 1), q2 = __shfl_xor((int)c2, 1);
  unsigned A1 = umaxu(a1, p1);
  unsigned A2 = umaxu(uminu(a1, p1), umaxu(a2, p2));
  unsigned C1 = umaxu(c1, q1);
  unsigned C2 = umaxu(uminu(c1, q1), umaxu(c2, q2));
  if (half == 0){
    int baseA = (((nq*NB + bl  )*NN + m) << 1);
    int baseB = (((nq*NB + bl+8)*NN + m) << 1);
    pcv[baseA+0] = gfromkey(A1 >> 9); pci[baseA+0] = chunkbase + 127 - (int)(A1 & 127u);
    pcv[baseA+1] = gfromkey(A2 >> 9); pci[baseA+1] = chunkbase + 127 - (int)(A2 & 127u);
    pcv[baseB+0] = gfromkey(C1 >> 9); pci[baseB+0] = chunkbase + 127 - (int)(C1 & 127u);
    pcv[baseB+1] = gfromkey(C2 >> 9); pci[baseB+1] = chunkbase + 127 - (int)(C2 & 127u);
  }
}

// ---------------- resolve: exact argmax among windowed candidates ----------------
__launch_bounds__(256)
__global__ void kresolve(const float* __restrict__ LLF, const float* __restrict__ HLF,
                         const float* __restrict__ nl, const float* __restrict__ nh,
                         const float* __restrict__ iS,
                         const float* __restrict__ pcv, const int* __restrict__ pci,
                         int* __restrict__ idx){
  int w    = threadIdx.x >> 6;               // wave within block
  int lane = threadIdx.x & 63;
  int g = blockIdx.x*4 + w;                  // b*NN+m
  int b = g >> 11, m = g & 2047;
  float pv = -INFINITY; int pn = 0;
  if (lane < 32){                            // nq = lane>>1, rank = lane&1
    int base = ((((lane>>1)*NB + b)*NN + m) << 1) + (lane & 1);
    pv = pcv[base]; pn = pci[base];
  }
  float gmax = pv;
  for (int o=32;o;o>>=1) gmax = fmaxf(gmax, __shfl_down(gmax,o));
  gmax = __shfl(gmax, 0);
  unsigned long long mask = __ballot(pv >= gmax - 8e-5f);
  mask &= 0xFFFFFFFFull;
  float invS = iS[g];
  float bestQ = -INFINITY; int bestN = 1<<30;
  while (mask){
    int src = __builtin_ctzll(mask); mask &= mask-1;
    int   n  = __shfl(pn, src);
    float gv = __shfl(pv, src);
    float4 a = ((const float4*)(LLF + ((size_t)b*NN + n)*ND))[lane];
    float4 h = ((const float4*)(HLF + ((size_t)b*NN + m)*ND))[lane];
    float d = a.x*h.x + a.y*h.y + a.z*h.z + a.w*h.w;
    for (int o=32;o;o>>=1) d += __shfl_down(d,o);
    d = __shfl(d, 0);
    float sim = (d / fmaxf(nl[b*NN+n]*nh[g], 1e-8f)) * 0.0625f;
    float q = expf(sim - 0.0625f)*invS + gv;
    if (q > bestQ || (q == bestQ && n < bestN)){ bestQ = q; bestN = n; }
  }
  if (lane==0) idx[g] = bestN;
}

// ---------------- last-resort fallback (tiny ws) ----------------
__launch_bounds__(256)
__global__ void kstats(const float* __restrict__ A, const float* __restrict__ Bm,
                       const float* __restrict__ nl, const float* __restrict__ nh,
                       float* __restrict__ Mout, float* __restrict__ Sinv){
  __shared__ float As[64][33];
  __shared__ float Bs[64][33];
  __shared__ float Cs[64][65];
  const int b  = blockIdx.x >> 5;
  const int m0 = (blockIdx.x & 31) << 6;
  const float* Ab = A  + (size_t)b*NN*ND;
  const float* Bb = Bm + (size_t)b*NN*ND;
  const int tid = threadIdx.x;
  const int tx = tid & 15, ty = tid >> 4;
  float nhv[4];
  #pragma unroll
  for (int j=0;j<4;j++) nhv[j] = nh[b*NN + m0 + tx*4 + j];
  float Mr = -INFINITY, Sr = 0.0f;
  for (int nt=0; nt<NN; nt+=64){
    float acc[4][4] = {{0.f,0.f,0.f,0.f},{0.f,0.f,0.f,0.f},{0.f,0.f,0.f,0.f},{0.f,0.f,0.f,0.f}};
    for (int kc=0; kc<ND; kc+=32){
      __syncthreads();
      #pragma unroll
      for (int s=0;s<2;s++){
        int f = tid + (s<<8);
        int r = f >> 3;
        int c = (f & 7) << 2;
        float4 va = *(const float4*)(Ab + (size_t)(nt+r)*ND + kc + c);
        As[r][c]=va.x; As[r][c+1]=va.y; As[r][c+2]=va.z; As[r][c+3]=va.w;
        float4 vb = *(const float4*)(Bb + (size_t)(m0+r)*ND + kc + c);
        Bs[r][c]=vb.x; Bs[r][c+1]=vb.y; Bs[r][c+2]=vb.z; Bs[r][c+3]=vb.w;
      }
      __syncthreads();
      #pragma unroll 4
      for (int k=0;k<32;k++){
        float a0=As[ty*4+0][k], a1=As[ty*4+1][k], a2=As[ty*4+2][k], a3=As[ty*4+3][k];
        float b0=Bs[tx*4+0][k], b1=Bs[tx*4+1][k], b2=Bs[tx*4+2][k], b3=Bs[tx*4+3][k];
        acc[0][0]+=a0*b0; acc[0][1]+=a0*b1; acc[0][2]+=a0*b2; acc[0][3]+=a0*b3;
        acc[1][0]+=a1*b0; acc[1][1]+=a1*b1; acc[1][2]+=a1*b2; acc[1][3]+=a1*b3;
        acc[2][0]+=a2*b0; acc[2][1]+=a2*b1; acc[2][2]+=a2*b2; acc[2][3]+=a2*b3;
        acc[3][0]+=a3*b0; acc[3][1]+=a3*b1; acc[3][2]+=a3*b2; acc[3][3]+=a3*b3;
      }
    }
    float nlv[4];
    #pragma unroll
    for (int i=0;i<4;i++) nlv[i] = nl[b*NN + nt + ty*4 + i];
    __syncthreads();
    #pragma unroll
    for (int i=0;i<4;i++)
      #pragma unroll
      for (int j=0;j<4;j++){
        float denom = fmaxf(nlv[i]*nhv[j], 1e-8f);
        Cs[ty*4+i][tx*4+j] = (acc[i][j]/denom)*0.0625f;
      }
    __syncthreads();
    if (tid < 64){
      float tmax = -INFINITY;
      #pragma unroll 8
      for (int r=0;r<64;r++) tmax = fmaxf(tmax, Cs[r][tid]);
      float newM = fmaxf(Mr, tmax);
      float s = 0.0f;
      #pragma unroll 4
      for (int r=0;r<64;r++) s += expf(Cs[r][tid]-newM);
      Sr = Sr*expf(Mr-newM) + s;
      Mr = newM;
    }
  }
  if (tid < 64){
    Mout[b*NN+m0+tid] = Mr;
    Sinv[b*NN+m0+tid] = 1.0f/Sr;
  }
}

__launch_bounds__(256)
__global__ void kargmax(const float* __restrict__ A, const float* __restrict__ Bm,
                        const float* __restrict__ nl, const float* __restrict__ nh,
                        const float* __restrict__ Mv, const float* __restrict__ Sv,
                        int* __restrict__ idxout){
  __shared__ float As[64][33];
  __shared__ float Bs[64][33];
  __shared__ float Vs[16][64];
  __shared__ int   Is[16][64];
  const int b  = blockIdx.x >> 5;
  const int m0 = (blockIdx.x & 31) << 6;
  const float* Ab = A  + (size_t)b*NN*ND;
  const float* Bb = Bm + (size_t)b*NN*ND;
  const int tid = threadIdx.x;
  const int tx = tid & 15, ty = tid >> 4;
  float nhv[4], Mj[4], iSj[4];
  #pragma unroll
  for (int j=0;j<4;j++){
    int m = m0 + tx*4 + j;
    nhv[j] = nh[b*NN + m];
    Mj[j]  = Mv[b*NN + m];
    iSj[j] = Sv[b*NN + m];
  }
  float bestV = -INFINITY; int bestN = 0;
  for (int nt=0; nt<NN; nt+=64){
    float acc[4][4] = {{0.f,0.f,0.f,0.f},{0.f,0.f,0.f,0.f},{0.f,0.f,0.f,0.f},{0.f,0.f,0.f,0.f}};
    for (int kc=0; kc<ND; kc+=32){
      __syncthreads();
      #pragma unroll
      for (int s=0;s<2;s++){
        int f = tid + (s<<8);
        int r = f >> 3;
        int c = (f & 7) << 2;
        float4 va = *(const float4*)(Ab + (size_t)(nt+r)*ND + kc + c);
        As[r][c]=va.x; As[r][c+1]=va.y; As[r][c+2]=va.z; As[r][c+3]=va.w;
        float4 vb = *(const float4*)(Bb + (size_t)(m0+r)*ND + kc + c);
        Bs[r][c]=vb.x; Bs[r][c+1]=vb.y; Bs[r][c+2]=vb.z; Bs[r][c+3]=vb.w;
      }
      __syncthreads();
      #pragma unroll 4
      for (int k=0;k<32;k++){
        float a0=As[ty*4+0][k], a1=As[ty*4+1][k], a2=As[ty*4+2][k], a3=As[ty*4+3][k];
        float b0=Bs[tx*4+0][k], b1=Bs[tx*4+1][k], b2=Bs[tx*4+2][k], b3=Bs[tx*4+3][k];
        acc[0][0]+=a0*b0; acc[0][1]+=a0*b1; acc[0][2]+=a0*b2; acc[0][3]+=a0*b3;
        acc[1][0]+=a1*b0; acc[1][1]+=a1*b1; acc[1][2]+=a1*b2; acc[1][3]+=a1*b3;
        acc[2][0]+=a2*b0; acc[2][1]+=a2*b1; acc[2][2]+=a2*b2; acc[2][3]+=a2*b3;
        acc[3][0]+=a3*b0; acc[3][1]+=a3*b1; acc[3][2]+=a3*b2; acc[3][3]+=a3*b3;
      }
    }
    float nlv[4];
    #pragma unroll
    for (int i=0;i<4;i++) nlv[i] = nl[b*NN + nt + ty*4 + i];
    float lv[4]; int li[4];
    #pragma unroll
    for (int j=0;j<4;j++){ lv[j] = -INFINITY; li[j] = 0; }
    #pragma unroll
    for (int i=0;i<4;i++){
      int n = nt + ty*4 + i;
      #pragma unroll
      for (int j=0;j<4;j++){
        float denom = fmaxf(nlv[i]*nhv[j], 1e-8f);
        float sim = (acc[i][j]/denom)*0.0625f;
        float p = expf(sim - Mj[j]) * iSj[j];
        float v = p + gumbelv((unsigned)b, (unsigned)n, (unsigned)(m0 + tx*4 + j));
        if (v > lv[j]) { lv[j] = v; li[j] = n; }
      }
    }
    __syncthreads();
    #pragma unroll
    for (int j=0;j<4;j++){ Vs[ty][tx*4+j]=lv[j]; Is[ty][tx*4+j]=li[j]; }
    __syncthreads();
    if (tid < 64){
      #pragma unroll 4
      for (int t=0;t<16;t++){
        float v = Vs[t][tid];
        if (v > bestV){ bestV = v; bestN = Is[t][tid]; }
      }
    }
  }
  if (tid < 64) idxout[b*NN + m0 + tid] = bestN;
}

// ---------------- shared tail kernels ----------------
__global__ void ksort(const int* __restrict__ idx, int* __restrict__ cntg,
                      int* __restrict__ offg, int* __restrict__ sl){
  __shared__ int c[NN];
  __shared__ int part[256];
  int b = blockIdx.x, tid = threadIdx.x;
  for (int v=tid; v<NN; v+=256) c[v]=0;
  __syncthreads();
  for (int j=tid; j<NN; j+=256) atomicAdd(&c[idx[b*NN+j]], 1);
  __syncthreads();
  int base = tid*8, s=0, lc[8];
  #pragma unroll
  for (int k=0;k<8;k++){ lc[k]=c[base+k]; s+=lc[k]; }
  part[tid]=s; __syncthreads();
  for (int o=1;o<256;o<<=1){
    int v = (tid>=o)? part[tid-o] : 0;
    __syncthreads();
    part[tid]+=v;
    __syncthreads();
  }
  int run = part[tid]-s;
  #pragma unroll
  for (int k=0;k<8;k++){
    int v = base+k;
    cntg[b*NN+v]=lc[k];
    offg[b*NN+v]=run;
    for (int j=0;j<lc[k];j++) sl[b*NN+run+j]=v;
    run += lc[k];
  }
}

__global__ void kw(const float* __restrict__ LLF, const float* __restrict__ HLF,
                   const float* __restrict__ nl, const float* __restrict__ nh,
                   const int* __restrict__ sl, float* __restrict__ w){
  int g = blockIdx.x*4 + (threadIdx.x>>6);
  int lane = threadIdx.x & 63;
  int b = g >> 11;
  int s = sl[g];
  float4 a = ((const float4*)(HLF + ((size_t)b*NN + s)*ND))[lane];
  float4 l = ((const float4*)(LLF + (size_t)g*ND))[lane];
  float d = a.x*l.x + a.y*l.y + a.z*l.z + a.w*l.w;
  for (int o=32;o;o>>=1) d += __shfl_down(d,o);
  if (lane==0){
    float denom = fmaxf(nh[b*NN+s]*nl[g], 1e-8f);
    w[g] = d/denom;
  }
}

__global__ void knoise(const float* __restrict__ w, float* __restrict__ nz){
  int b = blockIdx.x, tid = threadIdx.x;
  __shared__ float sred[4];
  float x[8]; float mx = -INFINITY;
  #pragma unroll
  for (int k=0;k<8;k++){ x[k] = w[b*NN + tid*8 + k] / 0.1f; mx = fmaxf(mx, x[k]); }
  for (int o=32;o;o>>=1) mx = fmaxf(mx, __shfl_down(mx,o));
  mx = __shfl(mx, 0);
  if ((tid&63)==0) sred[tid>>6] = mx;
  __syncthreads();
  mx = fmaxf(fmaxf(sred[0],sred[1]), fmaxf(sred[2],sred[3]));
  __syncthreads();
  float e[8]; float s = 0.f;
  #pragma unroll
  for (int k=0;k<8;k++){ e[k] = expf(x[k]-mx); s += e[k]; }
  for (int o=32;o;o>>=1) s += __shfl_down(s,o);
  s = __shfl(s, 0);
  if ((tid&63)==0) sred[tid>>6] = s;
  __syncthreads();
  s = sred[0]+sred[1]+sred[2]+sred[3];
  #pragma unroll
  for (int k=0;k<8;k++) nz[b*NN + tid*8 + k] = e[k]/s;
}

__global__ void kfinal(const float* __restrict__ LLF, const float* __restrict__ HLF,
                       const int* __restrict__ cnt, const int* __restrict__ off,
                       const float* __restrict__ nz, float* __restrict__ out){
  int row = blockIdx.x;
  int lane = threadIdx.x;
  int b = row >> 11;
  float4 h = ((const float4*)(HLF + (size_t)row*ND))[lane];
  int c = cnt[row];
  if (c > 0){
    int i = off[row] + c - 1;
    float ns = nz[b*NN + i];
    float4 l = ((const float4*)(LLF + ((size_t)(b*NN + i))*ND))[lane];
    h.x += l.x*ns; h.y += l.y*ns; h.z += l.z*ns; h.w += l.w*ns;
  }
  ((float4*)(out + (size_t)row*ND))[lane] = h;
}

extern "C" void kernel_launch(void* const* d_in, const int* in_sizes, int n_in,
                              void* d_out, int out_size, void* d_ws, size_t ws_size,
                              hipStream_t stream){
  const float* LLF = (const float*)d_in[0];
  const float* HLF = (const float*)d_in[1];
  float* out = (float*)d_out;
  float* ws = (float*)d_ws;

  float* nl  = ws;
  float* nh  = ws + 1*(size_t)BNtot;
  float* iS  = ws + 2*(size_t)BNtot;
  int*   idx = (int*)(ws + 3*(size_t)BNtot);
  int*   cnt = (int*)(ws + 4*(size_t)BNtot);
  int*   off = (int*)(ws + 5*(size_t)BNtot);
  int*   sl  = (int*)(ws + 6*(size_t)BNtot);
  float* wv  = ws + 7*(size_t)BNtot;
  float* nz  = ws + 8*(size_t)BNtot;
  float* partS = ws + 9*(size_t)BNtot;                 // 16*BNtot
  float* pcv   = partS + 16*(size_t)BNtot;             // 32*BNtot (16 chunks x 2 ranks)
  int*   pci   = (int*)(pcv + 32*(size_t)BNtot);       // 32*BNtot
  ushort* Abf  = (ushort*)(pci + 32*(size_t)BNtot);    // BNtot*256 bf16 (16.7 MB)
  ushort* Bbf  = Abf + (size_t)BNtot*ND;
  const size_t needBytes1 = (9 + 16 + 32 + 32) * (size_t)BNtot * 4;           // ~11.7 MB
  const size_t needBytes2 = needBytes1 + 2 * (size_t)BNtot * ND * 2;          // ~45.2 MB

  if (ws_size >= needBytes2){
    hipLaunchKernelGGL(kprep,    dim3(BNtot/4, 2), dim3(256), 0, stream, LLF, HLF, Abf, Bbf, nl, nh);
    hipLaunchKernelGGL(kgemm_dma,dim3(16,16,16),   dim3(256), 0, stream, Abf, Bbf, nl, nh, partS);
    hipLaunchKernelGGL(kScomb,   dim3(BNtot/256),  dim3(256), 0, stream, partS, iS);
    hipLaunchKernelGGL(kgumbel,  dim3(2048),       dim3(256), 0, stream, pcv, pci);
    hipLaunchKernelGGL(kresolve, dim3(BNtot/4),    dim3(256), 0, stream, LLF, HLF, nl, nh, iS, pcv, pci, idx);
  } else if (ws_size >= needBytes1){
    hipLaunchKernelGGL(knorms,   dim3(BNtot),      dim3(128), 0, stream, LLF, HLF, nl, nh);
    hipLaunchKernelGGL(kgemm_mfma,dim3(16,16,16),  dim3(256), 0, stream, LLF, HLF, nl, nh, partS);
    hipLaunchKernelGGL(kScomb,   dim3(BNtot/256),  dim3(256), 0, stream, partS, iS);
    hipLaunchKernelGGL(kgumbel,  dim3(2048),       dim3(256), 0, stream, pcv, pci);
    hipLaunchKernelGGL(kresolve, dim3(BNtot/4),    dim3(256), 0, stream, LLF, HLF, nl, nh, iS, pcv, pci, idx);
  } else {
    float* Mv = ws + 9*(size_t)BNtot;
    hipLaunchKernelGGL(knorms,   dim3(BNtot),      dim3(128), 0, stream, LLF, HLF, nl, nh);
    hipLaunchKernelGGL(kstats,   dim3(NB*32),      dim3(256), 0, stream, LLF, HLF, nl, nh, Mv, iS);
    hipLaunchKernelGGL(kargmax,  dim3(NB*32),      dim3(256), 0, stream, LLF, HLF, nl, nh, Mv, iS, idx);
  }

  hipLaunchKernelGGL(ksort,  dim3(NB),      dim3(256), 0, stream, idx, cnt, off, sl);
  hipLaunchKernelGGL(kw,     dim3(BNtot/4), dim3(256), 0, stream, LLF, HLF, nl, nh, sl, wv);
  hipLaunchKernelGGL(knoise, dim3(NB),      dim3(256), 0, stream, wv, nz);
  hipLaunchKernelGGL(kfinal, dim3(BNtot),   dim3(64),  0, stream, LLF, HLF, cnt, off, nz, out);
}